// Round 2
// baseline (7575.540 us; speedup 1.0000x reference)
//
#include <hip/hip_runtime.h>
#include <hip/hip_bf16.h>

#define B_  32
#define N_  512
#define D_  256
#define H_  8
#define HD_ 32
#define LW_ 25

// ---------------------------------------------------------------------------
// Generic tiled GEMM: C[m,o] = sum_k A[m,k] * W[o,k] (+bias) ; all f32
// Modes: plain store (opt. relu/accumulate) or QKV scatter to (B,H,L,32) bufs.
// A row mapping: row = (m/rowsPerA)*aBatch + (m%rowsPerA)*K  (for strided slices)
// z-batch strides for batched einsum.
// ---------------------------------------------------------------------------
#define BM 64
#define BO 64
#define BK 32

__global__ __launch_bounds__(256) void gemm_k(
    const float* Aq, const float* Akv,
    const float* W, const float* bias, float* C,
    int M, int K, int Onum,
    int rowsPerA, long long aBatch,
    long long aZ, long long wZ, long long cZ,
    int qkvmode, int flags,
    float* Qd, float* Kd, float* Vd, int Lseq)
{
    __shared__ __align__(16) float As[BK][BM + 4];
    __shared__ __align__(16) float Ws[BK][BO + 4];
    const int tid = threadIdx.x;
    const int o0 = blockIdx.x * BO;
    const int m0 = blockIdx.y * BM;
    const int z  = blockIdx.z;
    const float* A = (qkvmode && o0 >= 256) ? Akv : Aq;
    A += (long long)z * aZ;
    if (C) C += (long long)z * cZ;
    const long long wzoff = (long long)z * wZ;

    const int tx = tid & 15, ty = tid >> 4;
    float acc[4][4] = {};

    for (int k0 = 0; k0 < K; k0 += BK) {
        #pragma unroll
        for (int i = 0; i < 8; i++) {
            int e = tid + i * 256;
            int kk = e & 31, mm = e >> 5;
            int m = m0 + mm;
            float v = 0.f;
            if (m < M) {
                long long row = (long long)(m / rowsPerA) * aBatch +
                                (long long)(m % rowsPerA) * K;
                v = A[row + k0 + kk];
            }
            As[kk][mm] = v;
        }
        #pragma unroll
        for (int i = 0; i < 8; i++) {
            int e = tid + i * 256;
            int kk = e & 31, oo = e >> 5;
            long long idx = wzoff + (long long)(o0 + oo) * K + k0 + kk;
            Ws[kk][oo] = W[idx];
        }
        __syncthreads();
        #pragma unroll
        for (int kk = 0; kk < BK; kk++) {
            float4 a4 = *(const float4*)&As[kk][ty * 4];
            float4 w4 = *(const float4*)&Ws[kk][tx * 4];
            float a[4] = {a4.x, a4.y, a4.z, a4.w};
            float w[4] = {w4.x, w4.y, w4.z, w4.w};
            #pragma unroll
            for (int i = 0; i < 4; i++)
                #pragma unroll
                for (int j = 0; j < 4; j++)
                    acc[i][j] += a[i] * w[j];
        }
        __syncthreads();
    }

    #pragma unroll
    for (int i = 0; i < 4; i++) {
        int m = m0 + ty * 4 + i;
        if (m >= M) continue;
        #pragma unroll
        for (int j = 0; j < 4; j++) {
            int o = o0 + tx * 4 + j;
            if (o >= Onum) continue;
            float v = acc[i][j];
            if (bias) v += bias[o];
            if (flags & 1) v = fmaxf(v, 0.f);
            if (!qkvmode) {
                long long ci = (long long)m * Onum + o;
                if (flags & 2) C[ci] += v; else C[ci] = v;
            } else {
                int which = o >> 8;
                int oo = o & 255;
                int h = oo >> 5, j2 = oo & 31;
                int b = m / Lseq, n = m % Lseq;
                float* Dp = (which == 0) ? Qd : (which == 1) ? Kd : Vd;
                Dp[(((long long)b * H_ + h) * Lseq + n) * HD_ + j2] = v;
            }
        }
    }
}

// ---------------------------------------------------------------------------
// Fused attention: per (b, 16-row q-tile), loop heads; scores+softmax+PV in LDS.
// Q/K/V layout (B,H,L,32) f32. O layout (B*L, 256) f32 (heads concatenated).
// meanW (optional, L==512 only): accumulates sum over heads of softmax probs.
// ---------------------------------------------------------------------------
__global__ __launch_bounds__(256) void attn_k(
    const float* Qb, const float* Kb, const float* Vb,
    float* O, float* meanW, int L, int causal)
{
    __shared__ float S[16 * 512];
    __shared__ float Qt[16 * 32];
    __shared__ float Vt[64 * 32];
    __shared__ float pm[256];
    __shared__ float rmax[16];
    __shared__ float rinv[16];
    const int tid = threadIdx.x;
    const int qt = blockIdx.x, b = blockIdx.y;
    const int q0 = qt * 16;
    const float scale = 0.17677669529663687f;  // 1/sqrt(32)
    const int Lpad = (L + 63) & ~63;

    for (int h = 0; h < H_; h++) {
        const float* Qh = Qb + (((long long)b * H_ + h) * L) * HD_;
        const float* Kh = Kb + (((long long)b * H_ + h) * L) * HD_;
        const float* Vh = Vb + (((long long)b * H_ + h) * L) * HD_;

        for (int e = tid; e < 16 * 32; e += 256) {
            int rr = e >> 5, d = e & 31;
            int n = q0 + rr;
            Qt[e] = (n < L) ? Qh[(long long)n * HD_ + d] : 0.f;
        }
        __syncthreads();

        for (int k = tid; k < L; k += 256) {
            float4 kr[8];
            const float4* kp = (const float4*)(Kh + (long long)k * HD_);
            #pragma unroll
            for (int d = 0; d < 8; d++) kr[d] = kp[d];
            const float4* qp = (const float4*)Qt;
            #pragma unroll
            for (int rr = 0; rr < 16; rr++) {
                float s = 0.f;
                #pragma unroll
                for (int d = 0; d < 8; d++) {
                    float4 qv = qp[rr * 8 + d];
                    s += qv.x * kr[d].x + qv.y * kr[d].y + qv.z * kr[d].z + qv.w * kr[d].w;
                }
                s *= scale;
                if (causal && k > q0 + rr) s = -1e9f;
                S[rr * 512 + k] = s;
            }
        }
        __syncthreads();

        {
            const int rr = tid >> 4, g = tid & 15;
            float m = -3e38f;
            for (int k = g; k < L; k += 16) m = fmaxf(m, S[rr * 512 + k]);
            pm[tid] = m;
            __syncthreads();
            if (g == 0) {
                float mm = pm[rr * 16];
                #pragma unroll
                for (int t = 1; t < 16; t++) mm = fmaxf(mm, pm[rr * 16 + t]);
                rmax[rr] = mm;
            }
            __syncthreads();
            const float rm = rmax[rr];
            float ps = 0.f;
            for (int k = g; k < L; k += 16) {
                float e = __expf(S[rr * 512 + k] - rm);
                S[rr * 512 + k] = e;
                ps += e;
            }
            pm[tid] = ps;
            __syncthreads();
            if (g == 0) {
                float ss = 0.f;
                #pragma unroll
                for (int t = 0; t < 16; t++) ss += pm[rr * 16 + t];
                rinv[rr] = 1.f / ss;
            }
            __syncthreads();
            const float inv = rinv[rr];
            for (int k = g; k < L; k += 16) S[rr * 512 + k] *= inv;
            for (int k = L + g; k < Lpad; k += 16) S[rr * 512 + k] = 0.f;
        }
        __syncthreads();

        if (meanW != nullptr) {
            float* dst = meanW + ((long long)b * N_ + q0) * N_;
            for (int e = tid; e < 16 * 512; e += 256) {
                if (h == 0) dst[e] = S[e];
                else dst[e] += S[e];
            }
        }

        float acc0 = 0.f, acc1 = 0.f;
        const int j = tid & 31;
        const int r0 = tid >> 5;  // rows r0 and r0+8
        for (int c0 = 0; c0 < L; c0 += 64) {
            __syncthreads();
            #pragma unroll
            for (int ii = 0; ii < 8; ii++) {
                int e = tid + ii * 256;
                int kk = e >> 5, d = e & 31;
                int k = c0 + kk;
                Vt[e] = (k < L) ? Vh[(long long)k * HD_ + d] : 0.f;
            }
            __syncthreads();
            #pragma unroll 4
            for (int kk = 0; kk < 64; kk++) {
                float v = Vt[kk * 32 + j];
                acc0 += S[r0 * 512 + c0 + kk] * v;
                acc1 += S[(r0 + 8) * 512 + c0 + kk] * v;
            }
        }
        {
            int n0 = q0 + r0, n1 = q0 + r0 + 8;
            if (n0 < L) O[((long long)b * L + n0) * D_ + h * HD_ + j] = acc0;
            if (n1 < L) O[((long long)b * L + n1) * D_ + h * HD_ + j] = acc1;
        }
        __syncthreads();
    }
}

// ---------------------------------------------------------------------------
// Small kernels
// ---------------------------------------------------------------------------
__global__ __launch_bounds__(256) void rowsoftmax_k(const float* in, float* out) {
    __shared__ float red[256];
    const long long row = blockIdx.x;
    const int t = threadIdx.x;
    const float* ip = in + row * 2048;
    float* op = out + row * 2048;
    float m = -3e38f;
    for (int k = t; k < 2048; k += 256) m = fmaxf(m, ip[k]);
    red[t] = m; __syncthreads();
    for (int s = 128; s > 0; s >>= 1) { if (t < s) red[t] = fmaxf(red[t], red[t + s]); __syncthreads(); }
    m = red[0]; __syncthreads();
    float ps = 0.f;
    for (int k = t; k < 2048; k += 256) { float e = __expf(ip[k] - m); op[k] = e; ps += e; }
    red[t] = ps; __syncthreads();
    for (int s = 128; s > 0; s >>= 1) { if (t < s) red[t] += red[t + s]; __syncthreads(); }
    const float inv = 1.f / red[0];
    for (int k = t; k < 2048; k += 256) op[k] *= inv;
}

__global__ void embed_k(const int* q, const int* r, const int* qry,
                        const float* Memb, const float* Eemb, const float* P,
                        float* M, float* E) {
    const int i = blockIdx.x; const int t = threadIdx.x;
    const int n = i & (N_ - 1);
    const int x = q[i] + 2048 * r[i];
    M[(long long)i * D_ + t] = Memb[(long long)x * D_ + t] + P[(long long)n * D_ + t];
    E[(long long)i * D_ + t] = Eemb[(long long)qry[i] * D_ + t];
}

__global__ void gather_k(const int* q, const float* T, float* G) {
    const int i = blockIdx.x; const int t = threadIdx.x;
    G[(long long)i * D_ + t] = T[(long long)q[i] * D_ + t];
}

__global__ __launch_bounds__(256) void ln_k(const float* xa, const float* xb, const float* xc,
                                            const float* g, const float* bta,
                                            float* out1, float* out2) {
    __shared__ float red[256];
    const long long row = blockIdx.x;
    const int t = threadIdx.x;
    float v = xa[row * D_ + t];
    if (xb) v += xb[row * D_ + t];
    if (xc) v += xc[row * D_ + t];
    red[t] = v; __syncthreads();
    for (int s = 128; s > 0; s >>= 1) { if (t < s) red[t] += red[t + s]; __syncthreads(); }
    const float mean = red[0] * (1.f / 256.f);
    __syncthreads();
    const float d = v - mean;
    red[t] = d * d; __syncthreads();
    for (int s = 128; s > 0; s >>= 1) { if (t < s) red[t] += red[t + s]; __syncthreads(); }
    const float var = red[0] * (1.f / 256.f);
    const float y = d * rsqrtf(var + 1e-5f) * g[t] + bta[t];
    out1[row * D_ + t] = y;
    if (out2) out2[row * D_ + t] = y;
}

__global__ void scatterlocal_k(const float* tail, float* Slocal, float* Sacc) {
    const int i = blockIdx.x; const int t = threadIdx.x;
    const int n = i & (N_ - 1), b = i >> 9;
    float v = 0.f;
    if (n >= N_ - LW_) {
        v = tail[((long long)(b * LW_ + (n - (N_ - LW_)))) * D_ + t];
        Sacc[(long long)i * D_ + t] += v;
    }
    Slocal[(long long)i * D_ + t] = v;
}

__global__ void add_k(float* dst, const float* src) {
    const long long i = (long long)blockIdx.x * 256 + threadIdx.x;
    dst[i] += src[i];
}

__global__ void scale_k(float* x) {
    const long long i = (long long)blockIdx.x * 256 + threadIdx.x;
    x[i] *= 0.125f;
}

__global__ __launch_bounds__(256) void pred_k(const float* F, const float* pw, const float* pb,
                                              float* out) {
    const int tid = threadIdx.x;
    const int wave = tid >> 6, lane = tid & 63;
    const long long row = (long long)blockIdx.x * 4 + wave;
    const float* fp = F + row * D_ + lane * 4;
    float s = 0.f;
    #pragma unroll
    for (int j = 0; j < 4; j++) s += fp[j] * pw[lane * 4 + j];
    #pragma unroll
    for (int off = 32; off > 0; off >>= 1) s += __shfl_down(s, off);
    if (lane == 0) {
        float p = 1.f / (1.f + __expf(-(s + pb[0])));
        out[row] = p;
    }
}

// ---------------------------------------------------------------------------
static void gemm(hipStream_t st, const float* Aq, const float* Akv,
                 const float* W, const float* bias, float* C,
                 int M, int K, int Onum, int rowsPerA, long long aBatch,
                 long long aZ, long long wZ, long long cZ, int Z,
                 int qkv, int flags, float* Qd, float* Kd, float* Vd, int Lseq)
{
    dim3 g((Onum + BO - 1) / BO, (M + BM - 1) / BM, Z), blk(256, 1, 1);
    gemm_k<<<g, blk, 0, st>>>(Aq, Akv, W, bias, C, M, K, Onum, rowsPerA, aBatch,
                              aZ, wZ, cZ, qkv, flags, Qd, Kd, Vd, Lseq);
}

extern "C" void kernel_launch(void* const* d_in, const int* in_sizes, int n_in,
                              void* d_out, int out_size, void* d_ws, size_t ws_size,
                              hipStream_t stream)
{
    const int* qi  = (const int*)d_in[0];
    const int* ri  = (const int*)d_in[1];
    const int* qry = (const int*)d_in[2];
    const float* Memb = (const float*)d_in[3];
    const float* Eemb = (const float*)d_in[4];
    const float* Pp   = (const float*)d_in[5];
    const float* ainw = (const float*)d_in[6];
    const float* ainb = (const float*)d_in[7];
    const float* aoutw= (const float*)d_in[8];
    const float* aoutb= (const float*)d_in[9];
    const float* scw  = (const float*)d_in[10];
    const float* spw  = (const float*)d_in[11];
    const float* spb  = (const float*)d_in[12];
    const float* stew = (const float*)d_in[13];
    const float* steb = (const float*)d_in[14];
    const float* fw1  = (const float*)d_in[15];
    const float* fb1  = (const float*)d_in[16];
    const float* fw2  = (const float*)d_in[17];
    const float* fb2  = (const float*)d_in[18];
    const float* l1g  = (const float*)d_in[19];
    const float* l1b  = (const float*)d_in[20];
    const float* l2g  = (const float*)d_in[21];
    const float* l2b  = (const float*)d_in[22];
    const float* pw   = (const float*)d_in[23];
    const float* pb   = (const float*)d_in[24];
    float* out = (float*)d_out;
    float* outW = out + B_ * N_;   // attn-weights output region (f32)

    float* ws = (float*)d_ws;
    const size_t BND = (size_t)B_ * N_ * D_;   // 4,194,304 floats
    float* b0  = ws + 0 * BND;   // SW -> M -> FFNout
    float* b1  = ws + 1 * BND;   // E -> G -> F
    float* b2  = ws + 2 * BND;   // S_base
    float* b3  = ws + 3 * BND;   // Q
    float* b4  = ws + 4 * BND;   // K
    float* b5  = ws + 5 * BND;   // V
    float* b6  = ws + 6 * BND;   // O (attn out, pre-proj)
    float* b7  = ws + 7 * BND;   // S_local (padded)
    float* b8  = ws + 8 * BND;   // S_sg
    float* b9  = ws + 9 * BND;   // S_glob
    float* b10 = ws + 10 * BND;  // S accumulator
    float* b11 = ws + 11 * BND;  // S_sg-pre / FFN hidden
    float* BNN = ws + 12 * BND;               // (B,N,N) f32 scratch
    float* Ttab = BNN + (size_t)B_ * N_ * N_; // (2048, 256) f32
    const int BNrows = B_ * N_;               // 16384

    // --- skill table: T = softmax(scw) @ spw^T + spb ---
    rowsoftmax_k<<<2048, 256, 0, stream>>>(scw, b0);
    gemm(stream, b0, b0, spw, spb, Ttab, 2048, 2048, 256, 2048, 0, 0, 0, 0, 1,
         0, 0, nullptr, nullptr, nullptr, 0);

    // --- embeddings: M = M_emb[q + 2048 r] + P ; E = E_emb[qry] ---
    embed_k<<<BNrows, 256, 0, stream>>>(qi, ri, qry, Memb, Eemb, Pp, b0, b1);

    // --- attn 0: q=E, kv=M, causal, record mean weights (into out directly) ---
    gemm(stream, b1, b0, ainw + 0, ainb + 0, nullptr, BNrows, 256, 768, BNrows, 0,
         0, 0, 0, 1, 1, 0, b3, b4, b5, N_);
    attn_k<<<dim3(32, B_), 256, 0, stream>>>(b3, b4, b5, b6, outW, N_, 1);
    scale_k<<<(B_ * N_ * N_) / 256, 256, 0, stream>>>(outW);
    gemm(stream, b6, b6, aoutw + 0, aoutb + 0, b10, BNrows, 256, 256, BNrows, 0,
         0, 0, 0, 1, 0, 0, nullptr, nullptr, nullptr, 0);
    // S_base = LN1(proj + M + E)  (also init accumulator)
    ln_k<<<BNrows, 256, 0, stream>>>(b10, b0, b1, l1g, l1b, b2, b10);

    // --- attn 1 (local, LW=25, causal) on S_base[:, -25:, :] ---
    gemm(stream, b2 + (N_ - LW_) * D_, b2 + (N_ - LW_) * D_,
         ainw + 1 * 768 * 256, ainb + 768, nullptr, B_ * LW_, 256, 768,
         LW_, (long long)N_ * D_, 0, 0, 0, 1, 1, 0, b3, b4, b5, LW_);
    attn_k<<<dim3(2, B_), 256, 0, stream>>>(b3, b4, b5, b6, nullptr, LW_, 1);
    gemm(stream, b6, b6, aoutw + 1 * 65536, aoutb + 256, BNN, B_ * LW_, 256, 256,
         B_ * LW_, 0, 0, 0, 0, 1, 0, 0, nullptr, nullptr, nullptr, 0);
    scatterlocal_k<<<BNrows, 256, 0, stream>>>(BNN, b7, b10);

    // --- skill group path ---
    gather_k<<<BNrows, 256, 0, stream>>>(qi, Ttab, b1);   // G
    // BNN[b] = S_base[b] @ G[b]^T   (batched over z=32)
    gemm(stream, b2, b2, b1, nullptr, BNN, N_, 256, N_, N_, 0,
         (long long)N_ * D_, (long long)N_ * D_, (long long)N_ * N_, B_,
         0, 0, nullptr, nullptr, nullptr, 0);
    // S_sg-pre = BNN @ stew^T + steb
    gemm(stream, BNN, BNN, stew, steb, b11, BNrows, 512, 256, BNrows, 0,
         0, 0, 0, 1, 0, 0, nullptr, nullptr, nullptr, 0);
    // attn 2 (self, no mask)
    gemm(stream, b11, b11, ainw + 2 * 196608, ainb + 2 * 768, nullptr, BNrows, 256, 768,
         BNrows, 0, 0, 0, 0, 1, 1, 0, b3, b4, b5, N_);
    attn_k<<<dim3(32, B_), 256, 0, stream>>>(b3, b4, b5, b6, nullptr, N_, 0);
    gemm(stream, b6, b6, aoutw + 2 * 65536, aoutb + 2 * 256, b8, BNrows, 256, 256,
         BNrows, 0, 0, 0, 0, 1, 0, 0, nullptr, nullptr, nullptr, 0);
    add_k<<<BNrows, 256, 0, stream>>>(b10, b8);

    // --- attn 3: self on S_base, causal -> S_glob ---
    gemm(stream, b2, b2, ainw + 3 * 196608, ainb + 3 * 768, nullptr, BNrows, 256, 768,
         BNrows, 0, 0, 0, 0, 1, 1, 0, b3, b4, b5, N_);
    attn_k<<<dim3(32, B_), 256, 0, stream>>>(b3, b4, b5, b6, nullptr, N_, 1);
    gemm(stream, b6, b6, aoutw + 3 * 65536, aoutb + 3 * 256, b9, BNrows, 256, 256,
         BNrows, 0, 0, 0, 0, 1, 0, 0, nullptr, nullptr, nullptr, 0);
    add_k<<<BNrows, 256, 0, stream>>>(b10, b9);

    // --- attn 4: q=S_base, kv=S_local, no mask -> accumulate ---
    gemm(stream, b2, b7, ainw + 4 * 196608, ainb + 4 * 768, nullptr, BNrows, 256, 768,
         BNrows, 0, 0, 0, 0, 1, 1, 0, b3, b4, b5, N_);
    attn_k<<<dim3(32, B_), 256, 0, stream>>>(b3, b4, b5, b6, nullptr, N_, 0);
    gemm(stream, b6, b6, aoutw + 4 * 65536, aoutb + 4 * 256, b10, BNrows, 256, 256,
         BNrows, 0, 0, 0, 0, 1, 0, 2, nullptr, nullptr, nullptr, 0);

    // --- attn 5: q=S_sg, kv=S_glob, no mask -> accumulate ---
    gemm(stream, b8, b9, ainw + 5 * 196608, ainb + 5 * 768, nullptr, BNrows, 256, 768,
         BNrows, 0, 0, 0, 0, 1, 1, 0, b3, b4, b5, N_);
    attn_k<<<dim3(32, B_), 256, 0, stream>>>(b3, b4, b5, b6, nullptr, N_, 0);
    gemm(stream, b6, b6, aoutw + 5 * 65536, aoutb + 5 * 256, b10, BNrows, 256, 256,
         BNrows, 0, 0, 0, 0, 1, 0, 2, nullptr, nullptr, nullptr, 0);

    // --- FFN + LN2 + prediction ---
    gemm(stream, b10, b10, fw1, fb1, b11, BNrows, 256, 256, BNrows, 0,
         0, 0, 0, 1, 0, 1, nullptr, nullptr, nullptr, 0);
    gemm(stream, b11, b11, fw2, fb2, b0, BNrows, 256, 256, BNrows, 0,
         0, 0, 0, 1, 0, 0, nullptr, nullptr, nullptr, 0);
    ln_k<<<BNrows, 256, 0, stream>>>(b0, b10, nullptr, l2g, l2b, b1, nullptr);
    pred_k<<<BNrows / 4, 256, 0, stream>>>(b1, pw, pb, out);
}

// Round 3
// 3258.585 us; speedup vs baseline: 2.3248x; 2.3248x over previous
//
#include <hip/hip_runtime.h>
#include <hip/hip_bf16.h>

#define B_  32
#define N_  512
#define D_  256
#define H_  8
#define HD_ 32
#define LW_ 25

// ---------------------------------------------------------------------------
// Generic tiled GEMM: C[m,o] = sum_k A[m,k] * W[o,k] (+bias) ; all f32
// ---------------------------------------------------------------------------
#define BM 64
#define BO 64
#define BK 32

__global__ __launch_bounds__(256) void gemm_k(
    const float* Aq, const float* Akv,
    const float* W, const float* bias, float* C,
    int M, int K, int Onum,
    int rowsPerA, long long aBatch,
    long long aZ, long long wZ, long long cZ,
    int qkvmode, int flags,
    float* Qd, float* Kd, float* Vd, int Lseq)
{
    __shared__ __align__(16) float As[BK][BM + 4];
    __shared__ __align__(16) float Ws[BK][BO + 4];
    const int tid = threadIdx.x;
    const int o0 = blockIdx.x * BO;
    const int m0 = blockIdx.y * BM;
    const int z  = blockIdx.z;
    const float* A = (qkvmode && o0 >= 256) ? Akv : Aq;
    A += (long long)z * aZ;
    if (C) C += (long long)z * cZ;
    const long long wzoff = (long long)z * wZ;

    const int tx = tid & 15, ty = tid >> 4;
    float acc[4][4] = {};

    for (int k0 = 0; k0 < K; k0 += BK) {
        #pragma unroll
        for (int i = 0; i < 8; i++) {
            int e = tid + i * 256;
            int kk = e & 31, mm = e >> 5;
            int m = m0 + mm;
            float v = 0.f;
            if (m < M) {
                long long row = (long long)(m / rowsPerA) * aBatch +
                                (long long)(m % rowsPerA) * K;
                v = A[row + k0 + kk];
            }
            As[kk][mm] = v;
        }
        #pragma unroll
        for (int i = 0; i < 8; i++) {
            int e = tid + i * 256;
            int kk = e & 31, oo = e >> 5;
            long long idx = wzoff + (long long)(o0 + oo) * K + k0 + kk;
            Ws[kk][oo] = W[idx];
        }
        __syncthreads();
        #pragma unroll
        for (int kk = 0; kk < BK; kk++) {
            float4 a4 = *(const float4*)&As[kk][ty * 4];
            float4 w4 = *(const float4*)&Ws[kk][tx * 4];
            float a[4] = {a4.x, a4.y, a4.z, a4.w};
            float w[4] = {w4.x, w4.y, w4.z, w4.w};
            #pragma unroll
            for (int i = 0; i < 4; i++)
                #pragma unroll
                for (int j = 0; j < 4; j++)
                    acc[i][j] += a[i] * w[j];
        }
        __syncthreads();
    }

    #pragma unroll
    for (int i = 0; i < 4; i++) {
        int m = m0 + ty * 4 + i;
        if (m >= M) continue;
        #pragma unroll
        for (int j = 0; j < 4; j++) {
            int o = o0 + tx * 4 + j;
            if (o >= Onum) continue;
            float v = acc[i][j];
            if (bias) v += bias[o];
            if (flags & 1) v = fmaxf(v, 0.f);
            if (!qkvmode) {
                long long ci = (long long)m * Onum + o;
                if (flags & 2) C[ci] += v; else C[ci] = v;
            } else {
                int which = o >> 8;
                int oo = o & 255;
                int h = oo >> 5, j2 = oo & 31;
                int b = m / Lseq, n = m % Lseq;
                float* Dp = (which == 0) ? Qd : (which == 1) ? Kd : Vd;
                Dp[(((long long)b * H_ + h) * Lseq + n) * HD_ + j2] = v;
            }
        }
    }
}

// ---------------------------------------------------------------------------
// Fused attention, one block per (q-tile of 16, b*H+h).
// Q/K/V layout (B*H, L, 32) f32. O layout (B*L, 256) f32.
// meanW: atomicAdd of probs/8 into (B,N,N) (caller zero-fills first).
// ---------------------------------------------------------------------------
__global__ __launch_bounds__(256) void attn_k(
    const float* Qb, const float* Kb, const float* Vb,
    float* O, float* meanW, int L, int causal)
{
    __shared__ float S[16 * 512];
    __shared__ float Qt[16 * 32];
    __shared__ float Vt[64 * 32];   // V tile; reused as 2048-float partial buffer
    const int tid = threadIdx.x;
    const int qt = blockIdx.x;
    const int bh = blockIdx.y;
    const int b  = bh >> 3, h = bh & 7;
    const int q0 = qt * 16;
    const float scale = 0.17677669529663687f;  // 1/sqrt(32)
    const int Lpad = (L + 63) & ~63;

    const float* Qh = Qb + (long long)bh * L * HD_;
    const float* Kh = Kb + (long long)bh * L * HD_;
    const float* Vh = Vb + (long long)bh * L * HD_;

    // ---- Q tile -> LDS ----
    if (tid < 128) {
        int rr = tid >> 3, d4 = tid & 7;
        int n = q0 + rr;
        float4 v = make_float4(0.f, 0.f, 0.f, 0.f);
        if (n < L) v = *(const float4*)(Qh + (long long)n * HD_ + d4 * 4);
        *(float4*)(Qt + rr * 32 + d4 * 4) = v;
    }
    __syncthreads();

    // ---- scores: thread handles keys k1=tid, k2=tid+256 ----
    {
        const int k1 = tid, k2 = tid + 256;
        const bool a1 = k1 < L, a2 = k2 < L;
        float4 kr1[8], kr2[8];
        #pragma unroll
        for (int d = 0; d < 8; d++) {
            kr1[d] = make_float4(0.f, 0.f, 0.f, 0.f);
            kr2[d] = make_float4(0.f, 0.f, 0.f, 0.f);
        }
        if (a1) {
            const float4* p = (const float4*)(Kh + (long long)k1 * HD_);
            #pragma unroll
            for (int d = 0; d < 8; d++) kr1[d] = p[d];
        }
        if (a2) {
            const float4* p = (const float4*)(Kh + (long long)k2 * HD_);
            #pragma unroll
            for (int d = 0; d < 8; d++) kr2[d] = p[d];
        }
        const float4* qp = (const float4*)Qt;
        #pragma unroll
        for (int rr = 0; rr < 16; rr++) {
            float s1 = 0.f, s2 = 0.f;
            #pragma unroll
            for (int d = 0; d < 8; d++) {
                float4 qv = qp[rr * 8 + d];
                s1 += qv.x * kr1[d].x + qv.y * kr1[d].y + qv.z * kr1[d].z + qv.w * kr1[d].w;
                s2 += qv.x * kr2[d].x + qv.y * kr2[d].y + qv.z * kr2[d].z + qv.w * kr2[d].w;
            }
            if (a1) {
                float v = s1 * scale;
                if (causal && k1 > q0 + rr) v = -1e9f;
                S[rr * 512 + k1] = v;
            }
            if (a2) {
                float v = s2 * scale;
                if (causal && k2 > q0 + rr) v = -1e9f;
                S[rr * 512 + k2] = v;
            }
        }
    }
    __syncthreads();

    // ---- softmax: wave w owns rows 4w..4w+3; lane-stride-64 (conflict-free) ----
    {
        const int wave = tid >> 6, lane = tid & 63;
        #pragma unroll
        for (int rr4 = 0; rr4 < 4; rr4++) {
            const int rr = wave * 4 + rr4;
            float m = -3e38f;
            for (int k = lane; k < L; k += 64) m = fmaxf(m, S[rr * 512 + k]);
            #pragma unroll
            for (int off = 32; off; off >>= 1) m = fmaxf(m, __shfl_xor(m, off));
            float ps = 0.f;
            for (int k = lane; k < L; k += 64) {
                float e = __expf(S[rr * 512 + k] - m);
                S[rr * 512 + k] = e;
                ps += e;
            }
            #pragma unroll
            for (int off = 32; off; off >>= 1) ps += __shfl_xor(ps, off);
            const float inv = 1.f / ps;
            for (int k = lane; k < L; k += 64) S[rr * 512 + k] *= inv;
            for (int k = L + lane; k < Lpad; k += 64) S[rr * 512 + k] = 0.f;
        }
    }
    __syncthreads();

    // ---- head-mean accumulation (attn 0 only) ----
    if (meanW != nullptr) {
        float* dst = meanW + ((long long)b * N_ + q0) * N_;
        for (int e = tid; e < 16 * 512; e += 256)
            atomicAdd(dst + e, S[e] * 0.125f);
    }

    // ---- PV: thread = (key-quarter kq, row-pair rg, col-quad cg) ----
    const int kq = tid >> 6;           // == wave; all lanes share kq
    const int rg = (tid >> 3) & 7;
    const int cg = tid & 7;
    float acc[2][4] = {};
    for (int c0 = 0; c0 < Lpad; c0 += 64) {
        __syncthreads();
        #pragma unroll
        for (int ii = 0; ii < 2; ii++) {
            int e = tid + ii * 256;          // 512 float4 slots
            int k = c0 + (e >> 3);
            int d4 = e & 7;
            float4 v = make_float4(0.f, 0.f, 0.f, 0.f);
            if (k < L) v = *(const float4*)(Vh + (long long)k * HD_ + d4 * 4);
            *(float4*)(Vt + (e >> 3) * 32 + d4 * 4) = v;
        }
        __syncthreads();
        const int r0 = rg * 2, r1 = r0 + 1;
        #pragma unroll
        for (int i4 = 0; i4 < 4; i4++) {
            const int kkb = kq * 16 + i4 * 4;
            float4 s0 = *(const float4*)(S + r0 * 512 + c0 + kkb);
            float4 s1 = *(const float4*)(S + r1 * 512 + c0 + kkb);
            #pragma unroll
            for (int u = 0; u < 4; u++) {
                float4 vv = *(const float4*)(Vt + (kkb + u) * 32 + cg * 4);
                float w0 = (&s0.x)[u], w1 = (&s1.x)[u];
                acc[0][0] += w0 * vv.x; acc[0][1] += w0 * vv.y;
                acc[0][2] += w0 * vv.z; acc[0][3] += w0 * vv.w;
                acc[1][0] += w1 * vv.x; acc[1][1] += w1 * vv.y;
                acc[1][2] += w1 * vv.z; acc[1][3] += w1 * vv.w;
            }
        }
    }
    __syncthreads();
    #pragma unroll
    for (int r01 = 0; r01 < 2; r01++)
        #pragma unroll
        for (int c = 0; c < 4; c++)
            Vt[kq * 512 + (rg * 2 + r01) * 32 + cg * 4 + c] = acc[r01][c];
    __syncthreads();
    for (int o = tid; o < 512; o += 256) {
        float v = Vt[o] + Vt[512 + o] + Vt[1024 + o] + Vt[1536 + o];
        int r = o >> 5, j = o & 31;
        int n = q0 + r;
        if (n < L) O[((long long)b * L + n) * D_ + h * HD_ + j] = v;
    }
}

// ---------------------------------------------------------------------------
// Small kernels
// ---------------------------------------------------------------------------
__global__ __launch_bounds__(256) void rowsoftmax_k(const float* in, float* out) {
    __shared__ float red[256];
    const long long row = blockIdx.x;
    const int t = threadIdx.x;
    const float* ip = in + row * 2048;
    float* op = out + row * 2048;
    float m = -3e38f;
    for (int k = t; k < 2048; k += 256) m = fmaxf(m, ip[k]);
    red[t] = m; __syncthreads();
    for (int s = 128; s > 0; s >>= 1) { if (t < s) red[t] = fmaxf(red[t], red[t + s]); __syncthreads(); }
    m = red[0]; __syncthreads();
    float ps = 0.f;
    for (int k = t; k < 2048; k += 256) { float e = __expf(ip[k] - m); op[k] = e; ps += e; }
    red[t] = ps; __syncthreads();
    for (int s = 128; s > 0; s >>= 1) { if (t < s) red[t] += red[t + s]; __syncthreads(); }
    const float inv = 1.f / red[0];
    for (int k = t; k < 2048; k += 256) op[k] *= inv;
}

__global__ void embed_k(const int* q, const int* r, const int* qry,
                        const float* Memb, const float* Eemb, const float* P,
                        float* M, float* E) {
    const int i = blockIdx.x; const int t = threadIdx.x;
    const int n = i & (N_ - 1);
    const int x = q[i] + 2048 * r[i];
    M[(long long)i * D_ + t] = Memb[(long long)x * D_ + t] + P[(long long)n * D_ + t];
    E[(long long)i * D_ + t] = Eemb[(long long)qry[i] * D_ + t];
}

__global__ void gather_k(const int* q, const float* T, float* G) {
    const int i = blockIdx.x; const int t = threadIdx.x;
    G[(long long)i * D_ + t] = T[(long long)q[i] * D_ + t];
}

__global__ __launch_bounds__(256) void ln_k(const float* xa, const float* xb, const float* xc,
                                            const float* g, const float* bta,
                                            float* out1, float* out2) {
    __shared__ float red[256];
    const long long row = blockIdx.x;
    const int t = threadIdx.x;
    float v = xa[row * D_ + t];
    if (xb) v += xb[row * D_ + t];
    if (xc) v += xc[row * D_ + t];
    red[t] = v; __syncthreads();
    for (int s = 128; s > 0; s >>= 1) { if (t < s) red[t] += red[t + s]; __syncthreads(); }
    const float mean = red[0] * (1.f / 256.f);
    __syncthreads();
    const float d = v - mean;
    red[t] = d * d; __syncthreads();
    for (int s = 128; s > 0; s >>= 1) { if (t < s) red[t] += red[t + s]; __syncthreads(); }
    const float var = red[0] * (1.f / 256.f);
    const float y = d * rsqrtf(var + 1e-5f) * g[t] + bta[t];
    out1[row * D_ + t] = y;
    if (out2) out2[row * D_ + t] = y;
}

__global__ void scatterlocal_k(const float* tail, float* Slocal, float* Sacc) {
    const int i = blockIdx.x; const int t = threadIdx.x;
    const int n = i & (N_ - 1), b = i >> 9;
    float v = 0.f;
    if (n >= N_ - LW_) {
        v = tail[((long long)(b * LW_ + (n - (N_ - LW_)))) * D_ + t];
        Sacc[(long long)i * D_ + t] += v;
    }
    Slocal[(long long)i * D_ + t] = v;
}

__global__ void add_k(float* dst, const float* src) {
    const long long i = (long long)blockIdx.x * 256 + threadIdx.x;
    dst[i] += src[i];
}

__global__ void zero4_k(float4* p) {
    p[(long long)blockIdx.x * 256 + threadIdx.x] = make_float4(0.f, 0.f, 0.f, 0.f);
}

__global__ __launch_bounds__(256) void pred_k(const float* F, const float* pw, const float* pb,
                                              float* out) {
    const int tid = threadIdx.x;
    const int wave = tid >> 6, lane = tid & 63;
    const long long row = (long long)blockIdx.x * 4 + wave;
    const float* fp = F + row * D_ + lane * 4;
    float s = 0.f;
    #pragma unroll
    for (int j = 0; j < 4; j++) s += fp[j] * pw[lane * 4 + j];
    #pragma unroll
    for (int off = 32; off > 0; off >>= 1) s += __shfl_down(s, off);
    if (lane == 0) {
        float p = 1.f / (1.f + __expf(-(s + pb[0])));
        out[row] = p;
    }
}

// ---------------------------------------------------------------------------
static void gemm(hipStream_t st, const float* Aq, const float* Akv,
                 const float* W, const float* bias, float* C,
                 int M, int K, int Onum, int rowsPerA, long long aBatch,
                 long long aZ, long long wZ, long long cZ, int Z,
                 int qkv, int flags, float* Qd, float* Kd, float* Vd, int Lseq)
{
    dim3 g((Onum + BO - 1) / BO, (M + BM - 1) / BM, Z), blk(256, 1, 1);
    gemm_k<<<g, blk, 0, st>>>(Aq, Akv, W, bias, C, M, K, Onum, rowsPerA, aBatch,
                              aZ, wZ, cZ, qkv, flags, Qd, Kd, Vd, Lseq);
}

extern "C" void kernel_launch(void* const* d_in, const int* in_sizes, int n_in,
                              void* d_out, int out_size, void* d_ws, size_t ws_size,
                              hipStream_t stream)
{
    const int* qi  = (const int*)d_in[0];
    const int* ri  = (const int*)d_in[1];
    const int* qry = (const int*)d_in[2];
    const float* Memb = (const float*)d_in[3];
    const float* Eemb = (const float*)d_in[4];
    const float* Pp   = (const float*)d_in[5];
    const float* ainw = (const float*)d_in[6];
    const float* ainb = (const float*)d_in[7];
    const float* aoutw= (const float*)d_in[8];
    const float* aoutb= (const float*)d_in[9];
    const float* scw  = (const float*)d_in[10];
    const float* spw  = (const float*)d_in[11];
    const float* spb  = (const float*)d_in[12];
    const float* stew = (const float*)d_in[13];
    const float* steb = (const float*)d_in[14];
    const float* fw1  = (const float*)d_in[15];
    const float* fb1  = (const float*)d_in[16];
    const float* fw2  = (const float*)d_in[17];
    const float* fb2  = (const float*)d_in[18];
    const float* l1g  = (const float*)d_in[19];
    const float* l1b  = (const float*)d_in[20];
    const float* l2g  = (const float*)d_in[21];
    const float* l2b  = (const float*)d_in[22];
    const float* pw   = (const float*)d_in[23];
    const float* pb   = (const float*)d_in[24];
    float* out = (float*)d_out;
    float* outW = out + B_ * N_;   // attn-weights output region (f32)

    float* ws = (float*)d_ws;
    const size_t BND = (size_t)B_ * N_ * D_;   // 4,194,304 floats
    float* b0  = ws + 0 * BND;   // SW -> M -> FFNout
    float* b1  = ws + 1 * BND;   // E -> G -> F
    float* b2  = ws + 2 * BND;   // S_base
    float* b3  = ws + 3 * BND;   // Q
    float* b4  = ws + 4 * BND;   // K
    float* b5  = ws + 5 * BND;   // V
    float* b6  = ws + 6 * BND;   // O (attn out, pre-proj)
    float* b7  = ws + 7 * BND;   // S_local (padded)
    float* b8  = ws + 8 * BND;   // S_sg
    float* b9  = ws + 9 * BND;   // S_glob
    float* b10 = ws + 10 * BND;  // S accumulator
    float* b11 = ws + 11 * BND;  // S_sg-pre / FFN hidden
    float* BNN = ws + 12 * BND;               // (B,N,N) f32 scratch
    float* Ttab = BNN + (size_t)B_ * N_ * N_; // (2048, 256) f32
    const int BNrows = B_ * N_;               // 16384
    const int BH = B_ * H_;                   // 256

    // --- skill table: T = softmax(scw) @ spw^T + spb ---
    rowsoftmax_k<<<2048, 256, 0, stream>>>(scw, b0);
    gemm(stream, b0, b0, spw, spb, Ttab, 2048, 2048, 256, 2048, 0, 0, 0, 0, 1,
         0, 0, nullptr, nullptr, nullptr, 0);

    // --- embeddings: M = M_emb[q + 2048 r] + P ; E = E_emb[qry] ---
    embed_k<<<BNrows, 256, 0, stream>>>(qi, ri, qry, Memb, Eemb, Pp, b0, b1);

    // --- attn 0: q=E, kv=M, causal, mean weights -> out (atomic) ---
    zero4_k<<<(B_ * N_ * N_) / 1024, 256, 0, stream>>>((float4*)outW);
    gemm(stream, b1, b0, ainw + 0, ainb + 0, nullptr, BNrows, 256, 768, BNrows, 0,
         0, 0, 0, 1, 1, 0, b3, b4, b5, N_);
    attn_k<<<dim3(32, BH), 256, 0, stream>>>(b3, b4, b5, b6, outW, N_, 1);
    gemm(stream, b6, b6, aoutw + 0, aoutb + 0, b10, BNrows, 256, 256, BNrows, 0,
         0, 0, 0, 1, 0, 0, nullptr, nullptr, nullptr, 0);
    // S_base = LN1(proj + M + E)  (also init accumulator)
    ln_k<<<BNrows, 256, 0, stream>>>(b10, b0, b1, l1g, l1b, b2, b10);

    // --- attn 1 (local, LW=25, causal) on S_base[:, -25:, :] ---
    gemm(stream, b2 + (N_ - LW_) * D_, b2 + (N_ - LW_) * D_,
         ainw + 1 * 768 * 256, ainb + 768, nullptr, B_ * LW_, 256, 768,
         LW_, (long long)N_ * D_, 0, 0, 0, 1, 1, 0, b3, b4, b5, LW_);
    attn_k<<<dim3(2, BH), 256, 0, stream>>>(b3, b4, b5, b6, nullptr, LW_, 1);
    gemm(stream, b6, b6, aoutw + 1 * 65536, aoutb + 256, BNN, B_ * LW_, 256, 256,
         B_ * LW_, 0, 0, 0, 0, 1, 0, 0, nullptr, nullptr, nullptr, 0);
    scatterlocal_k<<<BNrows, 256, 0, stream>>>(BNN, b7, b10);

    // --- skill group path ---
    gather_k<<<BNrows, 256, 0, stream>>>(qi, Ttab, b1);   // G
    gemm(stream, b2, b2, b1, nullptr, BNN, N_, 256, N_, N_, 0,
         (long long)N_ * D_, (long long)N_ * D_, (long long)N_ * N_, B_,
         0, 0, nullptr, nullptr, nullptr, 0);
    gemm(stream, BNN, BNN, stew, steb, b11, BNrows, 512, 256, BNrows, 0,
         0, 0, 0, 1, 0, 0, nullptr, nullptr, nullptr, 0);
    gemm(stream, b11, b11, ainw + 2 * 196608, ainb + 2 * 768, nullptr, BNrows, 256, 768,
         BNrows, 0, 0, 0, 0, 1, 1, 0, b3, b4, b5, N_);
    attn_k<<<dim3(32, BH), 256, 0, stream>>>(b3, b4, b5, b6, nullptr, N_, 0);
    gemm(stream, b6, b6, aoutw + 2 * 65536, aoutb + 2 * 256, b8, BNrows, 256, 256,
         BNrows, 0, 0, 0, 0, 1, 0, 0, nullptr, nullptr, nullptr, 0);
    add_k<<<BNrows, 256, 0, stream>>>(b10, b8);

    // --- attn 3: self on S_base, causal -> S_glob ---
    gemm(stream, b2, b2, ainw + 3 * 196608, ainb + 3 * 768, nullptr, BNrows, 256, 768,
         BNrows, 0, 0, 0, 0, 1, 1, 0, b3, b4, b5, N_);
    attn_k<<<dim3(32, BH), 256, 0, stream>>>(b3, b4, b5, b6, nullptr, N_, 1);
    gemm(stream, b6, b6, aoutw + 3 * 65536, aoutb + 3 * 256, b9, BNrows, 256, 256,
         BNrows, 0, 0, 0, 0, 1, 0, 0, nullptr, nullptr, nullptr, 0);
    add_k<<<BNrows, 256, 0, stream>>>(b10, b9);

    // --- attn 4: q=S_base, kv=S_local, no mask -> accumulate ---
    gemm(stream, b2, b7, ainw + 4 * 196608, ainb + 4 * 768, nullptr, BNrows, 256, 768,
         BNrows, 0, 0, 0, 0, 1, 1, 0, b3, b4, b5, N_);
    attn_k<<<dim3(32, BH), 256, 0, stream>>>(b3, b4, b5, b6, nullptr, N_, 0);
    gemm(stream, b6, b6, aoutw + 4 * 65536, aoutb + 4 * 256, b10, BNrows, 256, 256,
         BNrows, 0, 0, 0, 0, 1, 0, 2, nullptr, nullptr, nullptr, 0);

    // --- attn 5: q=S_sg, kv=S_glob, no mask -> accumulate ---
    gemm(stream, b8, b9, ainw + 5 * 196608, ainb + 5 * 768, nullptr, BNrows, 256, 768,
         BNrows, 0, 0, 0, 0, 1, 1, 0, b3, b4, b5, N_);
    attn_k<<<dim3(32, BH), 256, 0, stream>>>(b3, b4, b5, b6, nullptr, N_, 0);
    gemm(stream, b6, b6, aoutw + 5 * 65536, aoutb + 5 * 256, b10, BNrows, 256, 256,
         BNrows, 0, 0, 0, 0, 1, 0, 2, nullptr, nullptr, nullptr, 0);

    // --- FFN + LN2 + prediction ---
    gemm(stream, b10, b10, fw1, fb1, b11, BNrows, 256, 256, BNrows, 0,
         0, 0, 0, 1, 0, 1, nullptr, nullptr, nullptr, 0);
    gemm(stream, b11, b11, fw2, fb2, b0, BNrows, 256, 256, BNrows, 0,
         0, 0, 0, 1, 0, 0, nullptr, nullptr, nullptr, 0);
    ln_k<<<BNrows, 256, 0, stream>>>(b0, b10, nullptr, l2g, l2b, b1, nullptr);
    pred_k<<<BNrows / 4, 256, 0, stream>>>(b1, pw, pb, out);
}

// Round 4
// 2370.582 us; speedup vs baseline: 3.1956x; 1.3746x over previous
//
#include <hip/hip_runtime.h>
#include <hip/hip_bf16.h>

#define B_  32
#define N_  512
#define D_  256
#define H_  8
#define HD_ 32
#define LW_ 25

typedef __attribute__((ext_vector_type(8))) short short8;
typedef __attribute__((ext_vector_type(4))) float f32x4;

// ---------------------------------------------------------------------------
// Generic tiled GEMM: C[m,o] = sum_k A[m,k] * W[o,k] (+bias) ; all f32
// qkvmode: scatter outputs to bf16 Q (BH,L,32), K (BH,L,32), V^T (BH,32,Lvt)
// ---------------------------------------------------------------------------
#define BM 64
#define BO 64
#define BK 32

__global__ __launch_bounds__(256) void gemm_k(
    const float* Aq, const float* Akv,
    const float* W, const float* bias, float* C,
    int M, int K, int Onum,
    int rowsPerA, long long aBatch,
    long long aZ, long long wZ, long long cZ,
    int qkvmode, int flags,
    __hip_bfloat16* Qd, __hip_bfloat16* Kd, __hip_bfloat16* Vd,
    int Lseq, int Lvt)
{
    __shared__ __align__(16) float As[BK][BM + 4];
    __shared__ __align__(16) float Ws[BK][BO + 4];
    const int tid = threadIdx.x;
    const int o0 = blockIdx.x * BO;
    const int m0 = blockIdx.y * BM;
    const int z  = blockIdx.z;
    const float* A = (qkvmode && o0 >= 256) ? Akv : Aq;
    A += (long long)z * aZ;
    if (C) C += (long long)z * cZ;
    const long long wzoff = (long long)z * wZ;

    const int tx = tid & 15, ty = tid >> 4;
    float acc[4][4] = {};

    for (int k0 = 0; k0 < K; k0 += BK) {
        #pragma unroll
        for (int i = 0; i < 8; i++) {
            int e = tid + i * 256;
            int kk = e & 31, mm = e >> 5;
            int m = m0 + mm;
            float v = 0.f;
            if (m < M) {
                long long row = (long long)(m / rowsPerA) * aBatch +
                                (long long)(m % rowsPerA) * K;
                v = A[row + k0 + kk];
            }
            As[kk][mm] = v;
        }
        #pragma unroll
        for (int i = 0; i < 8; i++) {
            int e = tid + i * 256;
            int kk = e & 31, oo = e >> 5;
            long long idx = wzoff + (long long)(o0 + oo) * K + k0 + kk;
            Ws[kk][oo] = W[idx];
        }
        __syncthreads();
        #pragma unroll
        for (int kk = 0; kk < BK; kk++) {
            float4 a4 = *(const float4*)&As[kk][ty * 4];
            float4 w4 = *(const float4*)&Ws[kk][tx * 4];
            float a[4] = {a4.x, a4.y, a4.z, a4.w};
            float w[4] = {w4.x, w4.y, w4.z, w4.w};
            #pragma unroll
            for (int i = 0; i < 4; i++)
                #pragma unroll
                for (int j = 0; j < 4; j++)
                    acc[i][j] += a[i] * w[j];
        }
        __syncthreads();
    }

    #pragma unroll
    for (int i = 0; i < 4; i++) {
        int m = m0 + ty * 4 + i;
        if (m >= M) continue;
        #pragma unroll
        for (int j = 0; j < 4; j++) {
            int o = o0 + tx * 4 + j;
            if (o >= Onum) continue;
            float v = acc[i][j];
            if (bias) v += bias[o];
            if (flags & 1) v = fmaxf(v, 0.f);
            if (!qkvmode) {
                long long ci = (long long)m * Onum + o;
                if (flags & 2) C[ci] += v; else C[ci] = v;
            } else {
                int which = o >> 8;
                int oo = o & 255;
                int hh = oo >> 5, j2 = oo & 31;
                int bb = m / Lseq, nn = m % Lseq;
                int bh = bb * H_ + hh;
                __hip_bfloat16 hv = __float2bfloat16(v);
                if (which == 0)
                    Qd[((size_t)bh * Lseq + nn) * HD_ + j2] = hv;
                else if (which == 1)
                    Kd[((size_t)bh * Lseq + nn) * HD_ + j2] = hv;
                else
                    Vd[((size_t)bh * HD_ + j2) * Lvt + nn] = hv;
            }
        }
    }
}

// ---------------------------------------------------------------------------
// MFMA fused attention. Block = (q-tile of 16, b*H+h), 4 waves.
// Q,K: (BH, L, 32) bf16.  Vt: (BH, 32, Lvt) bf16 (transposed).
// O: (B*L, 256) f32. meanW: atomicAdd probs/8 into (B,N,N) (pre-zeroed).
// A-frag: A[m=lane&15][k=quad*8+j]; B-frag: B[k=quad*8+j][n=lane&15];
// C/D: row=quad*4+reg, col=lane&15.   (16x16x32 bf16)
// ---------------------------------------------------------------------------
#define SROW 516
#define OPS  34

__global__ __launch_bounds__(256) void attn_k(
    const __hip_bfloat16* Qb, const __hip_bfloat16* Kb, const __hip_bfloat16* Vtb,
    float* O, float* meanW, int L, int Lvt, int causal)
{
    __shared__ float S[16 * SROW];   // 33 KB; reused for O-partials
    const int tid  = threadIdx.x;
    const int w    = tid >> 6, lane = tid & 63;
    const int col  = lane & 15, quad = lane >> 4;
    const int qt = blockIdx.x, bh = blockIdx.y;
    const int b  = bh >> 3, h = bh & 7;
    const int q0 = qt * 16;
    const int NT = (L + 15) >> 4;
    const int NC = (L + 31) >> 5;
    const int Lc = NC * 32;
    const float scale = 0.17677669529663687f;  // 1/sqrt(32)

    const __hip_bfloat16* Qh = Qb  + (size_t)bh * L * HD_;
    const __hip_bfloat16* Kh = Kb  + (size_t)bh * L * HD_;
    const __hip_bfloat16* Vh = Vtb + (size_t)bh * HD_ * Lvt;

    // ---- Q A-fragment (direct global, L1-served) ----
    short8 aq = (short8)(short)0;
    if (q0 + col < L)
        aq = *(const short8*)(Qh + (size_t)(q0 + col) * HD_ + quad * 8);

    // ---- QK^T: wave w does tiles kt = w, w+4, ... (16 keys each) ----
    f32x4 sc[8];
    #pragma unroll
    for (int t = 0; t < 8; t++) sc[t] = (f32x4)0.f;
    #pragma unroll
    for (int t = 0; t < 8; t++) {
        int kt = w + 4 * t;
        if (kt >= NT) break;
        int key = kt * 16 + col;
        short8 bk = (short8)(short)0;
        if (key < L)
            bk = *(const short8*)(Kh + (size_t)key * HD_ + quad * 8);
        sc[t] = __builtin_amdgcn_mfma_f32_16x16x32_bf16(aq, bk, sc[t], 0, 0, 0);
    }
    // ---- scale + causal mask + store to LDS ----
    #pragma unroll
    for (int t = 0; t < 8; t++) {
        int kt = w + 4 * t;
        if (kt >= NT) break;
        int kk = kt * 16 + col;
        #pragma unroll
        for (int r = 0; r < 4; r++) {
            int row = quad * 4 + r;
            float v = sc[t][r] * scale;
            if (causal && kk > q0 + row) v = -1e9f;
            S[row * SROW + kk] = v;
        }
    }
    __syncthreads();

    // ---- softmax: wave w owns rows 4w..4w+3, lane-stride 64 ----
    #pragma unroll
    for (int r4 = 0; r4 < 4; r4++) {
        const int row = w * 4 + r4;
        float* Sr = S + row * SROW;
        float m = -3e38f;
        for (int k = lane; k < L; k += 64) m = fmaxf(m, Sr[k]);
        #pragma unroll
        for (int off = 32; off; off >>= 1) m = fmaxf(m, __shfl_xor(m, off));
        float ps = 0.f;
        for (int k = lane; k < L; k += 64) {
            float e = __expf(Sr[k] - m);
            Sr[k] = e;
            ps += e;
        }
        #pragma unroll
        for (int off = 32; off; off >>= 1) ps += __shfl_xor(ps, off);
        const float inv = 1.f / ps;
        for (int k = lane; k < L; k += 64) Sr[k] *= inv;
        for (int k = L + lane; k < Lc; k += 64) Sr[k] = 0.f;  // zero pad for PV
    }
    __syncthreads();

    // ---- head-mean accumulation (attn 0 only) ----
    if (meanW != nullptr) {
        float* dst = meanW + ((size_t)b * N_ + q0) * N_;
        for (int e = tid; e < 16 * 512; e += 256) {
            int row = e >> 9, k = e & 511;
            atomicAdd(dst + e, S[row * SROW + k] * 0.125f);
        }
    }

    // ---- PV: wave w does chunks c = w, w+4, ... (32 keys each) ----
    f32x4 oacc[2];
    oacc[0] = (f32x4)0.f; oacc[1] = (f32x4)0.f;
    #pragma unroll
    for (int cc = 0; cc < 4; cc++) {
        int c = w + 4 * cc;
        if (c >= NC) break;
        const float* Sp = S + col * SROW + c * 32 + quad * 8;
        f32x4 p0 = *(const f32x4*)Sp;
        f32x4 p1 = *(const f32x4*)(Sp + 4);
        short8 ap;
        #pragma unroll
        for (int j = 0; j < 4; j++) {
            ap[j]     = __builtin_bit_cast(short, __float2bfloat16(p0[j]));
            ap[j + 4] = __builtin_bit_cast(short, __float2bfloat16(p1[j]));
        }
        #pragma unroll
        for (int hf = 0; hf < 2; hf++) {
            const short8 bv = *(const short8*)(Vh + (size_t)(hf * 16 + col) * Lvt
                                               + c * 32 + quad * 8);
            oacc[hf] = __builtin_amdgcn_mfma_f32_16x16x32_bf16(ap, bv, oacc[hf], 0, 0, 0);
        }
    }
    __syncthreads();   // all waves done reading S

    // ---- cross-wave O reduction (reuse S as [4][16][OPS]) ----
    #pragma unroll
    for (int hf = 0; hf < 2; hf++)
        #pragma unroll
        for (int r = 0; r < 4; r++)
            S[w * (16 * OPS) + (quad * 4 + r) * OPS + hf * 16 + col] = oacc[hf][r];
    __syncthreads();
    for (int e = tid; e < 512; e += 256) {
        int row = e >> 5, d = e & 31;
        float v = S[row * OPS + d] + S[544 + row * OPS + d] +
                  S[1088 + row * OPS + d] + S[1632 + row * OPS + d];
        int n = q0 + row;
        if (n < L) O[((size_t)b * L + n) * D_ + h * HD_ + d] = v;
    }
}

// ---------------------------------------------------------------------------
// Small kernels
// ---------------------------------------------------------------------------
__global__ __launch_bounds__(256) void rowsoftmax_k(const float* in, float* out) {
    __shared__ float red[256];
    const long long row = blockIdx.x;
    const int t = threadIdx.x;
    const float* ip = in + row * 2048;
    float* op = out + row * 2048;
    float m = -3e38f;
    for (int k = t; k < 2048; k += 256) m = fmaxf(m, ip[k]);
    red[t] = m; __syncthreads();
    for (int s = 128; s > 0; s >>= 1) { if (t < s) red[t] = fmaxf(red[t], red[t + s]); __syncthreads(); }
    m = red[0]; __syncthreads();
    float ps = 0.f;
    for (int k = t; k < 2048; k += 256) { float e = __expf(ip[k] - m); op[k] = e; ps += e; }
    red[t] = ps; __syncthreads();
    for (int s = 128; s > 0; s >>= 1) { if (t < s) red[t] += red[t + s]; __syncthreads(); }
    const float inv = 1.f / red[0];
    for (int k = t; k < 2048; k += 256) op[k] *= inv;
}

__global__ void embed_k(const int* q, const int* r, const int* qry,
                        const float* Memb, const float* Eemb, const float* P,
                        float* M, float* E) {
    const int i = blockIdx.x; const int t = threadIdx.x;
    const int n = i & (N_ - 1);
    const int x = q[i] + 2048 * r[i];
    M[(long long)i * D_ + t] = Memb[(long long)x * D_ + t] + P[(long long)n * D_ + t];
    E[(long long)i * D_ + t] = Eemb[(long long)qry[i] * D_ + t];
}

__global__ void gather_k(const int* q, const float* T, float* G) {
    const int i = blockIdx.x; const int t = threadIdx.x;
    G[(long long)i * D_ + t] = T[(long long)q[i] * D_ + t];
}

__global__ __launch_bounds__(256) void ln_k(const float* xa, const float* xb, const float* xc,
                                            const float* g, const float* bta,
                                            float* out1, float* out2) {
    __shared__ float red[256];
    const long long row = blockIdx.x;
    const int t = threadIdx.x;
    float v = xa[row * D_ + t];
    if (xb) v += xb[row * D_ + t];
    if (xc) v += xc[row * D_ + t];
    red[t] = v; __syncthreads();
    for (int s = 128; s > 0; s >>= 1) { if (t < s) red[t] += red[t + s]; __syncthreads(); }
    const float mean = red[0] * (1.f / 256.f);
    __syncthreads();
    const float d = v - mean;
    red[t] = d * d; __syncthreads();
    for (int s = 128; s > 0; s >>= 1) { if (t < s) red[t] += red[t + s]; __syncthreads(); }
    const float var = red[0] * (1.f / 256.f);
    const float y = d * rsqrtf(var + 1e-5f) * g[t] + bta[t];
    out1[row * D_ + t] = y;
    if (out2) out2[row * D_ + t] = y;
}

__global__ void scatterlocal_k(const float* tail, float* Slocal, float* Sacc) {
    const int i = blockIdx.x; const int t = threadIdx.x;
    const int n = i & (N_ - 1), b = i >> 9;
    float v = 0.f;
    if (n >= N_ - LW_) {
        v = tail[((long long)(b * LW_ + (n - (N_ - LW_)))) * D_ + t];
        Sacc[(long long)i * D_ + t] += v;
    }
    Slocal[(long long)i * D_ + t] = v;
}

__global__ void add_k(float* dst, const float* src) {
    const long long i = (long long)blockIdx.x * 256 + threadIdx.x;
    dst[i] += src[i];
}

__global__ void zero4_k(float4* p) {
    p[(long long)blockIdx.x * 256 + threadIdx.x] = make_float4(0.f, 0.f, 0.f, 0.f);
}

__global__ __launch_bounds__(256) void pred_k(const float* F, const float* pw, const float* pb,
                                              float* out) {
    const int tid = threadIdx.x;
    const int wave = tid >> 6, lane = tid & 63;
    const long long row = (long long)blockIdx.x * 4 + wave;
    const float* fp = F + row * D_ + lane * 4;
    float s = 0.f;
    #pragma unroll
    for (int j = 0; j < 4; j++) s += fp[j] * pw[lane * 4 + j];
    #pragma unroll
    for (int off = 32; off > 0; off >>= 1) s += __shfl_down(s, off);
    if (lane == 0) {
        float p = 1.f / (1.f + __expf(-(s + pb[0])));
        out[row] = p;
    }
}

// ---------------------------------------------------------------------------
static void gemm(hipStream_t st, const float* Aq, const float* Akv,
                 const float* W, const float* bias, float* C,
                 int M, int K, int Onum, int rowsPerA, long long aBatch,
                 long long aZ, long long wZ, long long cZ, int Z,
                 int qkv, int flags,
                 __hip_bfloat16* Qd, __hip_bfloat16* Kd, __hip_bfloat16* Vd,
                 int Lseq, int Lvt)
{
    dim3 g((Onum + BO - 1) / BO, (M + BM - 1) / BM, Z), blk(256, 1, 1);
    gemm_k<<<g, blk, 0, st>>>(Aq, Akv, W, bias, C, M, K, Onum, rowsPerA, aBatch,
                              aZ, wZ, cZ, qkv, flags, Qd, Kd, Vd, Lseq, Lvt);
}

extern "C" void kernel_launch(void* const* d_in, const int* in_sizes, int n_in,
                              void* d_out, int out_size, void* d_ws, size_t ws_size,
                              hipStream_t stream)
{
    const int* qi  = (const int*)d_in[0];
    const int* ri  = (const int*)d_in[1];
    const int* qry = (const int*)d_in[2];
    const float* Memb = (const float*)d_in[3];
    const float* Eemb = (const float*)d_in[4];
    const float* Pp   = (const float*)d_in[5];
    const float* ainw = (const float*)d_in[6];
    const float* ainb = (const float*)d_in[7];
    const float* aoutw= (const float*)d_in[8];
    const float* aoutb= (const float*)d_in[9];
    const float* scw  = (const float*)d_in[10];
    const float* spw  = (const float*)d_in[11];
    const float* spb  = (const float*)d_in[12];
    const float* stew = (const float*)d_in[13];
    const float* steb = (const float*)d_in[14];
    const float* fw1  = (const float*)d_in[15];
    const float* fb1  = (const float*)d_in[16];
    const float* fw2  = (const float*)d_in[17];
    const float* fb2  = (const float*)d_in[18];
    const float* l1g  = (const float*)d_in[19];
    const float* l1b  = (const float*)d_in[20];
    const float* l2g  = (const float*)d_in[21];
    const float* l2b  = (const float*)d_in[22];
    const float* pw   = (const float*)d_in[23];
    const float* pb   = (const float*)d_in[24];
    float* out = (float*)d_out;
    float* outW = out + B_ * N_;   // attn-weights output region (f32)

    float* ws = (float*)d_ws;
    const size_t BND = (size_t)B_ * N_ * D_;   // 4,194,304 floats
    float* b0  = ws + 0 * BND;   // SW -> M -> FFNout
    float* b1  = ws + 1 * BND;   // E -> G -> F
    float* b2  = ws + 2 * BND;   // S_base
    float* b3  = ws + 3 * BND;   // Q (bf16)
    float* b4  = ws + 4 * BND;   // K (bf16)
    float* b5  = ws + 5 * BND;   // V^T (bf16)
    float* b6  = ws + 6 * BND;   // O (attn out, pre-proj, f32)
    float* b7  = ws + 7 * BND;   // S_local (padded)
    float* b8  = ws + 8 * BND;   // S_sg
    float* b9  = ws + 9 * BND;   // S_glob
    float* b10 = ws + 10 * BND;  // S accumulator
    float* b11 = ws + 11 * BND;  // S_sg-pre / FFN hidden
    float* BNN = ws + 12 * BND;               // (B,N,N) f32 scratch
    float* Ttab = BNN + (size_t)B_ * N_ * N_; // (2048, 256) f32
    const int BNrows = B_ * N_;               // 16384
    const int BH = B_ * H_;                   // 256
    __hip_bfloat16* Qb  = (__hip_bfloat16*)b3;
    __hip_bfloat16* Kb  = (__hip_bfloat16*)b4;
    __hip_bfloat16* Vtb = (__hip_bfloat16*)b5;

    // --- skill table: T = softmax(scw) @ spw^T + spb ---
    rowsoftmax_k<<<2048, 256, 0, stream>>>(scw, b0);
    gemm(stream, b0, b0, spw, spb, Ttab, 2048, 2048, 256, 2048, 0, 0, 0, 0, 1,
         0, 0, nullptr, nullptr, nullptr, 0, 0);

    // --- embeddings: M = M_emb[q + 2048 r] + P ; E = E_emb[qry] ---
    embed_k<<<BNrows, 256, 0, stream>>>(qi, ri, qry, Memb, Eemb, Pp, b0, b1);

    // --- attn 0: q=E, kv=M, causal, mean weights -> out (atomic) ---
    zero4_k<<<(B_ * N_ * N_) / 1024, 256, 0, stream>>>((float4*)outW);
    gemm(stream, b1, b0, ainw + 0, ainb + 0, nullptr, BNrows, 256, 768, BNrows, 0,
         0, 0, 0, 1, 1, 0, Qb, Kb, Vtb, N_, N_);
    attn_k<<<dim3(32, BH), 256, 0, stream>>>(Qb, Kb, Vtb, b6, outW, N_, N_, 1);
    gemm(stream, b6, b6, aoutw + 0, aoutb + 0, b10, BNrows, 256, 256, BNrows, 0,
         0, 0, 0, 1, 0, 0, nullptr, nullptr, nullptr, 0, 0);
    // S_base = LN1(proj + M + E)  (also init accumulator)
    ln_k<<<BNrows, 256, 0, stream>>>(b10, b0, b1, l1g, l1b, b2, b10);

    // --- attn 1 (local, LW=25, causal) on S_base[:, -25:, :] ---
    gemm(stream, b2 + (N_ - LW_) * D_, b2 + (N_ - LW_) * D_,
         ainw + 1 * 768 * 256, ainb + 768, nullptr, B_ * LW_, 256, 768,
         LW_, (long long)N_ * D_, 0, 0, 0, 1, 1, 0, Qb, Kb, Vtb, LW_, 32);
    attn_k<<<dim3(2, BH), 256, 0, stream>>>(Qb, Kb, Vtb, b6, nullptr, LW_, 32, 1);
    gemm(stream, b6, b6, aoutw + 1 * 65536, aoutb + 256, BNN, B_ * LW_, 256, 256,
         B_ * LW_, 0, 0, 0, 0, 1, 0, 0, nullptr, nullptr, nullptr, 0, 0);
    scatterlocal_k<<<BNrows, 256, 0, stream>>>(BNN, b7, b10);

    // --- skill group path ---
    gather_k<<<BNrows, 256, 0, stream>>>(qi, Ttab, b1);   // G
    gemm(stream, b2, b2, b1, nullptr, BNN, N_, 256, N_, N_, 0,
         (long long)N_ * D_, (long long)N_ * D_, (long long)N_ * N_, B_,
         0, 0, nullptr, nullptr, nullptr, 0, 0);
    gemm(stream, BNN, BNN, stew, steb, b11, BNrows, 512, 256, BNrows, 0,
         0, 0, 0, 1, 0, 0, nullptr, nullptr, nullptr, 0, 0);
    gemm(stream, b11, b11, ainw + 2 * 196608, ainb + 2 * 768, nullptr, BNrows, 256, 768,
         BNrows, 0, 0, 0, 0, 1, 1, 0, Qb, Kb, Vtb, N_, N_);
    attn_k<<<dim3(32, BH), 256, 0, stream>>>(Qb, Kb, Vtb, b6, nullptr, N_, N_, 0);
    gemm(stream, b6, b6, aoutw + 2 * 65536, aoutb + 2 * 256, b8, BNrows, 256, 256,
         BNrows, 0, 0, 0, 0, 1, 0, 0, nullptr, nullptr, nullptr, 0, 0);
    add_k<<<BNrows, 256, 0, stream>>>(b10, b8);

    // --- attn 3: self on S_base, causal -> S_glob ---
    gemm(stream, b2, b2, ainw + 3 * 196608, ainb + 3 * 768, nullptr, BNrows, 256, 768,
         BNrows, 0, 0, 0, 0, 1, 1, 0, Qb, Kb, Vtb, N_, N_);
    attn_k<<<dim3(32, BH), 256, 0, stream>>>(Qb, Kb, Vtb, b6, nullptr, N_, N_, 1);
    gemm(stream, b6, b6, aoutw + 3 * 65536, aoutb + 3 * 256, b9, BNrows, 256, 256,
         BNrows, 0, 0, 0, 0, 1, 0, 0, nullptr, nullptr, nullptr, 0, 0);
    add_k<<<BNrows, 256, 0, stream>>>(b10, b9);

    // --- attn 4: q=S_base, kv=S_local, no mask -> accumulate ---
    gemm(stream, b2, b7, ainw + 4 * 196608, ainb + 4 * 768, nullptr, BNrows, 256, 768,
         BNrows, 0, 0, 0, 0, 1, 1, 0, Qb, Kb, Vtb, N_, N_);
    attn_k<<<dim3(32, BH), 256, 0, stream>>>(Qb, Kb, Vtb, b6, nullptr, N_, N_, 0);
    gemm(stream, b6, b6, aoutw + 4 * 65536, aoutb + 4 * 256, b10, BNrows, 256, 256,
         BNrows, 0, 0, 0, 0, 1, 0, 2, nullptr, nullptr, nullptr, 0, 0);

    // --- attn 5: q=S_sg, kv=S_glob, no mask -> accumulate ---
    gemm(stream, b8, b9, ainw + 5 * 196608, ainb + 5 * 768, nullptr, BNrows, 256, 768,
         BNrows, 0, 0, 0, 0, 1, 1, 0, Qb, Kb, Vtb, N_, N_);
    attn_k<<<dim3(32, BH), 256, 0, stream>>>(Qb, Kb, Vtb, b6, nullptr, N_, N_, 0);
    gemm(stream, b6, b6, aoutw + 5 * 65536, aoutb + 5 * 256, b10, BNrows, 256, 256,
         BNrows, 0, 0, 0, 0, 1, 0, 2, nullptr, nullptr, nullptr, 0, 0);

    // --- FFN + LN2 + prediction ---
    gemm(stream, b10, b10, fw1, fb1, b11, BNrows, 256, 256, BNrows, 0,
         0, 0, 0, 1, 0, 1, nullptr, nullptr, nullptr, 0, 0);
    gemm(stream, b11, b11, fw2, fb2, b0, BNrows, 256, 256, BNrows, 0,
         0, 0, 0, 1, 0, 0, nullptr, nullptr, nullptr, 0, 0);
    ln_k<<<BNrows, 256, 0, stream>>>(b0, b10, nullptr, l2g, l2b, b1, nullptr);
    pred_k<<<BNrows / 4, 256, 0, stream>>>(b1, pw, pb, out);
}

// Round 5
// 1729.310 us; speedup vs baseline: 4.3807x; 1.3708x over previous
//
#include <hip/hip_runtime.h>
#include <hip/hip_bf16.h>

#define B_  32
#define N_  512
#define D_  256
#define H_  8
#define HD_ 32
#define LW_ 25

typedef __attribute__((ext_vector_type(8))) short short8;
typedef __attribute__((ext_vector_type(4))) float f32x4;

// ---------------------------------------------------------------------------
// MFMA bf16 GEMM: C[m,o] = sum_k A[m,k] * W[o,k] (+bias); A,W f32 in HBM,
// converted to bf16 in LDS staging. Tile 128x64, BK=32, 4 waves x (64x32).
// qkvmode: scatter outputs to bf16 Q (BH,L,32), K (BH,L,32), V^T (BH,32,Lvt).
// A row mapping: row = (m/rowsPerA)*aBatch + (m%rowsPerA)*K.
// ---------------------------------------------------------------------------
#define GBM 128
#define GBO 64
#define GBK 32
#define APAD 40   // LDS row stride in bf16 (80 B): 2-way banks max, 16B-aligned

__global__ __launch_bounds__(256) void gemm_k(
    const float* Aq, const float* Akv,
    const float* W, const float* bias, float* C,
    int M, int K, int Onum,
    int rowsPerA, long long aBatch,
    long long aZ, long long wZ, long long cZ,
    int qkvmode, int flags,
    __hip_bfloat16* Qd, __hip_bfloat16* Kd, __hip_bfloat16* Vd,
    int Lseq, int Lvt)
{
    __shared__ __hip_bfloat16 As[GBM * APAD];   // 10240 B
    __shared__ __hip_bfloat16 Bs[GBO * APAD];   // 5120 B
    const int tid = threadIdx.x;
    const int o0 = blockIdx.x * GBO;
    const int m0 = blockIdx.y * GBM;
    const int z  = blockIdx.z;
    const float* A = (qkvmode && o0 >= 256) ? Akv : Aq;
    A += (long long)z * aZ;
    if (C) C += (long long)z * cZ;
    const float* Wz = W + (long long)z * wZ;

    const int w = tid >> 6, lane = tid & 63;
    const int col = lane & 15, quad = lane >> 4;
    const int wm = (w & 1) * 64;
    const int wn = (w >> 1) * 32;

    f32x4 acc[4][2];
    #pragma unroll
    for (int mt = 0; mt < 4; mt++)
        #pragma unroll
        for (int nt = 0; nt < 2; nt++)
            acc[mt][nt] = (f32x4)0.f;

    for (int k0 = 0; k0 < K; k0 += GBK) {
        // ---- stage A: 128 rows x 32 k = 1024 float4 ----
        #pragma unroll
        for (int i = 0; i < 4; i++) {
            int idx = tid + i * 256;
            int mm = idx >> 3, f4 = idx & 7;
            int m = m0 + mm;
            float4 v = make_float4(0.f, 0.f, 0.f, 0.f);
            if (m < M) {
                long long row = (long long)(m / rowsPerA) * aBatch +
                                (long long)(m % rowsPerA) * K;
                v = *(const float4*)(A + row + k0 + f4 * 4);
            }
            __hip_bfloat16* d = As + mm * APAD + f4 * 4;
            d[0] = __float2bfloat16(v.x); d[1] = __float2bfloat16(v.y);
            d[2] = __float2bfloat16(v.z); d[3] = __float2bfloat16(v.w);
        }
        // ---- stage B (weights): 64 rows x 32 k = 512 float4 ----
        #pragma unroll
        for (int i = 0; i < 2; i++) {
            int idx = tid + i * 256;
            int oo = idx >> 3, f4 = idx & 7;
            float4 v = *(const float4*)(Wz + (long long)(o0 + oo) * K + k0 + f4 * 4);
            __hip_bfloat16* d = Bs + oo * APAD + f4 * 4;
            d[0] = __float2bfloat16(v.x); d[1] = __float2bfloat16(v.y);
            d[2] = __float2bfloat16(v.z); d[3] = __float2bfloat16(v.w);
        }
        __syncthreads();
        short8 af[4], bfr[2];
        #pragma unroll
        for (int mt = 0; mt < 4; mt++)
            af[mt] = *(const short8*)(As + (wm + mt * 16 + col) * APAD + quad * 8);
        #pragma unroll
        for (int nt = 0; nt < 2; nt++)
            bfr[nt] = *(const short8*)(Bs + (wn + nt * 16 + col) * APAD + quad * 8);
        #pragma unroll
        for (int mt = 0; mt < 4; mt++)
            #pragma unroll
            for (int nt = 0; nt < 2; nt++)
                acc[mt][nt] = __builtin_amdgcn_mfma_f32_16x16x32_bf16(
                    af[mt], bfr[nt], acc[mt][nt], 0, 0, 0);
        __syncthreads();
    }

    // ---- epilogue ----
    #pragma unroll
    for (int mt = 0; mt < 4; mt++) {
        #pragma unroll
        for (int nt = 0; nt < 2; nt++) {
            const int o = o0 + wn + nt * 16 + col;
            #pragma unroll
            for (int r = 0; r < 4; r++) {
                const int m = m0 + wm + mt * 16 + quad * 4 + r;
                if (m >= M) continue;
                float v = acc[mt][nt][r];
                if (bias) v += bias[o];
                if (flags & 1) v = fmaxf(v, 0.f);
                if (!qkvmode) {
                    long long ci = (long long)m * Onum + o;
                    if (flags & 2) C[ci] += v; else C[ci] = v;
                } else {
                    int which = o >> 8;
                    int oo = o & 255;
                    int hh = oo >> 5, j2 = oo & 31;
                    int bb = m / Lseq, nn = m % Lseq;
                    int bh = bb * H_ + hh;
                    __hip_bfloat16 hv = __float2bfloat16(v);
                    if (which == 0)
                        Qd[((size_t)bh * Lseq + nn) * HD_ + j2] = hv;
                    else if (which == 1)
                        Kd[((size_t)bh * Lseq + nn) * HD_ + j2] = hv;
                    else
                        Vd[((size_t)bh * HD_ + j2) * Lvt + nn] = hv;
                }
            }
        }
    }
}

// ---------------------------------------------------------------------------
// MFMA fused attention. Block = (q-tile of 16, b*H+h), 4 waves.
// Q,K: (BH, L, 32) bf16.  Vt: (BH, 32, Lvt) bf16 (transposed).
// O: (B*L, 256) f32. meanW: atomicAdd probs/8 into (B,N,N) (pre-zeroed).
// ---------------------------------------------------------------------------
#define SROW 516
#define OPS  34

__global__ __launch_bounds__(256) void attn_k(
    const __hip_bfloat16* Qb, const __hip_bfloat16* Kb, const __hip_bfloat16* Vtb,
    float* O, float* meanW, int L, int Lvt, int causal)
{
    __shared__ float S[16 * SROW];   // 33 KB; reused for O-partials
    const int tid  = threadIdx.x;
    const int w    = tid >> 6, lane = tid & 63;
    const int col  = lane & 15, quad = lane >> 4;
    const int qt = blockIdx.x, bh = blockIdx.y;
    const int b  = bh >> 3, h = bh & 7;
    const int q0 = qt * 16;
    const int NT = (L + 15) >> 4;
    const int NC = (L + 31) >> 5;
    const int Lc = NC * 32;
    const float scale = 0.17677669529663687f;  // 1/sqrt(32)

    const __hip_bfloat16* Qh = Qb  + (size_t)bh * L * HD_;
    const __hip_bfloat16* Kh = Kb  + (size_t)bh * L * HD_;
    const __hip_bfloat16* Vh = Vtb + (size_t)bh * HD_ * Lvt;

    short8 aq = (short8)(short)0;
    if (q0 + col < L)
        aq = *(const short8*)(Qh + (size_t)(q0 + col) * HD_ + quad * 8);

    f32x4 sc[8];
    #pragma unroll
    for (int t = 0; t < 8; t++) sc[t] = (f32x4)0.f;
    #pragma unroll
    for (int t = 0; t < 8; t++) {
        int kt = w + 4 * t;
        if (kt >= NT) break;
        int key = kt * 16 + col;
        short8 bk = (short8)(short)0;
        if (key < L)
            bk = *(const short8*)(Kh + (size_t)key * HD_ + quad * 8);
        sc[t] = __builtin_amdgcn_mfma_f32_16x16x32_bf16(aq, bk, sc[t], 0, 0, 0);
    }
    #pragma unroll
    for (int t = 0; t < 8; t++) {
        int kt = w + 4 * t;
        if (kt >= NT) break;
        int kk = kt * 16 + col;
        #pragma unroll
        for (int r = 0; r < 4; r++) {
            int row = quad * 4 + r;
            float v = sc[t][r] * scale;
            if (causal && kk > q0 + row) v = -1e9f;
            S[row * SROW + kk] = v;
        }
    }
    __syncthreads();

    #pragma unroll
    for (int r4 = 0; r4 < 4; r4++) {
        const int row = w * 4 + r4;
        float* Sr = S + row * SROW;
        float m = -3e38f;
        for (int k = lane; k < L; k += 64) m = fmaxf(m, Sr[k]);
        #pragma unroll
        for (int off = 32; off; off >>= 1) m = fmaxf(m, __shfl_xor(m, off));
        float ps = 0.f;
        for (int k = lane; k < L; k += 64) {
            float e = __expf(Sr[k] - m);
            Sr[k] = e;
            ps += e;
        }
        #pragma unroll
        for (int off = 32; off; off >>= 1) ps += __shfl_xor(ps, off);
        const float inv = 1.f / ps;
        for (int k = lane; k < L; k += 64) Sr[k] *= inv;
        for (int k = L + lane; k < Lc; k += 64) Sr[k] = 0.f;
    }
    __syncthreads();

    if (meanW != nullptr) {
        float* dst = meanW + ((size_t)b * N_ + q0) * N_;
        for (int e = tid; e < 16 * 512; e += 256) {
            int row = e >> 9, k = e & 511;
            atomicAdd(dst + e, S[row * SROW + k] * 0.125f);
        }
    }

    f32x4 oacc[2];
    oacc[0] = (f32x4)0.f; oacc[1] = (f32x4)0.f;
    #pragma unroll
    for (int cc = 0; cc < 4; cc++) {
        int c = w + 4 * cc;
        if (c >= NC) break;
        const float* Sp = S + col * SROW + c * 32 + quad * 8;
        f32x4 p0 = *(const f32x4*)Sp;
        f32x4 p1 = *(const f32x4*)(Sp + 4);
        short8 ap;
        #pragma unroll
        for (int j = 0; j < 4; j++) {
            ap[j]     = __builtin_bit_cast(short, __float2bfloat16(p0[j]));
            ap[j + 4] = __builtin_bit_cast(short, __float2bfloat16(p1[j]));
        }
        #pragma unroll
        for (int hf = 0; hf < 2; hf++) {
            const short8 bv = *(const short8*)(Vh + (size_t)(hf * 16 + col) * Lvt
                                               + c * 32 + quad * 8);
            oacc[hf] = __builtin_amdgcn_mfma_f32_16x16x32_bf16(ap, bv, oacc[hf], 0, 0, 0);
        }
    }
    __syncthreads();

    #pragma unroll
    for (int hf = 0; hf < 2; hf++)
        #pragma unroll
        for (int r = 0; r < 4; r++)
            S[w * (16 * OPS) + (quad * 4 + r) * OPS + hf * 16 + col] = oacc[hf][r];
    __syncthreads();
    for (int e = tid; e < 512; e += 256) {
        int row = e >> 5, d = e & 31;
        float v = S[row * OPS + d] + S[544 + row * OPS + d] +
                  S[1088 + row * OPS + d] + S[1632 + row * OPS + d];
        int n = q0 + row;
        if (n < L) O[((size_t)b * L + n) * D_ + h * HD_ + d] = v;
    }
}

// ---------------------------------------------------------------------------
// Small kernels
// ---------------------------------------------------------------------------
__global__ __launch_bounds__(256) void rowsoftmax_k(const float* in, float* out) {
    __shared__ float red[256];
    const long long row = blockIdx.x;
    const int t = threadIdx.x;
    const float* ip = in + row * 2048;
    float* op = out + row * 2048;
    float m = -3e38f;
    for (int k = t; k < 2048; k += 256) m = fmaxf(m, ip[k]);
    red[t] = m; __syncthreads();
    for (int s = 128; s > 0; s >>= 1) { if (t < s) red[t] = fmaxf(red[t], red[t + s]); __syncthreads(); }
    m = red[0]; __syncthreads();
    float ps = 0.f;
    for (int k = t; k < 2048; k += 256) { float e = __expf(ip[k] - m); op[k] = e; ps += e; }
    red[t] = ps; __syncthreads();
    for (int s = 128; s > 0; s >>= 1) { if (t < s) red[t] += red[t + s]; __syncthreads(); }
    const float inv = 1.f / red[0];
    for (int k = t; k < 2048; k += 256) op[k] *= inv;
}

__global__ void embed_k(const int* q, const int* r, const int* qry,
                        const float* Memb, const float* Eemb, const float* P,
                        float* M, float* E) {
    const int i = blockIdx.x; const int t = threadIdx.x;
    const int n = i & (N_ - 1);
    const int x = q[i] + 2048 * r[i];
    M[(long long)i * D_ + t] = Memb[(long long)x * D_ + t] + P[(long long)n * D_ + t];
    E[(long long)i * D_ + t] = Eemb[(long long)qry[i] * D_ + t];
}

__global__ void gather_k(const int* q, const float* T, float* G) {
    const int i = blockIdx.x; const int t = threadIdx.x;
    G[(long long)i * D_ + t] = T[(long long)q[i] * D_ + t];
}

__global__ __launch_bounds__(256) void ln_k(const float* xa, const float* xb, const float* xc,
                                            const float* g, const float* bta,
                                            float* out1, float* out2) {
    __shared__ float red[256];
    const long long row = blockIdx.x;
    const int t = threadIdx.x;
    float v = xa[row * D_ + t];
    if (xb) v += xb[row * D_ + t];
    if (xc) v += xc[row * D_ + t];
    red[t] = v; __syncthreads();
    for (int s = 128; s > 0; s >>= 1) { if (t < s) red[t] += red[t + s]; __syncthreads(); }
    const float mean = red[0] * (1.f / 256.f);
    __syncthreads();
    const float d = v - mean;
    red[t] = d * d; __syncthreads();
    for (int s = 128; s > 0; s >>= 1) { if (t < s) red[t] += red[t + s]; __syncthreads(); }
    const float var = red[0] * (1.f / 256.f);
    const float y = d * rsqrtf(var + 1e-5f) * g[t] + bta[t];
    out1[row * D_ + t] = y;
    if (out2) out2[row * D_ + t] = y;
}

__global__ void scatterlocal_k(const float* tail, float* Slocal, float* Sacc) {
    const int i = blockIdx.x; const int t = threadIdx.x;
    const int n = i & (N_ - 1), b = i >> 9;
    float v = 0.f;
    if (n >= N_ - LW_) {
        v = tail[((long long)(b * LW_ + (n - (N_ - LW_)))) * D_ + t];
        Sacc[(long long)i * D_ + t] += v;
    }
    Slocal[(long long)i * D_ + t] = v;
}

__global__ void add_k(float* dst, const float* src) {
    const long long i = (long long)blockIdx.x * 256 + threadIdx.x;
    dst[i] += src[i];
}

__global__ void zero4_k(float4* p) {
    p[(long long)blockIdx.x * 256 + threadIdx.x] = make_float4(0.f, 0.f, 0.f, 0.f);
}

__global__ __launch_bounds__(256) void pred_k(const float* F, const float* pw, const float* pb,
                                              float* out) {
    const int tid = threadIdx.x;
    const int wave = tid >> 6, lane = tid & 63;
    const long long row = (long long)blockIdx.x * 4 + wave;
    const float* fp = F + row * D_ + lane * 4;
    float s = 0.f;
    #pragma unroll
    for (int j = 0; j < 4; j++) s += fp[j] * pw[lane * 4 + j];
    #pragma unroll
    for (int off = 32; off > 0; off >>= 1) s += __shfl_down(s, off);
    if (lane == 0) {
        float p = 1.f / (1.f + __expf(-(s + pb[0])));
        out[row] = p;
    }
}

// ---------------------------------------------------------------------------
static void gemm(hipStream_t st, const float* Aq, const float* Akv,
                 const float* W, const float* bias, float* C,
                 int M, int K, int Onum, int rowsPerA, long long aBatch,
                 long long aZ, long long wZ, long long cZ, int Z,
                 int qkv, int flags,
                 __hip_bfloat16* Qd, __hip_bfloat16* Kd, __hip_bfloat16* Vd,
                 int Lseq, int Lvt)
{
    dim3 g((Onum + GBO - 1) / GBO, (M + GBM - 1) / GBM, Z), blk(256, 1, 1);
    gemm_k<<<g, blk, 0, st>>>(Aq, Akv, W, bias, C, M, K, Onum, rowsPerA, aBatch,
                              aZ, wZ, cZ, qkv, flags, Qd, Kd, Vd, Lseq, Lvt);
}

extern "C" void kernel_launch(void* const* d_in, const int* in_sizes, int n_in,
                              void* d_out, int out_size, void* d_ws, size_t ws_size,
                              hipStream_t stream)
{
    const int* qi  = (const int*)d_in[0];
    const int* ri  = (const int*)d_in[1];
    const int* qry = (const int*)d_in[2];
    const float* Memb = (const float*)d_in[3];
    const float* Eemb = (const float*)d_in[4];
    const float* Pp   = (const float*)d_in[5];
    const float* ainw = (const float*)d_in[6];
    const float* ainb = (const float*)d_in[7];
    const float* aoutw= (const float*)d_in[8];
    const float* aoutb= (const float*)d_in[9];
    const float* scw  = (const float*)d_in[10];
    const float* spw  = (const float*)d_in[11];
    const float* spb  = (const float*)d_in[12];
    const float* stew = (const float*)d_in[13];
    const float* steb = (const float*)d_in[14];
    const float* fw1  = (const float*)d_in[15];
    const float* fb1  = (const float*)d_in[16];
    const float* fw2  = (const float*)d_in[17];
    const float* fb2  = (const float*)d_in[18];
    const float* l1g  = (const float*)d_in[19];
    const float* l1b  = (const float*)d_in[20];
    const float* l2g  = (const float*)d_in[21];
    const float* l2b  = (const float*)d_in[22];
    const float* pw   = (const float*)d_in[23];
    const float* pb   = (const float*)d_in[24];
    float* out = (float*)d_out;
    float* outW = out + B_ * N_;   // attn-weights output region (f32)

    float* ws = (float*)d_ws;
    const size_t BND = (size_t)B_ * N_ * D_;   // 4,194,304 floats
    float* b0  = ws + 0 * BND;   // SW -> M -> FFNout
    float* b1  = ws + 1 * BND;   // E -> G -> F
    float* b2  = ws + 2 * BND;   // S_base
    float* b3  = ws + 3 * BND;   // Q (bf16)
    float* b4  = ws + 4 * BND;   // K (bf16)
    float* b5  = ws + 5 * BND;   // V^T (bf16)
    float* b6  = ws + 6 * BND;   // O (attn out, pre-proj, f32)
    float* b7  = ws + 7 * BND;   // S_local (padded)
    float* b8  = ws + 8 * BND;   // S_sg
    float* b9  = ws + 9 * BND;   // S_glob
    float* b10 = ws + 10 * BND;  // S accumulator
    float* b11 = ws + 11 * BND;  // S_sg-pre / FFN hidden
    float* BNN = ws + 12 * BND;               // (B,N,N) f32 scratch
    float* Ttab = BNN + (size_t)B_ * N_ * N_; // (2048, 256) f32
    const int BNrows = B_ * N_;               // 16384
    const int BH = B_ * H_;                   // 256
    __hip_bfloat16* Qb  = (__hip_bfloat16*)b3;
    __hip_bfloat16* Kb  = (__hip_bfloat16*)b4;
    __hip_bfloat16* Vtb = (__hip_bfloat16*)b5;

    // --- skill table: T = softmax(scw) @ spw^T + spb ---
    rowsoftmax_k<<<2048, 256, 0, stream>>>(scw, b0);
    gemm(stream, b0, b0, spw, spb, Ttab, 2048, 2048, 256, 2048, 0, 0, 0, 0, 1,
         0, 0, nullptr, nullptr, nullptr, 0, 0);

    // --- embeddings: M = M_emb[q + 2048 r] + P ; E = E_emb[qry] ---
    embed_k<<<BNrows, 256, 0, stream>>>(qi, ri, qry, Memb, Eemb, Pp, b0, b1);

    // --- attn 0: q=E, kv=M, causal, mean weights -> out (atomic) ---
    zero4_k<<<(B_ * N_ * N_) / 1024, 256, 0, stream>>>((float4*)outW);
    gemm(stream, b1, b0, ainw + 0, ainb + 0, nullptr, BNrows, 256, 768, BNrows, 0,
         0, 0, 0, 1, 1, 0, Qb, Kb, Vtb, N_, N_);
    attn_k<<<dim3(32, BH), 256, 0, stream>>>(Qb, Kb, Vtb, b6, outW, N_, N_, 1);
    gemm(stream, b6, b6, aoutw + 0, aoutb + 0, b10, BNrows, 256, 256, BNrows, 0,
         0, 0, 0, 1, 0, 0, nullptr, nullptr, nullptr, 0, 0);
    // S_base = LN1(proj + M + E)  (also init accumulator)
    ln_k<<<BNrows, 256, 0, stream>>>(b10, b0, b1, l1g, l1b, b2, b10);

    // --- attn 1 (local, LW=25, causal) on S_base[:, -25:, :] ---
    gemm(stream, b2 + (N_ - LW_) * D_, b2 + (N_ - LW_) * D_,
         ainw + 1 * 768 * 256, ainb + 768, nullptr, B_ * LW_, 256, 768,
         LW_, (long long)N_ * D_, 0, 0, 0, 1, 1, 0, Qb, Kb, Vtb, LW_, 32);
    attn_k<<<dim3(2, BH), 256, 0, stream>>>(Qb, Kb, Vtb, b6, nullptr, LW_, 32, 1);
    gemm(stream, b6, b6, aoutw + 1 * 65536, aoutb + 256, BNN, B_ * LW_, 256, 256,
         B_ * LW_, 0, 0, 0, 0, 1, 0, 0, nullptr, nullptr, nullptr, 0, 0);
    scatterlocal_k<<<BNrows, 256, 0, stream>>>(BNN, b7, b10);

    // --- skill group path ---
    gather_k<<<BNrows, 256, 0, stream>>>(qi, Ttab, b1);   // G
    gemm(stream, b2, b2, b1, nullptr, BNN, N_, 256, N_, N_, 0,
         (long long)N_ * D_, (long long)N_ * D_, (long long)N_ * N_, B_,
         0, 0, nullptr, nullptr, nullptr, 0, 0);
    gemm(stream, BNN, BNN, stew, steb, b11, BNrows, 512, 256, BNrows, 0,
         0, 0, 0, 1, 0, 0, nullptr, nullptr, nullptr, 0, 0);
    gemm(stream, b11, b11, ainw + 2 * 196608, ainb + 2 * 768, nullptr, BNrows, 256, 768,
         BNrows, 0, 0, 0, 0, 1, 1, 0, Qb, Kb, Vtb, N_, N_);
    attn_k<<<dim3(32, BH), 256, 0, stream>>>(Qb, Kb, Vtb, b6, nullptr, N_, N_, 0);
    gemm(stream, b6, b6, aoutw + 2 * 65536, aoutb + 2 * 256, b8, BNrows, 256, 256,
         BNrows, 0, 0, 0, 0, 1, 0, 0, nullptr, nullptr, nullptr, 0, 0);
    add_k<<<BNrows, 256, 0, stream>>>(b10, b8);

    // --- attn 3: self on S_base, causal -> S_glob ---
    gemm(stream, b2, b2, ainw + 3 * 196608, ainb + 3 * 768, nullptr, BNrows, 256, 768,
         BNrows, 0, 0, 0, 0, 1, 1, 0, Qb, Kb, Vtb, N_, N_);
    attn_k<<<dim3(32, BH), 256, 0, stream>>>(Qb, Kb, Vtb, b6, nullptr, N_, N_, 1);
    gemm(stream, b6, b6, aoutw + 3 * 65536, aoutb + 3 * 256, b9, BNrows, 256, 256,
         BNrows, 0, 0, 0, 0, 1, 0, 0, nullptr, nullptr, nullptr, 0, 0);
    add_k<<<BNrows, 256, 0, stream>>>(b10, b9);

    // --- attn 4: q=S_base, kv=S_local, no mask -> accumulate ---
    gemm(stream, b2, b7, ainw + 4 * 196608, ainb + 4 * 768, nullptr, BNrows, 256, 768,
         BNrows, 0, 0, 0, 0, 1, 1, 0, Qb, Kb, Vtb, N_, N_);
    attn_k<<<dim3(32, BH), 256, 0, stream>>>(Qb, Kb, Vtb, b6, nullptr, N_, N_, 0);
    gemm(stream, b6, b6, aoutw + 4 * 65536, aoutb + 4 * 256, b10, BNrows, 256, 256,
         BNrows, 0, 0, 0, 0, 1, 0, 2, nullptr, nullptr, nullptr, 0, 0);

    // --- attn 5: q=S_sg, kv=S_glob, no mask -> accumulate ---
    gemm(stream, b8, b9, ainw + 5 * 196608, ainb + 5 * 768, nullptr, BNrows, 256, 768,
         BNrows, 0, 0, 0, 0, 1, 1, 0, Qb, Kb, Vtb, N_, N_);
    attn_k<<<dim3(32, BH), 256, 0, stream>>>(Qb, Kb, Vtb, b6, nullptr, N_, N_, 0);
    gemm(stream, b6, b6, aoutw + 5 * 65536, aoutb + 5 * 256, b10, BNrows, 256, 256,
         BNrows, 0, 0, 0, 0, 1, 0, 2, nullptr, nullptr, nullptr, 0, 0);

    // --- FFN + LN2 + prediction ---
    gemm(stream, b10, b10, fw1, fb1, b11, BNrows, 256, 256, BNrows, 0,
         0, 0, 0, 1, 0, 1, nullptr, nullptr, nullptr, 0, 0);
    gemm(stream, b11, b11, fw2, fb2, b0, BNrows, 256, 256, BNrows, 0,
         0, 0, 0, 1, 0, 0, nullptr, nullptr, nullptr, 0, 0);
    ln_k<<<BNrows, 256, 0, stream>>>(b0, b10, nullptr, l2g, l2b, b1, nullptr);
    pred_k<<<BNrows / 4, 256, 0, stream>>>(b1, pw, pb, out);
}

// Round 6
// 1336.409 us; speedup vs baseline: 5.6686x; 1.2940x over previous
//
#include <hip/hip_runtime.h>
#include <hip/hip_bf16.h>

#define B_  32
#define N_  512
#define D_  256
#define H_  8
#define HD_ 32
#define LW_ 25

typedef __hip_bfloat16 bf;
typedef __attribute__((ext_vector_type(8))) short short8;
typedef __attribute__((ext_vector_type(4))) float f32x4;

__device__ __forceinline__ void gload16(const void* g, void* l) {
    __builtin_amdgcn_global_load_lds(
        (const __attribute__((address_space(1))) unsigned int*)g,
        (__attribute__((address_space(3))) unsigned int*)l, 16, 0, 0);
}

// ---------------------------------------------------------------------------
// MFMA bf16 GEMM v2: C[m,o] = sum_k A[m,k] * W[o,k] (+bias). A,W bf16.
// Tile 128x128, BK=32, 4 waves x (64x64). global_load_lds staging (16B).
// A row mapping: row = (m/rowsPerA)*aBatch + (m%rowsPerA)*K  (elements).
// flags: 1=relu, 2=accumulate(f32), 4=atomicAdd(f32, splitK).
// qkvmode: scatter to bf16 Q (BH,L,32), K (BH,L,32), V^T (BH,32,Lvt).
// splitKc>0: blockIdx.z indexes K-chunks (no z pointer offsets).
// ---------------------------------------------------------------------------
__global__ __launch_bounds__(256) void gemm2_k(
    const bf* Aq, const bf* Akv, const bf* W, const float* bias,
    float* Cf, bf* Cb,
    int M, int K, int Onum,
    int rowsPerA, long long aBatch,
    long long aZ, long long wZ, long long cZ,
    int qkvmode, int flags, int splitKc,
    bf* Qd, bf* Kd, bf* Vd, int Lseq, int Lvt)
{
    __shared__ __align__(16) bf As[128 * 32];
    __shared__ __align__(16) bf Bs[128 * 32];
    const int tid = threadIdx.x;
    const int o0 = blockIdx.x * 128;
    const int m0 = blockIdx.y * 128;
    const int z  = blockIdx.z;
    const bf* A = (qkvmode && o0 >= 256) ? Akv : Aq;
    const bf* Wp = W;
    int kStart = 0, kEnd = K;
    if (splitKc > 0) {
        kStart = z * splitKc;
        kEnd   = min(K, kStart + splitKc);
    } else {
        A  += (long long)z * aZ;
        Wp += (long long)z * wZ;
        if (Cf) Cf += (long long)z * cZ;
        if (Cb) Cb += (long long)z * cZ;
    }

    const int w = tid >> 6, lane = tid & 63;
    const int col = lane & 15, quad = lane >> 4;
    const int wm = (w & 1) * 64;
    const int wn = (w >> 1) * 64;

    // precompute per-thread staging rows
    const int sidx0 = tid, sidx1 = tid + 256;
    long long arow0, arow1;
    {
        int m = m0 + (sidx0 >> 2);
        arow0 = (long long)(m / rowsPerA) * aBatch + (long long)(m % rowsPerA) * K;
        m = m0 + (sidx1 >> 2);
        arow1 = (long long)(m / rowsPerA) * aBatch + (long long)(m % rowsPerA) * K;
    }
    const long long wrow0 = (long long)(o0 + (sidx0 >> 2)) * K;
    const long long wrow1 = (long long)(o0 + (sidx1 >> 2)) * K;
    const int ac0 = (sidx0 & 3) * 8, ac1 = (sidx1 & 3) * 8;

    f32x4 acc[4][4];
    #pragma unroll
    for (int mt = 0; mt < 4; mt++)
        #pragma unroll
        for (int nt = 0; nt < 4; nt++)
            acc[mt][nt] = (f32x4)0.f;

    for (int k0 = kStart; k0 < kEnd; k0 += 32) {
        gload16(A + arow0 + k0 + ac0, As + sidx0 * 8);
        gload16(A + arow1 + k0 + ac1, As + sidx1 * 8);
        gload16(Wp + wrow0 + k0 + ac0, Bs + sidx0 * 8);
        gload16(Wp + wrow1 + k0 + ac1, Bs + sidx1 * 8);
        __syncthreads();
        short8 af[4], bfr[4];
        #pragma unroll
        for (int mt = 0; mt < 4; mt++)
            af[mt] = *(const short8*)(As + (wm + mt * 16 + col) * 32 + quad * 8);
        #pragma unroll
        for (int nt = 0; nt < 4; nt++)
            bfr[nt] = *(const short8*)(Bs + (wn + nt * 16 + col) * 32 + quad * 8);
        #pragma unroll
        for (int mt = 0; mt < 4; mt++)
            #pragma unroll
            for (int nt = 0; nt < 4; nt++)
                acc[mt][nt] = __builtin_amdgcn_mfma_f32_16x16x32_bf16(
                    af[mt], bfr[nt], acc[mt][nt], 0, 0, 0);
        __syncthreads();
    }

    // ---- epilogue ----
    #pragma unroll
    for (int mt = 0; mt < 4; mt++) {
        #pragma unroll
        for (int nt = 0; nt < 4; nt++) {
            const int o = o0 + wn + nt * 16 + col;
            #pragma unroll
            for (int r = 0; r < 4; r++) {
                const int m = m0 + wm + mt * 16 + quad * 4 + r;
                if (m >= M) continue;
                float v = acc[mt][nt][r];
                if (bias) v += bias[o];
                if (flags & 1) v = fmaxf(v, 0.f);
                if (qkvmode) {
                    int which = o >> 8;
                    int oo = o & 255;
                    int hh = oo >> 5, j2 = oo & 31;
                    int bb = m / Lseq, nn = m % Lseq;
                    int bh = bb * H_ + hh;
                    bf hv = __float2bfloat16(v);
                    if (which == 0)
                        Qd[((size_t)bh * Lseq + nn) * HD_ + j2] = hv;
                    else if (which == 1)
                        Kd[((size_t)bh * Lseq + nn) * HD_ + j2] = hv;
                    else
                        Vd[((size_t)bh * HD_ + j2) * Lvt + nn] = hv;
                } else if (flags & 4) {
                    atomicAdd(Cf + (long long)m * Onum + o, v);
                } else {
                    long long ci = (long long)m * Onum + o;
                    if (flags & 2) v += Cf[ci];
                    if (Cf) Cf[ci] = v;
                    if (Cb) Cb[ci] = __float2bfloat16(v);
                }
            }
        }
    }
}

// ---------------------------------------------------------------------------
// MFMA fused attention (no mean). Block = (q-tile 16, b*H+h), 4 waves.
// Q,K: (BH,L,32) bf16.  Vt: (BH,32,Lvt) bf16.  O: (B*L,256) bf16.
// ---------------------------------------------------------------------------
#define SROW 516
#define OPS  34

__global__ __launch_bounds__(256) void attn_k(
    const bf* Qb, const bf* Kb, const bf* Vtb,
    bf* O, int L, int Lvt, int causal)
{
    __shared__ float S[16 * SROW];
    const int tid  = threadIdx.x;
    const int w    = tid >> 6, lane = tid & 63;
    const int col  = lane & 15, quad = lane >> 4;
    const int qt = blockIdx.x, bh = blockIdx.y;
    const int b  = bh >> 3, h = bh & 7;
    const int q0 = qt * 16;
    const int NT = (L + 15) >> 4;
    const int NC = (L + 31) >> 5;
    const int Lc = NC * 32;
    const float scale = 0.17677669529663687f;

    const bf* Qh = Qb  + (size_t)bh * L * HD_;
    const bf* Kh = Kb  + (size_t)bh * L * HD_;
    const bf* Vh = Vtb + (size_t)bh * HD_ * Lvt;

    short8 aq = (short8)(short)0;
    if (q0 + col < L)
        aq = *(const short8*)(Qh + (size_t)(q0 + col) * HD_ + quad * 8);

    f32x4 sc[8];
    #pragma unroll
    for (int t = 0; t < 8; t++) sc[t] = (f32x4)0.f;
    #pragma unroll
    for (int t = 0; t < 8; t++) {
        int kt = w + 4 * t;
        if (kt >= NT) break;
        int key = kt * 16 + col;
        short8 bk = (short8)(short)0;
        if (key < L)
            bk = *(const short8*)(Kh + (size_t)key * HD_ + quad * 8);
        sc[t] = __builtin_amdgcn_mfma_f32_16x16x32_bf16(aq, bk, sc[t], 0, 0, 0);
    }
    #pragma unroll
    for (int t = 0; t < 8; t++) {
        int kt = w + 4 * t;
        if (kt >= NT) break;
        int kk = kt * 16 + col;
        #pragma unroll
        for (int r = 0; r < 4; r++) {
            int row = quad * 4 + r;
            float v = sc[t][r] * scale;
            if (causal && kk > q0 + row) v = -1e9f;
            S[row * SROW + kk] = v;
        }
    }
    __syncthreads();

    #pragma unroll
    for (int r4 = 0; r4 < 4; r4++) {
        const int row = w * 4 + r4;
        float* Sr = S + row * SROW;
        float m = -3e38f;
        for (int k = lane; k < L; k += 64) m = fmaxf(m, Sr[k]);
        #pragma unroll
        for (int off = 32; off; off >>= 1) m = fmaxf(m, __shfl_xor(m, off));
        float ps = 0.f;
        for (int k = lane; k < L; k += 64) {
            float e = __expf(Sr[k] - m);
            Sr[k] = e;
            ps += e;
        }
        #pragma unroll
        for (int off = 32; off; off >>= 1) ps += __shfl_xor(ps, off);
        const float inv = 1.f / ps;
        for (int k = lane; k < L; k += 64) Sr[k] *= inv;
        for (int k = L + lane; k < Lc; k += 64) Sr[k] = 0.f;
    }
    __syncthreads();

    f32x4 oacc[2];
    oacc[0] = (f32x4)0.f; oacc[1] = (f32x4)0.f;
    #pragma unroll
    for (int cc = 0; cc < 4; cc++) {
        int c = w + 4 * cc;
        if (c >= NC) break;
        const float* Sp = S + col * SROW + c * 32 + quad * 8;
        f32x4 p0 = *(const f32x4*)Sp;
        f32x4 p1 = *(const f32x4*)(Sp + 4);
        short8 ap;
        #pragma unroll
        for (int j = 0; j < 4; j++) {
            ap[j]     = __builtin_bit_cast(short, __float2bfloat16(p0[j]));
            ap[j + 4] = __builtin_bit_cast(short, __float2bfloat16(p1[j]));
        }
        #pragma unroll
        for (int hf = 0; hf < 2; hf++) {
            const short8 bv = *(const short8*)(Vh + (size_t)(hf * 16 + col) * Lvt
                                               + c * 32 + quad * 8);
            oacc[hf] = __builtin_amdgcn_mfma_f32_16x16x32_bf16(ap, bv, oacc[hf], 0, 0, 0);
        }
    }
    __syncthreads();

    #pragma unroll
    for (int hf = 0; hf < 2; hf++)
        #pragma unroll
        for (int r = 0; r < 4; r++)
            S[w * (16 * OPS) + (quad * 4 + r) * OPS + hf * 16 + col] = oacc[hf][r];
    __syncthreads();
    for (int e = tid; e < 512; e += 256) {
        int row = e >> 5, d = e & 31;
        float v = S[row * OPS + d] + S[544 + row * OPS + d] +
                  S[1088 + row * OPS + d] + S[1632 + row * OPS + d];
        int n = q0 + row;
        if (n < L) O[((size_t)b * L + n) * D_ + h * HD_ + d] = __float2bfloat16(v);
    }
}

// ---------------------------------------------------------------------------
// attn0 variant: block = (q-tile 16, b); loops 8 heads; head-mean kept in
// registers (32 f32/thread), written once at the end. L=512, causal.
// ---------------------------------------------------------------------------
__global__ __launch_bounds__(256) void attn_mean_k(
    const bf* Qball, const bf* Kball, const bf* Vtball,
    bf* O, float* meanW)
{
    __shared__ float S[16 * SROW];
    const int tid  = threadIdx.x;
    const int w    = tid >> 6, lane = tid & 63;
    const int col  = lane & 15, quad = lane >> 4;
    const int q0 = blockIdx.x * 16, b = blockIdx.y;
    const float scale = 0.17677669529663687f;

    f32x4 mreg[8];
    #pragma unroll
    for (int j = 0; j < 8; j++) mreg[j] = (f32x4)0.f;

    for (int h = 0; h < H_; h++) {
        const int bh = b * H_ + h;
        const bf* Qh = Qball  + (size_t)bh * N_ * HD_;
        const bf* Kh = Kball  + (size_t)bh * N_ * HD_;
        const bf* Vh = Vtball + (size_t)bh * HD_ * N_;

        short8 aq = *(const short8*)(Qh + (size_t)(q0 + col) * HD_ + quad * 8);
        f32x4 sc[8];
        #pragma unroll
        for (int t = 0; t < 8; t++) sc[t] = (f32x4)0.f;
        #pragma unroll
        for (int t = 0; t < 8; t++) {
            int key = (w + 4 * t) * 16 + col;
            short8 bk = *(const short8*)(Kh + (size_t)key * HD_ + quad * 8);
            sc[t] = __builtin_amdgcn_mfma_f32_16x16x32_bf16(aq, bk, sc[t], 0, 0, 0);
        }
        #pragma unroll
        for (int t = 0; t < 8; t++) {
            int kk = (w + 4 * t) * 16 + col;
            #pragma unroll
            for (int r = 0; r < 4; r++) {
                int row = quad * 4 + r;
                float v = sc[t][r] * scale;
                if (kk > q0 + row) v = -1e9f;
                S[row * SROW + kk] = v;
            }
        }
        __syncthreads();

        #pragma unroll
        for (int r4 = 0; r4 < 4; r4++) {
            const int row = w * 4 + r4;
            float* Sr = S + row * SROW;
            float m = -3e38f;
            for (int k = lane; k < N_; k += 64) m = fmaxf(m, Sr[k]);
            #pragma unroll
            for (int off = 32; off; off >>= 1) m = fmaxf(m, __shfl_xor(m, off));
            float ps = 0.f;
            for (int k = lane; k < N_; k += 64) {
                float e = __expf(Sr[k] - m);
                Sr[k] = e;
                ps += e;
            }
            #pragma unroll
            for (int off = 32; off; off >>= 1) ps += __shfl_xor(ps, off);
            const float inv = 1.f / ps;
            for (int k = lane; k < N_; k += 64) Sr[k] *= inv;
        }
        __syncthreads();

        // mean accumulation (registers, coalesced f32x4 LDS reads)
        #pragma unroll
        for (int j = 0; j < 8; j++) {
            int e = tid * 4 + 1024 * j;
            int row = e >> 9, k = e & 511;
            mreg[j] += *(const f32x4*)(S + row * SROW + k);
        }

        // PV
        f32x4 oacc[2];
        oacc[0] = (f32x4)0.f; oacc[1] = (f32x4)0.f;
        #pragma unroll
        for (int cc = 0; cc < 4; cc++) {
            int c = w + 4 * cc;
            const float* Sp = S + col * SROW + c * 32 + quad * 8;
            f32x4 p0 = *(const f32x4*)Sp;
            f32x4 p1 = *(const f32x4*)(Sp + 4);
            short8 ap;
            #pragma unroll
            for (int j = 0; j < 4; j++) {
                ap[j]     = __builtin_bit_cast(short, __float2bfloat16(p0[j]));
                ap[j + 4] = __builtin_bit_cast(short, __float2bfloat16(p1[j]));
            }
            #pragma unroll
            for (int hf = 0; hf < 2; hf++) {
                const short8 bv = *(const short8*)(Vh + (size_t)(hf * 16 + col) * N_
                                                   + c * 32 + quad * 8);
                oacc[hf] = __builtin_amdgcn_mfma_f32_16x16x32_bf16(ap, bv, oacc[hf], 0, 0, 0);
            }
        }
        __syncthreads();

        #pragma unroll
        for (int hf = 0; hf < 2; hf++)
            #pragma unroll
            for (int r = 0; r < 4; r++)
                S[w * (16 * OPS) + (quad * 4 + r) * OPS + hf * 16 + col] = oacc[hf][r];
        __syncthreads();
        for (int e = tid; e < 512; e += 256) {
            int row = e >> 5, d = e & 31;
            float v = S[row * OPS + d] + S[544 + row * OPS + d] +
                      S[1088 + row * OPS + d] + S[1632 + row * OPS + d];
            O[((size_t)b * N_ + q0 + row) * D_ + h * HD_ + d] = __float2bfloat16(v);
        }
        __syncthreads();
    }

    #pragma unroll
    for (int j = 0; j < 8; j++) {
        int e = tid * 4 + 1024 * j;
        int row = e >> 9, k = e & 511;
        f32x4 mv = mreg[j] * 0.125f;
        *(f32x4*)(meanW + ((size_t)b * N_ + q0 + row) * N_ + k) = mv;
    }
}

// ---------------------------------------------------------------------------
// Small kernels
// ---------------------------------------------------------------------------
__global__ void conv_k(const float* s, bf* d, int n) {
    int i = blockIdx.x * 256 + threadIdx.x;
    if (i < n) d[i] = __float2bfloat16(s[i]);
}

__global__ __launch_bounds__(256) void rowsoftmax_k(const float* in, bf* out) {
    __shared__ float red[256];
    const long long row = blockIdx.x;
    const int t = threadIdx.x;
    const float* ip = in + row * 2048;
    bf* op = out + row * 2048;
    float m = -3e38f;
    for (int k = t; k < 2048; k += 256) m = fmaxf(m, ip[k]);
    red[t] = m; __syncthreads();
    for (int s = 128; s > 0; s >>= 1) { if (t < s) red[t] = fmaxf(red[t], red[t + s]); __syncthreads(); }
    m = red[0]; __syncthreads();
    float ps = 0.f;
    float ev[8];
    #pragma unroll
    for (int i = 0; i < 8; i++) { ev[i] = __expf(ip[t + i * 256] - m); ps += ev[i]; }
    red[t] = ps; __syncthreads();
    for (int s = 128; s > 0; s >>= 1) { if (t < s) red[t] += red[t + s]; __syncthreads(); }
    const float inv = 1.f / red[0];
    #pragma unroll
    for (int i = 0; i < 8; i++) op[t + i * 256] = __float2bfloat16(ev[i] * inv);
}

__global__ void embed_k(const int* q, const int* r, const int* qry,
                        const float* Memb, const float* Eemb, const float* P,
                        float* M, float* E, bf* Mh, bf* Eh) {
    const int i = blockIdx.x; const int t = threadIdx.x;
    const int n = i & (N_ - 1);
    const int x = q[i] + 2048 * r[i];
    float mv = Memb[(long long)x * D_ + t] + P[(long long)n * D_ + t];
    float evv = Eemb[(long long)qry[i] * D_ + t];
    M[(long long)i * D_ + t] = mv;  Mh[(long long)i * D_ + t] = __float2bfloat16(mv);
    E[(long long)i * D_ + t] = evv; Eh[(long long)i * D_ + t] = __float2bfloat16(evv);
}

__global__ void gather_k(const int* q, const float* T, const float* spb, bf* G) {
    const int i = blockIdx.x; const int t = threadIdx.x;
    G[(long long)i * D_ + t] = __float2bfloat16(T[(long long)q[i] * D_ + t] + spb[t]);
}

__global__ __launch_bounds__(256) void ln_k(const float* xa, const float* xb, const float* xc,
                                            const float* g, const float* bta,
                                            float* outF, bf* outB, float* out2) {
    __shared__ float red[256];
    const long long row = blockIdx.x;
    const int t = threadIdx.x;
    float v = xa[row * D_ + t];
    if (xb) v += xb[row * D_ + t];
    if (xc) v += xc[row * D_ + t];
    red[t] = v; __syncthreads();
    for (int s = 128; s > 0; s >>= 1) { if (t < s) red[t] += red[t + s]; __syncthreads(); }
    const float mean = red[0] * (1.f / 256.f);
    __syncthreads();
    const float d = v - mean;
    red[t] = d * d; __syncthreads();
    for (int s = 128; s > 0; s >>= 1) { if (t < s) red[t] += red[t + s]; __syncthreads(); }
    const float var = red[0] * (1.f / 256.f);
    const float y = d * rsqrtf(var + 1e-5f) * g[t] + bta[t];
    if (outF) outF[row * D_ + t] = y;
    if (outB) outB[row * D_ + t] = __float2bfloat16(y);
    if (out2) out2[row * D_ + t] = y;
}

__global__ void scatterlocal_k(const float* tail, bf* Slocalh, float* Sacc) {
    const int i = blockIdx.x; const int t = threadIdx.x;
    const int n = i & (N_ - 1), b = i >> 9;
    float v = 0.f;
    if (n >= N_ - LW_) {
        v = tail[((long long)(b * LW_ + (n - (N_ - LW_)))) * D_ + t];
        Sacc[(long long)i * D_ + t] += v;
    }
    Slocalh[(long long)i * D_ + t] = __float2bfloat16(v);
}

__global__ void add_k(float* dst, const float* src) {
    const long long i = (long long)blockIdx.x * 256 + threadIdx.x;
    dst[i] += src[i];
}

__global__ void zero4_k(float4* p) {
    p[(long long)blockIdx.x * 256 + threadIdx.x] = make_float4(0.f, 0.f, 0.f, 0.f);
}

__global__ __launch_bounds__(256) void pred_k(const float* F, const float* pw, const float* pb,
                                              float* out) {
    const int tid = threadIdx.x;
    const int wave = tid >> 6, lane = tid & 63;
    const long long row = (long long)blockIdx.x * 4 + wave;
    const float* fp = F + row * D_ + lane * 4;
    float s = 0.f;
    #pragma unroll
    for (int j = 0; j < 4; j++) s += fp[j] * pw[lane * 4 + j];
    #pragma unroll
    for (int off = 32; off > 0; off >>= 1) s += __shfl_down(s, off);
    if (lane == 0) {
        float p = 1.f / (1.f + __expf(-(s + pb[0])));
        out[row] = p;
    }
}

// ---------------------------------------------------------------------------
static void gemm2(hipStream_t st, const bf* Aq, const bf* Akv,
                  const bf* W, const float* bias, float* Cf, bf* Cb,
                  int M, int K, int Onum, int rowsPerA, long long aBatch,
                  long long aZ, long long wZ, long long cZ, int Z,
                  int qkv, int flags, int splitKc,
                  bf* Qd, bf* Kd, bf* Vd, int Lseq, int Lvt)
{
    dim3 g(Onum / 128, (M + 127) / 128, Z), blk(256, 1, 1);
    gemm2_k<<<g, blk, 0, st>>>(Aq, Akv, W, bias, Cf, Cb, M, K, Onum, rowsPerA,
                               aBatch, aZ, wZ, cZ, qkv, flags, splitKc,
                               Qd, Kd, Vd, Lseq, Lvt);
}

extern "C" void kernel_launch(void* const* d_in, const int* in_sizes, int n_in,
                              void* d_out, int out_size, void* d_ws, size_t ws_size,
                              hipStream_t stream)
{
    const int* qi  = (const int*)d_in[0];
    const int* ri  = (const int*)d_in[1];
    const int* qry = (const int*)d_in[2];
    const float* Memb = (const float*)d_in[3];
    const float* Eemb = (const float*)d_in[4];
    const float* Pp   = (const float*)d_in[5];
    const float* ainw = (const float*)d_in[6];
    const float* ainb = (const float*)d_in[7];
    const float* aoutw= (const float*)d_in[8];
    const float* aoutb= (const float*)d_in[9];
    const float* scw  = (const float*)d_in[10];
    const float* spw  = (const float*)d_in[11];
    const float* spb  = (const float*)d_in[12];
    const float* stew = (const float*)d_in[13];
    const float* steb = (const float*)d_in[14];
    const float* fw1  = (const float*)d_in[15];
    const float* fb1  = (const float*)d_in[16];
    const float* fw2  = (const float*)d_in[17];
    const float* fb2  = (const float*)d_in[18];
    const float* l1g  = (const float*)d_in[19];
    const float* l1b  = (const float*)d_in[20];
    const float* l2g  = (const float*)d_in[21];
    const float* l2b  = (const float*)d_in[22];
    const float* pw   = (const float*)d_in[23];
    const float* pb   = (const float*)d_in[24];
    float* out = (float*)d_out;
    float* outW = out + B_ * N_;

    const size_t BND = (size_t)B_ * N_ * D_;   // 4,194,304
    float* ws = (float*)d_ws;
    float* b10 = ws;                 // accumulator f32
    float* b0  = ws + 1 * BND;       // M f32 / tail scratch / FFN-out f32
    float* b1  = ws + 2 * BND;       // E f32 / ln2-out f32
    float* b8  = ws + 3 * BND;       // S_sg f32
    float* b9  = ws + 4 * BND;       // S_glob f32
    float* hp  = ws + 5 * BND;       // bf16 region start
    bf* b0h  = (bf*)(hp + 0 * (BND / 2));   // M bf16
    bf* b1h  = (bf*)(hp + 1 * (BND / 2));   // E bf16 / G bf16
    bf* b2h  = (bf*)(hp + 2 * (BND / 2));   // S_base bf16
    bf* b7h  = (bf*)(hp + 3 * (BND / 2));   // S_local bf16
    bf* b8h  = (bf*)(hp + 4 * (BND / 2));
    bf* b9h  = (bf*)(hp + 5 * (BND / 2));
    bf* b10h = (bf*)(hp + 6 * (BND / 2));
    bf* b11h = (bf*)(hp + 7 * (BND / 2));   // S_sg-pre / FFN hidden bf16
    bf* Qb   = (bf*)(hp + 8 * (BND / 2));
    bf* Kb   = (bf*)(hp + 9 * (BND / 2));
    bf* Vtb  = (bf*)(hp + 10 * (BND / 2));
    bf* Ob   = (bf*)(hp + 11 * (BND / 2));  // attn out bf16
    bf* BNNb = (bf*)(hp + 12 * (BND / 2));  // (B,N,N) bf16
    float* Ttab = hp + 12 * (BND / 2) + BND;        // (2048,256) f32
    bf* SWb  = (bf*)(Ttab + 2048 * 256);            // (2048,2048) bf16
    bf* Wb   = SWb + (size_t)2048 * 2048;           // weights bf16
    bf* ainwB = Wb;
    bf* aoutwB = ainwB + 6 * 768 * 256;
    bf* spwB  = aoutwB + 6 * 256 * 256;
    bf* stewB = spwB + 256 * 2048;
    bf* fw1B  = stewB + 256 * 512;
    bf* fw2B  = fw1B + 256 * 256;
    const int BNrows = B_ * N_;               // 16384
    const int BH = B_ * H_;                   // 256

    // --- weight conversions (bf16) ---
    conv_k<<<(6*768*256 + 255)/256, 256, 0, stream>>>(ainw, ainwB, 6*768*256);
    conv_k<<<(6*256*256 + 255)/256, 256, 0, stream>>>(aoutw, aoutwB, 6*256*256);
    conv_k<<<(256*2048 + 255)/256, 256, 0, stream>>>(spw, spwB, 256*2048);
    conv_k<<<(256*512 + 255)/256, 256, 0, stream>>>(stew, stewB, 256*512);
    conv_k<<<(256*256 + 255)/256, 256, 0, stream>>>(fw1, fw1B, 256*256);
    conv_k<<<(256*256 + 255)/256, 256, 0, stream>>>(fw2, fw2B, 256*256);

    // --- skill table: Ttab = softmax(scw) @ spw^T   (splitK=8, f32 atomics) ---
    rowsoftmax_k<<<2048, 256, 0, stream>>>(scw, SWb);
    zero4_k<<<(2048 * 256) / 1024, 256, 0, stream>>>((float4*)Ttab);
    gemm2(stream, SWb, SWb, spwB, nullptr, Ttab, nullptr, 2048, 2048, 256,
          2048, 0, 0, 0, 0, 8, 0, 4, 256, nullptr, nullptr, nullptr, 0, 0);

    // --- embeddings ---
    embed_k<<<BNrows, 256, 0, stream>>>(qi, ri, qry, Memb, Eemb, Pp, b0, b1, b0h, b1h);

    // --- attn 0: q=E, kv=M, causal, head-mean -> outW directly ---
    gemm2(stream, b1h, b0h, ainwB + 0, ainb + 0, nullptr, nullptr, BNrows, 256, 768,
          BNrows, 0, 0, 0, 0, 1, 1, 0, 0, Qb, Kb, Vtb, N_, N_);
    attn_mean_k<<<dim3(32, B_), 256, 0, stream>>>(Qb, Kb, Vtb, Ob, outW);
    gemm2(stream, Ob, Ob, aoutwB + 0, aoutb + 0, b10, nullptr, BNrows, 256, 256,
          BNrows, 0, 0, 0, 0, 1, 0, 0, 0, nullptr, nullptr, nullptr, 0, 0);
    // S_base = LN1(proj + M + E): bf16 out + f32 accumulator init
    ln_k<<<BNrows, 256, 0, stream>>>(b10, b0, b1, l1g, l1b, nullptr, b2h, b10);

    // --- attn 1 (local, LW=25, causal) on S_base tail ---
    gemm2(stream, b2h + (size_t)(N_ - LW_) * D_, b2h + (size_t)(N_ - LW_) * D_,
          ainwB + 1 * 196608, ainb + 768, nullptr, nullptr, B_ * LW_, 256, 768,
          LW_, (long long)N_ * D_, 0, 0, 0, 1, 1, 0, 0, Qb, Kb, Vtb, LW_, 32);
    attn_k<<<dim3(2, BH), 256, 0, stream>>>(Qb, Kb, Vtb, Ob, LW_, 32, 1);
    gemm2(stream, Ob, Ob, aoutwB + 1 * 65536, aoutb + 256, b0, nullptr, B_ * LW_,
          256, 256, B_ * LW_, 0, 0, 0, 0, 1, 0, 0, 0, nullptr, nullptr, nullptr, 0, 0);
    scatterlocal_k<<<BNrows, 256, 0, stream>>>(b0, b7h, b10);

    // --- skill group path ---
    gather_k<<<BNrows, 256, 0, stream>>>(qi, Ttab, spb, b1h);   // G bf16
    gemm2(stream, b2h, b2h, b1h, nullptr, nullptr, BNNb, N_, 256, N_,
          N_, 0, (long long)N_ * D_, (long long)N_ * D_, (long long)N_ * N_, B_,
          0, 0, 0, nullptr, nullptr, nullptr, 0, 0);
    gemm2(stream, BNNb, BNNb, stewB, steb, nullptr, b11h, BNrows, 512, 256,
          BNrows, 0, 0, 0, 0, 1, 0, 0, 0, nullptr, nullptr, nullptr, 0, 0);
    gemm2(stream, b11h, b11h, ainwB + 2 * 196608, ainb + 2 * 768, nullptr, nullptr,
          BNrows, 256, 768, BNrows, 0, 0, 0, 0, 1, 1, 0, 0, Qb, Kb, Vtb, N_, N_);
    attn_k<<<dim3(32, BH), 256, 0, stream>>>(Qb, Kb, Vtb, Ob, N_, N_, 0);
    gemm2(stream, Ob, Ob, aoutwB + 2 * 65536, aoutb + 2 * 256, b8, b8h, BNrows,
          256, 256, BNrows, 0, 0, 0, 0, 1, 0, 0, 0, nullptr, nullptr, nullptr, 0, 0);
    add_k<<<BNrows, 256, 0, stream>>>(b10, b8);

    // --- attn 3: self on S_base, causal -> S_glob ---
    gemm2(stream, b2h, b2h, ainwB + 3 * 196608, ainb + 3 * 768, nullptr, nullptr,
          BNrows, 256, 768, BNrows, 0, 0, 0, 0, 1, 1, 0, 0, Qb, Kb, Vtb, N_, N_);
    attn_k<<<dim3(32, BH), 256, 0, stream>>>(Qb, Kb, Vtb, Ob, N_, N_, 1);
    gemm2(stream, Ob, Ob, aoutwB + 3 * 65536, aoutb + 3 * 256, b9, b9h, BNrows,
          256, 256, BNrows, 0, 0, 0, 0, 1, 0, 0, 0, nullptr, nullptr, nullptr, 0, 0);
    add_k<<<BNrows, 256, 0, stream>>>(b10, b9);

    // --- attn 4: q=S_base, kv=S_local -> accumulate ---
    gemm2(stream, b2h, b7h, ainwB + 4 * 196608, ainb + 4 * 768, nullptr, nullptr,
          BNrows, 256, 768, BNrows, 0, 0, 0, 0, 1, 1, 0, 0, Qb, Kb, Vtb, N_, N_);
    attn_k<<<dim3(32, BH), 256, 0, stream>>>(Qb, Kb, Vtb, Ob, N_, N_, 0);
    gemm2(stream, Ob, Ob, aoutwB + 4 * 65536, aoutb + 4 * 256, b10, nullptr, BNrows,
          256, 256, BNrows, 0, 0, 0, 0, 1, 0, 2, 0, nullptr, nullptr, nullptr, 0, 0);

    // --- attn 5: q=S_sg, kv=S_glob -> accumulate + bf16 shadow ---
    gemm2(stream, b8h, b9h, ainwB + 5 * 196608, ainb + 5 * 768, nullptr, nullptr,
          BNrows, 256, 768, BNrows, 0, 0, 0, 0, 1, 1, 0, 0, Qb, Kb, Vtb, N_, N_);
    attn_k<<<dim3(32, BH), 256, 0, stream>>>(Qb, Kb, Vtb, Ob, N_, N_, 0);
    gemm2(stream, Ob, Ob, aoutwB + 5 * 65536, aoutb + 5 * 256, b10, b10h, BNrows,
          256, 256, BNrows, 0, 0, 0, 0, 1, 0, 2, 0, nullptr, nullptr, nullptr, 0, 0);

    // --- FFN + LN2 + prediction ---
    gemm2(stream, b10h, b10h, fw1B, fb1, nullptr, b11h, BNrows, 256, 256,
          BNrows, 0, 0, 0, 0, 1, 0, 1, 0, nullptr, nullptr, nullptr, 0, 0);
    gemm2(stream, b11h, b11h, fw2B, fb2, b0, nullptr, BNrows, 256, 256,
          BNrows, 0, 0, 0, 0, 1, 0, 0, 0, nullptr, nullptr, nullptr, 0, 0);
    ln_k<<<BNrows, 256, 0, stream>>>(b0, b10, nullptr, l2g, l2b, b1, nullptr, nullptr);
    pred_k<<<BNrows / 4, 256, 0, stream>>>(b1, pw, pb, out);
}

// Round 7
// 1301.394 us; speedup vs baseline: 5.8211x; 1.0269x over previous
//
#include <hip/hip_runtime.h>
#include <hip/hip_bf16.h>

#define B_  32
#define N_  512
#define D_  256
#define H_  8
#define HD_ 32
#define LW_ 25

typedef __hip_bfloat16 bf;
typedef __attribute__((ext_vector_type(8))) short short8;
typedef __attribute__((ext_vector_type(4))) float f32x4;

__device__ __forceinline__ void gload16(const void* g, void* l) {
    __builtin_amdgcn_global_load_lds(
        (const __attribute__((address_space(1))) unsigned int*)g,
        (__attribute__((address_space(3))) unsigned int*)l, 16, 0, 0);
}

// ---------------------------------------------------------------------------
// MFMA bf16 GEMM: C[m,o] = sum_k A[m,k] * W[o,k] (+bias). A,W bf16.
// Tile 128x128, BK=32, 4 waves x (64x64). global_load_lds staging (16B).
// flags: 1=relu, 2=accumulate into Cf, 4=atomicAdd (splitK).
// Cacc: optional second accumulator (Cacc[ci] += v).
// qkvmode: scatter to bf16 Q (BH,L,32), K (BH,L,32), V^T (BH,32,Lvt).
// ---------------------------------------------------------------------------
__global__ __launch_bounds__(256) void gemm2_k(
    const bf* Aq, const bf* Akv, const bf* W, const float* bias,
    float* Cf, bf* Cb, float* Cacc,
    int M, int K, int Onum,
    int rowsPerA, long long aBatch,
    long long aZ, long long wZ, long long cZ,
    int qkvmode, int flags, int splitKc,
    bf* Qd, bf* Kd, bf* Vd, int Lseq, int Lvt)
{
    __shared__ __align__(16) bf As[128 * 32];
    __shared__ __align__(16) bf Bs[128 * 32];
    const int tid = threadIdx.x;
    const int o0 = blockIdx.x * 128;
    const int m0 = blockIdx.y * 128;
    const int z  = blockIdx.z;
    const bf* A = (qkvmode && o0 >= 256) ? Akv : Aq;
    const bf* Wp = W;
    int kStart = 0, kEnd = K;
    if (splitKc > 0) {
        kStart = z * splitKc;
        kEnd   = min(K, kStart + splitKc);
    } else {
        A  += (long long)z * aZ;
        Wp += (long long)z * wZ;
        if (Cf) Cf += (long long)z * cZ;
        if (Cb) Cb += (long long)z * cZ;
    }

    const int w = tid >> 6, lane = tid & 63;
    const int col = lane & 15, quad = lane >> 4;
    const int wm = (w & 1) * 64;
    const int wn = (w >> 1) * 64;

    const int sidx0 = tid, sidx1 = tid + 256;
    long long arow0, arow1;
    {
        int m = m0 + (sidx0 >> 2);
        arow0 = (long long)(m / rowsPerA) * aBatch + (long long)(m % rowsPerA) * K;
        m = m0 + (sidx1 >> 2);
        arow1 = (long long)(m / rowsPerA) * aBatch + (long long)(m % rowsPerA) * K;
    }
    const long long wrow0 = (long long)(o0 + (sidx0 >> 2)) * K;
    const long long wrow1 = (long long)(o0 + (sidx1 >> 2)) * K;
    const int ac0 = (sidx0 & 3) * 8, ac1 = (sidx1 & 3) * 8;

    f32x4 acc[4][4];
    #pragma unroll
    for (int mt = 0; mt < 4; mt++)
        #pragma unroll
        for (int nt = 0; nt < 4; nt++)
            acc[mt][nt] = (f32x4)0.f;

    for (int k0 = kStart; k0 < kEnd; k0 += 32) {
        gload16(A + arow0 + k0 + ac0, As + sidx0 * 8);
        gload16(A + arow1 + k0 + ac1, As + sidx1 * 8);
        gload16(Wp + wrow0 + k0 + ac0, Bs + sidx0 * 8);
        gload16(Wp + wrow1 + k0 + ac1, Bs + sidx1 * 8);
        __syncthreads();
        short8 af[4], bfr[4];
        #pragma unroll
        for (int mt = 0; mt < 4; mt++)
            af[mt] = *(const short8*)(As + (wm + mt * 16 + col) * 32 + quad * 8);
        #pragma unroll
        for (int nt = 0; nt < 4; nt++)
            bfr[nt] = *(const short8*)(Bs + (wn + nt * 16 + col) * 32 + quad * 8);
        #pragma unroll
        for (int mt = 0; mt < 4; mt++)
            #pragma unroll
            for (int nt = 0; nt < 4; nt++)
                acc[mt][nt] = __builtin_amdgcn_mfma_f32_16x16x32_bf16(
                    af[mt], bfr[nt], acc[mt][nt], 0, 0, 0);
        __syncthreads();
    }

    #pragma unroll
    for (int mt = 0; mt < 4; mt++) {
        #pragma unroll
        for (int nt = 0; nt < 4; nt++) {
            const int o = o0 + wn + nt * 16 + col;
            #pragma unroll
            for (int r = 0; r < 4; r++) {
                const int m = m0 + wm + mt * 16 + quad * 4 + r;
                if (m >= M) continue;
                float v = acc[mt][nt][r];
                if (bias) v += bias[o];
                if (flags & 1) v = fmaxf(v, 0.f);
                if (qkvmode) {
                    int which = o >> 8;
                    int oo = o & 255;
                    int hh = oo >> 5, j2 = oo & 31;
                    int bb = m / Lseq, nn = m % Lseq;
                    int bh = bb * H_ + hh;
                    bf hv = __float2bfloat16(v);
                    if (which == 0)
                        Qd[((size_t)bh * Lseq + nn) * HD_ + j2] = hv;
                    else if (which == 1)
                        Kd[((size_t)bh * Lseq + nn) * HD_ + j2] = hv;
                    else
                        Vd[((size_t)bh * HD_ + j2) * Lvt + nn] = hv;
                } else if (flags & 4) {
                    atomicAdd(Cf + (long long)m * Onum + o, v);
                } else {
                    long long ci = (long long)m * Onum + o;
                    if (flags & 2) v += Cf[ci];
                    if (Cf) Cf[ci] = v;
                    if (Cb) Cb[ci] = __float2bfloat16(v);
                    if (Cacc) Cacc[ci] += v;
                }
            }
        }
    }
}

// ---------------------------------------------------------------------------
// MFMA attention v2. Block = (q-tile 16, bh-group), 4 waves.
// Wave w owns key-chunks c with c%4==w (32 keys each) -> P store/PV read are
// wave-private (no barrier). In-register softmax: 2 tiny LDS exchanges.
// Q,K: (BH,L,32) bf16. Vt: (BH,32,Lvt) bf16. O: (B*L,256) bf16.
// MEAN: loop nhl heads, head-mean of probs in registers -> meanW (B,N,N).
// ---------------------------------------------------------------------------
#define SP 520
#define OPS 34

template<int MEAN>
__global__ __launch_bounds__(256) void attn2_k(
    const bf* Qb, const bf* Kb, const bf* Vtb,
    bf* O, float* meanW, int L, int Lvt, int causal, int nhl)
{
    __shared__ __align__(16) bf Sh[16 * SP];          // P (bf16)
    __shared__ __align__(16) float redm[2][16][4];
    __shared__ __align__(16) float Opart[4][16][OPS];
    const int tid = threadIdx.x;
    const int w = tid >> 6, lane = tid & 63;
    const int col = lane & 15, quad = lane >> 4;
    const int q0 = blockIdx.x * 16;
    const int bh0 = blockIdx.y * nhl;
    const int NCH = (L + 31) >> 5;
    const float scale = 0.17677669529663687f;  // 1/sqrt(32)
    const int cmax = causal ? min(NCH - 1, (q0 + 15) >> 5) : (NCH - 1);
    const int ncc = (w <= cmax) ? ((cmax - w) >> 2) + 1 : 0;

    f32x4 mreg[4][2];
    if (MEAN) {
        #pragma unroll
        for (int cc = 0; cc < 4; cc++)
            #pragma unroll
            for (int hf = 0; hf < 2; hf++) mreg[cc][hf] = (f32x4)0.f;
    }

    for (int hh = 0; hh < nhl; hh++) {
        const int bh = bh0 + hh;
        const int b = bh >> 3, h = bh & 7;
        const bf* Qh = Qb  + (size_t)bh * L * HD_;
        const bf* Kh = Kb  + (size_t)bh * L * HD_;
        const bf* Vh = Vtb + (size_t)bh * HD_ * Lvt;

        short8 aq = (short8)(short)0;
        if (q0 + col < L)
            aq = *(const short8*)(Qh + (size_t)(q0 + col) * HD_ + quad * 8);

        // ---- QK^T for own chunks ----
        f32x4 sc[4][2];
        #pragma unroll
        for (int cc = 0; cc < 4; cc++) {
            if (cc >= ncc) break;
            const int c = w + 4 * cc;
            #pragma unroll
            for (int hf = 0; hf < 2; hf++) {
                const int key = c * 32 + hf * 16 + col;
                short8 bk = (short8)(short)0;
                if (key < L)
                    bk = *(const short8*)(Kh + (size_t)key * HD_ + quad * 8);
                sc[cc][hf] = __builtin_amdgcn_mfma_f32_16x16x32_bf16(
                    aq, bk, (f32x4)0.f, 0, 0, 0);
            }
        }

        // ---- scale + mask + partial row-max (registers) ----
        float pm[4] = {-3e38f, -3e38f, -3e38f, -3e38f};
        #pragma unroll
        for (int cc = 0; cc < 4; cc++) {
            if (cc >= ncc) break;
            const int c = w + 4 * cc;
            #pragma unroll
            for (int hf = 0; hf < 2; hf++) {
                const int key = c * 32 + hf * 16 + col;
                #pragma unroll
                for (int r = 0; r < 4; r++) {
                    float v = sc[cc][hf][r] * scale;
                    if (key >= L || (causal && key > q0 + quad * 4 + r)) v = -1e9f;
                    sc[cc][hf][r] = v;
                    pm[r] = fmaxf(pm[r], v);
                }
            }
        }
        #pragma unroll
        for (int r = 0; r < 4; r++)
            #pragma unroll
            for (int off = 1; off < 16; off <<= 1)
                pm[r] = fmaxf(pm[r], __shfl_xor(pm[r], off));
        if (col == 0) {
            #pragma unroll
            for (int r = 0; r < 4; r++) redm[0][quad * 4 + r][w] = pm[r];
        }
        __syncthreads();
        float gm[4];
        #pragma unroll
        for (int r = 0; r < 4; r++) {
            f32x4 t = *(const f32x4*)redm[0][quad * 4 + r];
            gm[r] = fmaxf(fmaxf(t[0], t[1]), fmaxf(t[2], t[3]));
        }

        // ---- exp + partial sum (registers) ----
        float ps[4] = {0.f, 0.f, 0.f, 0.f};
        #pragma unroll
        for (int cc = 0; cc < 4; cc++) {
            if (cc >= ncc) break;
            #pragma unroll
            for (int hf = 0; hf < 2; hf++)
                #pragma unroll
                for (int r = 0; r < 4; r++) {
                    float e = __expf(sc[cc][hf][r] - gm[r]);
                    sc[cc][hf][r] = e;
                    ps[r] += e;
                }
        }
        #pragma unroll
        for (int r = 0; r < 4; r++)
            #pragma unroll
            for (int off = 1; off < 16; off <<= 1)
                ps[r] += __shfl_xor(ps[r], off);
        if (col == 0) {
            #pragma unroll
            for (int r = 0; r < 4; r++) redm[1][quad * 4 + r][w] = ps[r];
        }
        __syncthreads();
        float giv[4];
        #pragma unroll
        for (int r = 0; r < 4; r++) {
            f32x4 t = *(const f32x4*)redm[1][quad * 4 + r];
            giv[r] = 1.f / (t[0] + t[1] + t[2] + t[3]);
        }

        // ---- normalize, mean-accumulate, store P bf16 (wave-private) ----
        #pragma unroll
        for (int cc = 0; cc < 4; cc++) {
            if (cc >= ncc) break;
            const int c = w + 4 * cc;
            #pragma unroll
            for (int hf = 0; hf < 2; hf++)
                #pragma unroll
                for (int r = 0; r < 4; r++) {
                    float p = sc[cc][hf][r] * giv[r];
                    if (MEAN) mreg[cc][hf][r] += p;
                    Sh[(quad * 4 + r) * SP + c * 32 + hf * 16 + col] =
                        __float2bfloat16(p);
                }
        }

        // ---- PV on own chunks (no barrier needed) ----
        f32x4 oacc[2];
        oacc[0] = (f32x4)0.f; oacc[1] = (f32x4)0.f;
        #pragma unroll
        for (int cc = 0; cc < 4; cc++) {
            if (cc >= ncc) break;
            const int c = w + 4 * cc;
            const short8 ap = *(const short8*)(Sh + col * SP + c * 32 + quad * 8);
            #pragma unroll
            for (int hf = 0; hf < 2; hf++) {
                const short8 bv = *(const short8*)(Vh + (size_t)(hf * 16 + col) * Lvt
                                                   + c * 32 + quad * 8);
                oacc[hf] = __builtin_amdgcn_mfma_f32_16x16x32_bf16(ap, bv, oacc[hf], 0, 0, 0);
            }
        }

        // ---- cross-wave O reduction ----
        #pragma unroll
        for (int hf = 0; hf < 2; hf++)
            #pragma unroll
            for (int r = 0; r < 4; r++)
                Opart[w][quad * 4 + r][hf * 16 + col] = oacc[hf][r];
        __syncthreads();
        for (int e = tid; e < 512; e += 256) {
            int row = e >> 5, d = e & 31;
            float v = Opart[0][row][d] + Opart[1][row][d] +
                      Opart[2][row][d] + Opart[3][row][d];
            int n = q0 + row;
            if (n < L)
                O[((size_t)b * L + n) * D_ + h * HD_ + d] = __float2bfloat16(v);
        }
    }

    if (MEAN) {
        const size_t base = ((size_t)blockIdx.y * N_ + q0) * N_;
        #pragma unroll
        for (int cc = 0; cc < 4; cc++) {
            const int c = w + 4 * cc;
            #pragma unroll
            for (int hf = 0; hf < 2; hf++)
                #pragma unroll
                for (int r = 0; r < 4; r++)
                    meanW[base + (size_t)(quad * 4 + r) * N_ + c * 32 + hf * 16 + col]
                        = mreg[cc][hf][r] * 0.125f;
        }
    }
}

// ---------------------------------------------------------------------------
// Small kernels
// ---------------------------------------------------------------------------
__global__ void conv_k(const float* s, bf* d, int n) {
    int i = blockIdx.x * 256 + threadIdx.x;
    if (i < n) d[i] = __float2bfloat16(s[i]);
}

__global__ __launch_bounds__(256) void rowsoftmax_k(const float* in, bf* out) {
    __shared__ float red[256];
    const long long row = blockIdx.x;
    const int t = threadIdx.x;
    const float* ip = in + row * 2048;
    bf* op = out + row * 2048;
    float m = -3e38f;
    for (int k = t; k < 2048; k += 256) m = fmaxf(m, ip[k]);
    red[t] = m; __syncthreads();
    for (int s = 128; s > 0; s >>= 1) { if (t < s) red[t] = fmaxf(red[t], red[t + s]); __syncthreads(); }
    m = red[0]; __syncthreads();
    float ps = 0.f;
    float ev[8];
    #pragma unroll
    for (int i = 0; i < 8; i++) { ev[i] = __expf(ip[t + i * 256] - m); ps += ev[i]; }
    red[t] = ps; __syncthreads();
    for (int s = 128; s > 0; s >>= 1) { if (t < s) red[t] += red[t + s]; __syncthreads(); }
    const float inv = 1.f / red[0];
    #pragma unroll
    for (int i = 0; i < 8; i++) op[t + i * 256] = __float2bfloat16(ev[i] * inv);
}

__global__ void embed_k(const int* q, const int* r, const int* qry,
                        const float* Memb, const float* Eemb, const float* P,
                        float* M, float* E, bf* Mh, bf* Eh) {
    const int i = blockIdx.x; const int t = threadIdx.x;
    const int n = i & (N_ - 1);
    const int x = q[i] + 2048 * r[i];
    float mv = Memb[(long long)x * D_ + t] + P[(long long)n * D_ + t];
    float evv = Eemb[(long long)qry[i] * D_ + t];
    M[(long long)i * D_ + t] = mv;  Mh[(long long)i * D_ + t] = __float2bfloat16(mv);
    E[(long long)i * D_ + t] = evv; Eh[(long long)i * D_ + t] = __float2bfloat16(evv);
}

__global__ void gather_k(const int* q, const float* T, const float* spb, bf* G) {
    const int i = blockIdx.x; const int t = threadIdx.x;
    G[(long long)i * D_ + t] = __float2bfloat16(T[(long long)q[i] * D_ + t] + spb[t]);
}

__global__ __launch_bounds__(256) void ln_k(const float* xa, const float* xb, const float* xc,
                                            const float* g, const float* bta,
                                            float* outF, bf* outB, float* out2) {
    __shared__ float red[256];
    const long long row = blockIdx.x;
    const int t = threadIdx.x;
    float v = xa[row * D_ + t];
    if (xb) v += xb[row * D_ + t];
    if (xc) v += xc[row * D_ + t];
    red[t] = v; __syncthreads();
    for (int s = 128; s > 0; s >>= 1) { if (t < s) red[t] += red[t + s]; __syncthreads(); }
    const float mean = red[0] * (1.f / 256.f);
    __syncthreads();
    const float d = v - mean;
    red[t] = d * d; __syncthreads();
    for (int s = 128; s > 0; s >>= 1) { if (t < s) red[t] += red[t + s]; __syncthreads(); }
    const float var = red[0] * (1.f / 256.f);
    const float y = d * rsqrtf(var + 1e-5f) * g[t] + bta[t];
    if (outF) outF[row * D_ + t] = y;
    if (outB) outB[row * D_ + t] = __float2bfloat16(y);
    if (out2) out2[row * D_ + t] = y;
}

__global__ void scatterlocal_k(const float* tail, bf* Slocalh, float* Sacc) {
    const int i = blockIdx.x; const int t = threadIdx.x;
    const int n = i & (N_ - 1), b = i >> 9;
    float v = 0.f;
    if (n >= N_ - LW_) {
        v = tail[((long long)(b * LW_ + (n - (N_ - LW_)))) * D_ + t];
        Sacc[(long long)i * D_ + t] += v;
    }
    Slocalh[(long long)i * D_ + t] = __float2bfloat16(v);
}

__global__ void zero4_k(float4* p) {
    p[(long long)blockIdx.x * 256 + threadIdx.x] = make_float4(0.f, 0.f, 0.f, 0.f);
}

__global__ __launch_bounds__(256) void pred_k(const float* F, const float* pw, const float* pb,
                                              float* out) {
    const int tid = threadIdx.x;
    const int wave = tid >> 6, lane = tid & 63;
    const long long row = (long long)blockIdx.x * 4 + wave;
    const float* fp = F + row * D_ + lane * 4;
    float s = 0.f;
    #pragma unroll
    for (int j = 0; j < 4; j++) s += fp[j] * pw[lane * 4 + j];
    #pragma unroll
    for (int off = 32; off > 0; off >>= 1) s += __shfl_down(s, off);
    if (lane == 0) {
        float p = 1.f / (1.f + __expf(-(s + pb[0])));
        out[row] = p;
    }
}

// ---------------------------------------------------------------------------
static void gemm2(hipStream_t st, const bf* Aq, const bf* Akv,
                  const bf* W, const float* bias, float* Cf, bf* Cb, float* Cacc,
                  int M, int K, int Onum, int rowsPerA, long long aBatch,
                  long long aZ, long long wZ, long long cZ, int Z,
                  int qkv, int flags, int splitKc,
                  bf* Qd, bf* Kd, bf* Vd, int Lseq, int Lvt)
{
    dim3 g(Onum / 128, (M + 127) / 128, Z), blk(256, 1, 1);
    gemm2_k<<<g, blk, 0, st>>>(Aq, Akv, W, bias, Cf, Cb, Cacc, M, K, Onum, rowsPerA,
                               aBatch, aZ, wZ, cZ, qkv, flags, splitKc,
                               Qd, Kd, Vd, Lseq, Lvt);
}

extern "C" void kernel_launch(void* const* d_in, const int* in_sizes, int n_in,
                              void* d_out, int out_size, void* d_ws, size_t ws_size,
                              hipStream_t stream)
{
    const int* qi  = (const int*)d_in[0];
    const int* ri  = (const int*)d_in[1];
    const int* qry = (const int*)d_in[2];
    const float* Memb = (const float*)d_in[3];
    const float* Eemb = (const float*)d_in[4];
    const float* Pp   = (const float*)d_in[5];
    const float* ainw = (const float*)d_in[6];
    const float* ainb = (const float*)d_in[7];
    const float* aoutw= (const float*)d_in[8];
    const float* aoutb= (const float*)d_in[9];
    const float* scw  = (const float*)d_in[10];
    const float* spw  = (const float*)d_in[11];
    const float* spb  = (const float*)d_in[12];
    const float* stew = (const float*)d_in[13];
    const float* steb = (const float*)d_in[14];
    const float* fw1  = (const float*)d_in[15];
    const float* fb1  = (const float*)d_in[16];
    const float* fw2  = (const float*)d_in[17];
    const float* fb2  = (const float*)d_in[18];
    const float* l1g  = (const float*)d_in[19];
    const float* l1b  = (const float*)d_in[20];
    const float* l2g  = (const float*)d_in[21];
    const float* l2b  = (const float*)d_in[22];
    const float* pw   = (const float*)d_in[23];
    const float* pb   = (const float*)d_in[24];
    float* out = (float*)d_out;
    float* outW = out + B_ * N_;

    const size_t BND = (size_t)B_ * N_ * D_;   // 4,194,304
    float* ws = (float*)d_ws;
    float* b10 = ws;                 // accumulator f32
    float* b0  = ws + 1 * BND;       // M f32 / tail scratch / FFN-out f32
    float* b1  = ws + 2 * BND;       // E f32 / ln2-out f32
    float* b8  = ws + 3 * BND;       // S_sg f32
    float* b9  = ws + 4 * BND;       // S_glob f32
    float* hp  = ws + 5 * BND;       // bf16 region start
    bf* b0h  = (bf*)(hp + 0 * (BND / 2));   // M bf16
    bf* b1h  = (bf*)(hp + 1 * (BND / 2));   // E bf16 / G bf16
    bf* b2h  = (bf*)(hp + 2 * (BND / 2));   // S_base bf16
    bf* b7h  = (bf*)(hp + 3 * (BND / 2));   // S_local bf16
    bf* b8h  = (bf*)(hp + 4 * (BND / 2));
    bf* b9h  = (bf*)(hp + 5 * (BND / 2));
    bf* b10h = (bf*)(hp + 6 * (BND / 2));
    bf* b11h = (bf*)(hp + 7 * (BND / 2));   // S_sg-pre / FFN hidden bf16
    bf* Qb   = (bf*)(hp + 8 * (BND / 2));
    bf* Kb   = (bf*)(hp + 9 * (BND / 2));
    bf* Vtb  = (bf*)(hp + 10 * (BND / 2));
    bf* Ob   = (bf*)(hp + 11 * (BND / 2));  // attn out bf16
    bf* BNNb = (bf*)(hp + 12 * (BND / 2));  // (B,N,N) bf16
    float* Ttab = hp + 12 * (BND / 2) + BND;        // (2048,256) f32
    bf* SWb  = (bf*)(Ttab + 2048 * 256);            // (2048,2048) bf16
    bf* Wb   = SWb + (size_t)2048 * 2048;           // weights bf16
    bf* ainwB = Wb;
    bf* aoutwB = ainwB + 6 * 768 * 256;
    bf* spwB  = aoutwB + 6 * 256 * 256;
    bf* stewB = spwB + 256 * 2048;
    bf* fw1B  = stewB + 256 * 512;
    bf* fw2B  = fw1B + 256 * 256;
    const int BNrows = B_ * N_;               // 16384
    const int BH = B_ * H_;                   // 256

    // --- weight conversions (bf16) ---
    conv_k<<<(6*768*256 + 255)/256, 256, 0, stream>>>(ainw, ainwB, 6*768*256);
    conv_k<<<(6*256*256 + 255)/256, 256, 0, stream>>>(aoutw, aoutwB, 6*256*256);
    conv_k<<<(256*2048 + 255)/256, 256, 0, stream>>>(spw, spwB, 256*2048);
    conv_k<<<(256*512 + 255)/256, 256, 0, stream>>>(stew, stewB, 256*512);
    conv_k<<<(256*256 + 255)/256, 256, 0, stream>>>(fw1, fw1B, 256*256);
    conv_k<<<(256*256 + 255)/256, 256, 0, stream>>>(fw2, fw2B, 256*256);

    // --- skill table: Ttab = softmax(scw) @ spw^T   (splitK=8, f32 atomics) ---
    rowsoftmax_k<<<2048, 256, 0, stream>>>(scw, SWb);
    zero4_k<<<(2048 * 256) / 1024, 256, 0, stream>>>((float4*)Ttab);
    gemm2(stream, SWb, SWb, spwB, nullptr, Ttab, nullptr, nullptr, 2048, 2048, 256,
          2048, 0, 0, 0, 0, 8, 0, 4, 256, nullptr, nullptr, nullptr, 0, 0);

    // --- embeddings ---
    embed_k<<<BNrows, 256, 0, stream>>>(qi, ri, qry, Memb, Eemb, Pp, b0, b1, b0h, b1h);

    // --- attn 0: q=E, kv=M, causal, head-mean -> outW (registers) ---
    gemm2(stream, b1h, b0h, ainwB + 0, ainb + 0, nullptr, nullptr, nullptr, BNrows, 256, 768,
          BNrows, 0, 0, 0, 0, 1, 1, 0, 0, Qb, Kb, Vtb, N_, N_);
    attn2_k<1><<<dim3(32, B_), 256, 0, stream>>>(Qb, Kb, Vtb, Ob, outW, N_, N_, 1, H_);
    gemm2(stream, Ob, Ob, aoutwB + 0, aoutb + 0, b10, nullptr, nullptr, BNrows, 256, 256,
          BNrows, 0, 0, 0, 0, 1, 0, 0, 0, nullptr, nullptr, nullptr, 0, 0);
    // S_base = LN1(proj + M + E): bf16 out + f32 accumulator init
    ln_k<<<BNrows, 256, 0, stream>>>(b10, b0, b1, l1g, l1b, nullptr, b2h, b10);

    // --- attn 1 (local, LW=25, causal) on S_base tail ---
    gemm2(stream, b2h + (size_t)(N_ - LW_) * D_, b2h + (size_t)(N_ - LW_) * D_,
          ainwB + 1 * 196608, ainb + 768, nullptr, nullptr, nullptr, B_ * LW_, 256, 768,
          LW_, (long long)N_ * D_, 0, 0, 0, 1, 1, 0, 0, Qb, Kb, Vtb, LW_, 32);
    attn2_k<0><<<dim3(2, BH), 256, 0, stream>>>(Qb, Kb, Vtb, Ob, nullptr, LW_, 32, 1, 1);
    gemm2(stream, Ob, Ob, aoutwB + 1 * 65536, aoutb + 256, b0, nullptr, nullptr, B_ * LW_,
          256, 256, B_ * LW_, 0, 0, 0, 0, 1, 0, 0, 0, nullptr, nullptr, nullptr, 0, 0);
    scatterlocal_k<<<BNrows, 256, 0, stream>>>(b0, b7h, b10);

    // --- skill group path ---
    gather_k<<<BNrows, 256, 0, stream>>>(qi, Ttab, spb, b1h);   // G bf16
    gemm2(stream, b2h, b2h, b1h, nullptr, nullptr, BNNb, nullptr, N_, 256, N_,
          N_, 0, (long long)N_ * D_, (long long)N_ * D_, (long long)N_ * N_, B_,
          0, 0, 0, nullptr, nullptr, nullptr, 0, 0);
    gemm2(stream, BNNb, BNNb, stewB, steb, nullptr, b11h, nullptr, BNrows, 512, 256,
          BNrows, 0, 0, 0, 0, 1, 0, 0, 0, nullptr, nullptr, nullptr, 0, 0);
    gemm2(stream, b11h, b11h, ainwB + 2 * 196608, ainb + 2 * 768, nullptr, nullptr, nullptr,
          BNrows, 256, 768, BNrows, 0, 0, 0, 0, 1, 1, 0, 0, Qb, Kb, Vtb, N_, N_);
    attn2_k<0><<<dim3(32, BH), 256, 0, stream>>>(Qb, Kb, Vtb, Ob, nullptr, N_, N_, 0, 1);
    gemm2(stream, Ob, Ob, aoutwB + 2 * 65536, aoutb + 2 * 256, b8, b8h, b10, BNrows,
          256, 256, BNrows, 0, 0, 0, 0, 1, 0, 0, 0, nullptr, nullptr, nullptr, 0, 0);

    // --- attn 3: self on S_base, causal -> S_glob (+acc) ---
    gemm2(stream, b2h, b2h, ainwB + 3 * 196608, ainb + 3 * 768, nullptr, nullptr, nullptr,
          BNrows, 256, 768, BNrows, 0, 0, 0, 0, 1, 1, 0, 0, Qb, Kb, Vtb, N_, N_);
    attn2_k<0><<<dim3(32, BH), 256, 0, stream>>>(Qb, Kb, Vtb, Ob, nullptr, N_, N_, 1, 1);
    gemm2(stream, Ob, Ob, aoutwB + 3 * 65536, aoutb + 3 * 256, b9, b9h, b10, BNrows,
          256, 256, BNrows, 0, 0, 0, 0, 1, 0, 0, 0, nullptr, nullptr, nullptr, 0, 0);

    // --- attn 4: q=S_base, kv=S_local -> accumulate ---
    gemm2(stream, b2h, b7h, ainwB + 4 * 196608, ainb + 4 * 768, nullptr, nullptr, nullptr,
          BNrows, 256, 768, BNrows, 0, 0, 0, 0, 1, 1, 0, 0, Qb, Kb, Vtb, N_, N_);
    attn2_k<0><<<dim3(32, BH), 256, 0, stream>>>(Qb, Kb, Vtb, Ob, nullptr, N_, N_, 0, 1);
    gemm2(stream, Ob, Ob, aoutwB + 4 * 65536, aoutb + 4 * 256, b10, nullptr, nullptr, BNrows,
          256, 256, BNrows, 0, 0, 0, 0, 1, 0, 2, 0, nullptr, nullptr, nullptr, 0, 0);

    // --- attn 5: q=S_sg, kv=S_glob -> accumulate + bf16 shadow ---
    gemm2(stream, b8h, b9h, ainwB + 5 * 196608, ainb + 5 * 768, nullptr, nullptr, nullptr,
          BNrows, 256, 768, BNrows, 0, 0, 0, 0, 1, 1, 0, 0, Qb, Kb, Vtb, N_, N_);
    attn2_k<0><<<dim3(32, BH), 256, 0, stream>>>(Qb, Kb, Vtb, Ob, nullptr, N_, N_, 0, 1);
    gemm2(stream, Ob, Ob, aoutwB + 5 * 65536, aoutb + 5 * 256, b10, b10h, nullptr, BNrows,
          256, 256, BNrows, 0, 0, 0, 0, 1, 0, 2, 0, nullptr, nullptr, nullptr, 0, 0);

    // --- FFN + LN2 + prediction ---
    gemm2(stream, b10h, b10h, fw1B, fb1, nullptr, b11h, nullptr, BNrows, 256, 256,
          BNrows, 0, 0, 0, 0, 1, 0, 1, 0, nullptr, nullptr, nullptr, 0, 0);
    gemm2(stream, b11h, b11h, fw2B, fb2, b0, nullptr, nullptr, BNrows, 256, 256,
          BNrows, 0, 0, 0, 0, 1, 0, 0, 0, nullptr, nullptr, nullptr, 0, 0);
    ln_k<<<BNrows, 256, 0, stream>>>(b0, b10, nullptr, l2g, l2b, b1, nullptr, nullptr);
    pred_k<<<BNrows / 4, 256, 0, stream>>>(b1, pw, pb, out);
}

// Round 8
// 1261.738 us; speedup vs baseline: 6.0040x; 1.0314x over previous
//
#include <hip/hip_runtime.h>
#include <hip/hip_bf16.h>

#define B_  32
#define N_  512
#define D_  256
#define H_  8
#define HD_ 32
#define LW_ 25

typedef __hip_bfloat16 bf;
typedef __attribute__((ext_vector_type(8))) short short8;
typedef __attribute__((ext_vector_type(4))) float f32x4;

__device__ __forceinline__ void gload16(const void* g, void* l) {
    __builtin_amdgcn_global_load_lds(
        (const __attribute__((address_space(1))) unsigned int*)g,
        (__attribute__((address_space(3))) unsigned int*)l, 16, 0, 0);
}

// ---------------------------------------------------------------------------
// MFMA bf16 GEMM: C[m,o] = sum_k A[m,k]*W[o,k] (+bias). A,W bf16.
// Tile 128x128, BK=32, 4 waves x (64x64), global_load_lds staging.
// A address: (m/rowsPerA)*aBatch + (m%rowsPerA)*aRstride + k0*aKMul + (k&31)
//   standard: aRstride=K, aKMul=1. attn-O input: aRstride=32, aKMul=Lseq.
// flags: 1=relu, 2=accumulate into Cf, 4=atomicAdd (splitK).
// Cacc: optional second accumulator. qkvmode: scatter Q/K/V^T bf16.
// ---------------------------------------------------------------------------
__global__ __launch_bounds__(256) void gemm2_k(
    const bf* Aq, const bf* Akv, const bf* W, const float* bias,
    float* Cf, bf* Cb, float* Cacc,
    int M, int K, int Onum,
    int rowsPerA, long long aBatch, int aRstride, long long aKMul,
    long long aZ, long long wZ, long long cZ,
    int qkvmode, int flags, int splitKc,
    bf* Qd, bf* Kd, bf* Vd, int Lseq, int Lvt)
{
    __shared__ __align__(16) bf As[128 * 32];
    __shared__ __align__(16) bf Bs[128 * 32];
    const int tid = threadIdx.x;
    const int o0 = blockIdx.x * 128;
    const int m0 = blockIdx.y * 128;
    const int z  = blockIdx.z;
    const bf* A = (qkvmode && o0 >= 256) ? Akv : Aq;
    const bf* Wp = W;
    int kStart = 0, kEnd = K;
    if (splitKc > 0) {
        kStart = z * splitKc;
        kEnd   = min(K, kStart + splitKc);
    } else {
        A  += (long long)z * aZ;
        Wp += (long long)z * wZ;
        if (Cf) Cf += (long long)z * cZ;
        if (Cb) Cb += (long long)z * cZ;
    }

    const int w = tid >> 6, lane = tid & 63;
    const int col = lane & 15, quad = lane >> 4;
    const int wm = (w & 1) * 64;
    const int wn = (w >> 1) * 64;

    const int sidx0 = tid, sidx1 = tid + 256;
    long long arow0, arow1;
    {
        int m = m0 + (sidx0 >> 2);
        arow0 = (long long)(m / rowsPerA) * aBatch + (long long)(m % rowsPerA) * aRstride;
        m = m0 + (sidx1 >> 2);
        arow1 = (long long)(m / rowsPerA) * aBatch + (long long)(m % rowsPerA) * aRstride;
    }
    const long long wrow0 = (long long)(o0 + (sidx0 >> 2)) * K;
    const long long wrow1 = (long long)(o0 + (sidx1 >> 2)) * K;
    const int ac0 = (sidx0 & 3) * 8, ac1 = (sidx1 & 3) * 8;

    f32x4 acc[4][4];
    #pragma unroll
    for (int mt = 0; mt < 4; mt++)
        #pragma unroll
        for (int nt = 0; nt < 4; nt++)
            acc[mt][nt] = (f32x4)0.f;

    for (int k0 = kStart; k0 < kEnd; k0 += 32) {
        const long long ka = (long long)k0 * aKMul;
        gload16(A + arow0 + ka + ac0, As + sidx0 * 8);
        gload16(A + arow1 + ka + ac1, As + sidx1 * 8);
        gload16(Wp + wrow0 + k0 + ac0, Bs + sidx0 * 8);
        gload16(Wp + wrow1 + k0 + ac1, Bs + sidx1 * 8);
        __syncthreads();
        short8 af[4], bfr[4];
        #pragma unroll
        for (int mt = 0; mt < 4; mt++)
            af[mt] = *(const short8*)(As + (wm + mt * 16 + col) * 32 + quad * 8);
        #pragma unroll
        for (int nt = 0; nt < 4; nt++)
            bfr[nt] = *(const short8*)(Bs + (wn + nt * 16 + col) * 32 + quad * 8);
        #pragma unroll
        for (int mt = 0; mt < 4; mt++)
            #pragma unroll
            for (int nt = 0; nt < 4; nt++)
                acc[mt][nt] = __builtin_amdgcn_mfma_f32_16x16x32_bf16(
                    af[mt], bfr[nt], acc[mt][nt], 0, 0, 0);
        __syncthreads();
    }

    #pragma unroll
    for (int mt = 0; mt < 4; mt++) {
        #pragma unroll
        for (int nt = 0; nt < 4; nt++) {
            const int o = o0 + wn + nt * 16 + col;
            #pragma unroll
            for (int r = 0; r < 4; r++) {
                const int m = m0 + wm + mt * 16 + quad * 4 + r;
                if (m >= M) continue;
                float v = acc[mt][nt][r];
                if (bias) v += bias[o];
                if (flags & 1) v = fmaxf(v, 0.f);
                if (qkvmode) {
                    int which = o >> 8;
                    int oo = o & 255;
                    int hh = oo >> 5, j2 = oo & 31;
                    int bb = m / Lseq, nn = m % Lseq;
                    int bh = bb * H_ + hh;
                    bf hv = __float2bfloat16(v);
                    if (which == 0)
                        Qd[((size_t)bh * Lseq + nn) * HD_ + j2] = hv;
                    else if (which == 1)
                        Kd[((size_t)bh * Lseq + nn) * HD_ + j2] = hv;
                    else
                        Vd[((size_t)bh * HD_ + j2) * Lvt + nn] = hv;
                } else if (flags & 4) {
                    atomicAdd(Cf + (long long)m * Onum + o, v);
                } else {
                    long long ci = (long long)m * Onum + o;
                    if (flags & 2) v += Cf[ci];
                    if (Cf) Cf[ci] = v;
                    if (Cb) Cb[ci] = __float2bfloat16(v);
                    if (Cacc) Cacc[ci] += v;
                }
            }
        }
    }
}

// ---------------------------------------------------------------------------
// MFMA attention v3. Grid: x = bh (XCD-local), y = q-tile. 4 waves; wave w
// owns key-chunks c%4==w (32 keys). Register-prefetched K/V fragments.
// Q,K: (BH,L,32) bf16. Vt: (BH,32,Lvt) bf16. O: (BH,L,32) bf16 (contiguous).
// MEAN: x = b, loop 8 heads, head-mean of probs in registers -> meanW.
// ---------------------------------------------------------------------------
#define SP 520
#define OPS 34

template<int MEAN>
__global__ __launch_bounds__(256) void attn3_k(
    const bf* Qb, const bf* Kb, const bf* Vtb,
    bf* O, float* meanW, int L, int Lvt, int causal, int nhl)
{
    __shared__ __align__(16) bf Sh[16 * SP];
    __shared__ __align__(16) float redm[2][16][4];
    __shared__ __align__(16) float Opart[4][16][OPS];
    const int tid = threadIdx.x;
    const int w = tid >> 6, lane = tid & 63;
    const int col = lane & 15, quad = lane >> 4;
    const int q0 = blockIdx.y * 16;
    const int bh0 = blockIdx.x * nhl;
    const int NCH = (L + 31) >> 5;
    const float scale = 0.17677669529663687f;  // 1/sqrt(32)
    const int cmax = causal ? min(NCH - 1, (q0 + 15) >> 5) : (NCH - 1);
    const int ncc = (w <= cmax) ? ((cmax - w) >> 2) + 1 : 0;

    f32x4 mreg[4][2];
    if (MEAN) {
        #pragma unroll
        for (int cc = 0; cc < 4; cc++)
            #pragma unroll
            for (int hf = 0; hf < 2; hf++) mreg[cc][hf] = (f32x4)0.f;
    }

    for (int hh = 0; hh < nhl; hh++) {
        const int bh = bh0 + hh;
        const bf* Qh = Qb  + (size_t)bh * L * HD_;
        const bf* Kh = Kb  + (size_t)bh * L * HD_;
        const bf* Vh = Vtb + (size_t)bh * HD_ * Lvt;

        // ---- prefetch Q, K (and V if !MEAN) fragments ----
        short8 aq = (short8)(short)0;
        if (q0 + col < L)
            aq = *(const short8*)(Qh + (size_t)(q0 + col) * HD_ + quad * 8);
        short8 kfr[4][2], vfr[4][2];
        #pragma unroll
        for (int cc = 0; cc < 4; cc++) {
            if (cc >= ncc) break;
            const int c = w + 4 * cc;
            #pragma unroll
            for (int hf = 0; hf < 2; hf++) {
                const int key = c * 32 + hf * 16 + col;
                kfr[cc][hf] = (short8)(short)0;
                if (key < L)
                    kfr[cc][hf] = *(const short8*)(Kh + (size_t)key * HD_ + quad * 8);
                if (!MEAN)
                    vfr[cc][hf] = *(const short8*)(Vh + (size_t)(hf * 16 + col) * Lvt
                                                    + c * 32 + quad * 8);
            }
        }

        // ---- QK^T ----
        f32x4 sc[4][2];
        #pragma unroll
        for (int cc = 0; cc < 4; cc++) {
            if (cc >= ncc) break;
            #pragma unroll
            for (int hf = 0; hf < 2; hf++)
                sc[cc][hf] = __builtin_amdgcn_mfma_f32_16x16x32_bf16(
                    aq, kfr[cc][hf], (f32x4)0.f, 0, 0, 0);
        }

        // ---- scale + mask + partial row-max ----
        float pm[4] = {-3e38f, -3e38f, -3e38f, -3e38f};
        #pragma unroll
        for (int cc = 0; cc < 4; cc++) {
            if (cc >= ncc) break;
            const int c = w + 4 * cc;
            #pragma unroll
            for (int hf = 0; hf < 2; hf++) {
                const int key = c * 32 + hf * 16 + col;
                #pragma unroll
                for (int r = 0; r < 4; r++) {
                    float v = sc[cc][hf][r] * scale;
                    if (key >= L || (causal && key > q0 + quad * 4 + r)) v = -1e9f;
                    sc[cc][hf][r] = v;
                    pm[r] = fmaxf(pm[r], v);
                }
            }
        }
        #pragma unroll
        for (int r = 0; r < 4; r++)
            #pragma unroll
            for (int off = 1; off < 16; off <<= 1)
                pm[r] = fmaxf(pm[r], __shfl_xor(pm[r], off));
        if (col == 0) {
            #pragma unroll
            for (int r = 0; r < 4; r++) redm[0][quad * 4 + r][w] = pm[r];
        }
        __syncthreads();
        float gm[4];
        #pragma unroll
        for (int r = 0; r < 4; r++) {
            f32x4 t = *(const f32x4*)redm[0][quad * 4 + r];
            gm[r] = fmaxf(fmaxf(t[0], t[1]), fmaxf(t[2], t[3]));
        }

        // ---- exp + partial sum ----
        float ps[4] = {0.f, 0.f, 0.f, 0.f};
        #pragma unroll
        for (int cc = 0; cc < 4; cc++) {
            if (cc >= ncc) break;
            #pragma unroll
            for (int hf = 0; hf < 2; hf++)
                #pragma unroll
                for (int r = 0; r < 4; r++) {
                    float e = __expf(sc[cc][hf][r] - gm[r]);
                    sc[cc][hf][r] = e;
                    ps[r] += e;
                }
        }
        #pragma unroll
        for (int r = 0; r < 4; r++)
            #pragma unroll
            for (int off = 1; off < 16; off <<= 1)
                ps[r] += __shfl_xor(ps[r], off);
        if (col == 0) {
            #pragma unroll
            for (int r = 0; r < 4; r++) redm[1][quad * 4 + r][w] = ps[r];
        }
        __syncthreads();
        float giv[4];
        #pragma unroll
        for (int r = 0; r < 4; r++) {
            f32x4 t = *(const f32x4*)redm[1][quad * 4 + r];
            giv[r] = 1.f / (t[0] + t[1] + t[2] + t[3]);
        }

        // ---- normalize, mean-accumulate, store P bf16 (wave-private) ----
        #pragma unroll
        for (int cc = 0; cc < 4; cc++) {
            if (cc >= ncc) break;
            const int c = w + 4 * cc;
            #pragma unroll
            for (int hf = 0; hf < 2; hf++)
                #pragma unroll
                for (int r = 0; r < 4; r++) {
                    float p = sc[cc][hf][r] * giv[r];
                    if (MEAN) mreg[cc][hf][r] += p;
                    Sh[(quad * 4 + r) * SP + c * 32 + hf * 16 + col] =
                        __float2bfloat16(p);
                }
        }

        // ---- PV on own chunks (no barrier needed) ----
        f32x4 oacc[2];
        oacc[0] = (f32x4)0.f; oacc[1] = (f32x4)0.f;
        #pragma unroll
        for (int cc = 0; cc < 4; cc++) {
            if (cc >= ncc) break;
            const int c = w + 4 * cc;
            const short8 ap = *(const short8*)(Sh + col * SP + c * 32 + quad * 8);
            #pragma unroll
            for (int hf = 0; hf < 2; hf++) {
                short8 bv;
                if (!MEAN) bv = vfr[cc][hf];
                else bv = *(const short8*)(Vh + (size_t)(hf * 16 + col) * Lvt
                                            + c * 32 + quad * 8);
                oacc[hf] = __builtin_amdgcn_mfma_f32_16x16x32_bf16(ap, bv, oacc[hf], 0, 0, 0);
            }
        }

        // ---- cross-wave O reduction, contiguous (bh,L,32) write ----
        #pragma unroll
        for (int hf = 0; hf < 2; hf++)
            #pragma unroll
            for (int r = 0; r < 4; r++)
                Opart[w][quad * 4 + r][hf * 16 + col] = oacc[hf][r];
        __syncthreads();
        for (int e = tid; e < 512; e += 256) {
            int row = e >> 5, d = e & 31;
            float v = Opart[0][row][d] + Opart[1][row][d] +
                      Opart[2][row][d] + Opart[3][row][d];
            int n = q0 + row;
            if (n < L)
                O[((size_t)bh * L + n) * HD_ + d] = __float2bfloat16(v);
        }
        __syncthreads();
    }

    if (MEAN) {
        const size_t base = ((size_t)blockIdx.x * N_ + q0) * N_;
        #pragma unroll
        for (int cc = 0; cc < 4; cc++) {
            const int c = w + 4 * cc;
            #pragma unroll
            for (int hf = 0; hf < 2; hf++)
                #pragma unroll
                for (int r = 0; r < 4; r++)
                    meanW[base + (size_t)(quad * 4 + r) * N_ + c * 32 + hf * 16 + col]
                        = mreg[cc][hf][r] * 0.125f;
        }
    }
}

// ---------------------------------------------------------------------------
// Small kernels
// ---------------------------------------------------------------------------
__global__ void conv_k(const float* s, bf* d, int n) {
    int i = blockIdx.x * 256 + threadIdx.x;
    if (i < n) d[i] = __float2bfloat16(s[i]);
}

__global__ __launch_bounds__(256) void rowsoftmax_k(const float* in, bf* out) {
    __shared__ float red[256];
    const long long row = blockIdx.x;
    const int t = threadIdx.x;
    const float* ip = in + row * 2048;
    bf* op = out + row * 2048;
    float m = -3e38f;
    for (int k = t; k < 2048; k += 256) m = fmaxf(m, ip[k]);
    red[t] = m; __syncthreads();
    for (int s = 128; s > 0; s >>= 1) { if (t < s) red[t] = fmaxf(red[t], red[t + s]); __syncthreads(); }
    m = red[0]; __syncthreads();
    float ps = 0.f;
    float ev[8];
    #pragma unroll
    for (int i = 0; i < 8; i++) { ev[i] = __expf(ip[t + i * 256] - m); ps += ev[i]; }
    red[t] = ps; __syncthreads();
    for (int s = 128; s > 0; s >>= 1) { if (t < s) red[t] += red[t + s]; __syncthreads(); }
    const float inv = 1.f / red[0];
    #pragma unroll
    for (int i = 0; i < 8; i++) op[t + i * 256] = __float2bfloat16(ev[i] * inv);
}

__global__ void embed_k(const int* q, const int* r, const int* qry,
                        const float* Memb, const float* Eemb, const float* P,
                        float* M, float* E, bf* Mh, bf* Eh) {
    const int i = blockIdx.x; const int t = threadIdx.x;
    const int n = i & (N_ - 1);
    const int x = q[i] + 2048 * r[i];
    float mv = Memb[(long long)x * D_ + t] + P[(long long)n * D_ + t];
    float evv = Eemb[(long long)qry[i] * D_ + t];
    M[(long long)i * D_ + t] = mv;  Mh[(long long)i * D_ + t] = __float2bfloat16(mv);
    E[(long long)i * D_ + t] = evv; Eh[(long long)i * D_ + t] = __float2bfloat16(evv);
}

__global__ void gather_k(const int* q, const float* T, const float* spb, bf* G) {
    const int i = blockIdx.x; const int t = threadIdx.x;
    G[(long long)i * D_ + t] = __float2bfloat16(T[(long long)q[i] * D_ + t] + spb[t]);
}

__global__ __launch_bounds__(256) void ln_k(const float* xa, const float* xb, const float* xc,
                                            const float* g, const float* bta,
                                            float* outF, bf* outB, float* out2) {
    __shared__ float red[256];
    const long long row = blockIdx.x;
    const int t = threadIdx.x;
    float v = xa[row * D_ + t];
    if (xb) v += xb[row * D_ + t];
    if (xc) v += xc[row * D_ + t];
    red[t] = v; __syncthreads();
    for (int s = 128; s > 0; s >>= 1) { if (t < s) red[t] += red[t + s]; __syncthreads(); }
    const float mean = red[0] * (1.f / 256.f);
    __syncthreads();
    const float d = v - mean;
    red[t] = d * d; __syncthreads();
    for (int s = 128; s > 0; s >>= 1) { if (t < s) red[t] += red[t + s]; __syncthreads(); }
    const float var = red[0] * (1.f / 256.f);
    const float y = d * rsqrtf(var + 1e-5f) * g[t] + bta[t];
    if (outF) outF[row * D_ + t] = y;
    if (outB) outB[row * D_ + t] = __float2bfloat16(y);
    if (out2) out2[row * D_ + t] = y;
}

__global__ void scatterlocal_k(const float* tail, bf* Slocalh, float* Sacc) {
    const int i = blockIdx.x; const int t = threadIdx.x;
    const int n = i & (N_ - 1), b = i >> 9;
    float v = 0.f;
    if (n >= N_ - LW_) {
        v = tail[((long long)(b * LW_ + (n - (N_ - LW_)))) * D_ + t];
        Sacc[(long long)i * D_ + t] += v;
    }
    Slocalh[(long long)i * D_ + t] = __float2bfloat16(v);
}

__global__ void zero4_k(float4* p) {
    p[(long long)blockIdx.x * 256 + threadIdx.x] = make_float4(0.f, 0.f, 0.f, 0.f);
}

__global__ __launch_bounds__(256) void pred_k(const float* F, const float* pw, const float* pb,
                                              float* out) {
    const int tid = threadIdx.x;
    const int wave = tid >> 6, lane = tid & 63;
    const long long row = (long long)blockIdx.x * 4 + wave;
    const float* fp = F + row * D_ + lane * 4;
    float s = 0.f;
    #pragma unroll
    for (int j = 0; j < 4; j++) s += fp[j] * pw[lane * 4 + j];
    #pragma unroll
    for (int off = 32; off > 0; off >>= 1) s += __shfl_down(s, off);
    if (lane == 0) {
        float p = 1.f / (1.f + __expf(-(s + pb[0])));
        out[row] = p;
    }
}

// ---------------------------------------------------------------------------
static void gemm2(hipStream_t st, const bf* Aq, const bf* Akv,
                  const bf* W, const float* bias, float* Cf, bf* Cb, float* Cacc,
                  int M, int K, int Onum,
                  int rowsPerA, long long aBatch, int aRstride, long long aKMul,
                  long long aZ, long long wZ, long long cZ, int Z,
                  int qkv, int flags, int splitKc,
                  bf* Qd, bf* Kd, bf* Vd, int Lseq, int Lvt)
{
    dim3 g(Onum / 128, (M + 127) / 128, Z), blk(256, 1, 1);
    gemm2_k<<<g, blk, 0, st>>>(Aq, Akv, W, bias, Cf, Cb, Cacc, M, K, Onum,
                               rowsPerA, aBatch, aRstride, aKMul,
                               aZ, wZ, cZ, qkv, flags, splitKc,
                               Qd, Kd, Vd, Lseq, Lvt);
}

extern "C" void kernel_launch(void* const* d_in, const int* in_sizes, int n_in,
                              void* d_out, int out_size, void* d_ws, size_t ws_size,
                              hipStream_t stream)
{
    const int* qi  = (const int*)d_in[0];
    const int* ri  = (const int*)d_in[1];
    const int* qry = (const int*)d_in[2];
    const float* Memb = (const float*)d_in[3];
    const float* Eemb = (const float*)d_in[4];
    const float* Pp   = (const float*)d_in[5];
    const float* ainw = (const float*)d_in[6];
    const float* ainb = (const float*)d_in[7];
    const float* aoutw= (const float*)d_in[8];
    const float* aoutb= (const float*)d_in[9];
    const float* scw  = (const float*)d_in[10];
    const float* spw  = (const float*)d_in[11];
    const float* spb  = (const float*)d_in[12];
    const float* stew = (const float*)d_in[13];
    const float* steb = (const float*)d_in[14];
    const float* fw1  = (const float*)d_in[15];
    const float* fb1  = (const float*)d_in[16];
    const float* fw2  = (const float*)d_in[17];
    const float* fb2  = (const float*)d_in[18];
    const float* l1g  = (const float*)d_in[19];
    const float* l1b  = (const float*)d_in[20];
    const float* l2g  = (const float*)d_in[21];
    const float* l2b  = (const float*)d_in[22];
    const float* pw   = (const float*)d_in[23];
    const float* pb   = (const float*)d_in[24];
    float* out = (float*)d_out;
    float* outW = out + B_ * N_;

    const size_t BND = (size_t)B_ * N_ * D_;   // 4,194,304
    float* ws = (float*)d_ws;
    float* b10 = ws;                 // accumulator f32
    float* b0  = ws + 1 * BND;       // M f32 / tail scratch / FFN-out f32
    float* b1  = ws + 2 * BND;       // E f32 / ln2-out f32
    float* b8  = ws + 3 * BND;       // S_sg f32
    float* b9  = ws + 4 * BND;       // S_glob f32
    float* hp  = ws + 5 * BND;       // bf16 region start
    bf* b0h  = (bf*)(hp + 0 * (BND / 2));   // M bf16
    bf* b1h  = (bf*)(hp + 1 * (BND / 2));   // E bf16 / G bf16
    bf* b2h  = (bf*)(hp + 2 * (BND / 2));   // S_base bf16
    bf* b7h  = (bf*)(hp + 3 * (BND / 2));   // S_local bf16
    bf* b8h  = (bf*)(hp + 4 * (BND / 2));
    bf* b9h  = (bf*)(hp + 5 * (BND / 2));
    bf* b10h = (bf*)(hp + 6 * (BND / 2));
    bf* b11h = (bf*)(hp + 7 * (BND / 2));   // S_sg-pre / FFN hidden bf16
    bf* Qb   = (bf*)(hp + 8 * (BND / 2));
    bf* Kb   = (bf*)(hp + 9 * (BND / 2));
    bf* Vtb  = (bf*)(hp + 10 * (BND / 2));
    bf* Ob   = (bf*)(hp + 11 * (BND / 2));  // attn out bf16 (BH,L,32)
    bf* BNNb = (bf*)(hp + 12 * (BND / 2));  // (B,N,N) bf16
    float* Ttab = hp + 12 * (BND / 2) + BND;        // (2048,256) f32
    bf* SWb  = (bf*)(Ttab + 2048 * 256);            // (2048,2048) bf16
    bf* Wb   = SWb + (size_t)2048 * 2048;           // weights bf16
    bf* ainwB = Wb;
    bf* aoutwB = ainwB + 6 * 768 * 256;
    bf* spwB  = aoutwB + 6 * 256 * 256;
    bf* stewB = spwB + 256 * 2048;
    bf* fw1B  = stewB + 256 * 512;
    bf* fw2B  = fw1B + 256 * 256;
    const int BNrows = B_ * N_;               // 16384
    const int BH = B_ * H_;                   // 256
    const long long OBAT = 8LL * N_ * HD_;    // O batch stride (b) full attns
    const long long OBATL = 8LL * LW_ * HD_;  // O batch stride attn1

    // --- weight conversions (bf16) ---
    conv_k<<<(6*768*256 + 255)/256, 256, 0, stream>>>(ainw, ainwB, 6*768*256);
    conv_k<<<(6*256*256 + 255)/256, 256, 0, stream>>>(aoutw, aoutwB, 6*256*256);
    conv_k<<<(256*2048 + 255)/256, 256, 0, stream>>>(spw, spwB, 256*2048);
    conv_k<<<(256*512 + 255)/256, 256, 0, stream>>>(stew, stewB, 256*512);
    conv_k<<<(256*256 + 255)/256, 256, 0, stream>>>(fw1, fw1B, 256*256);
    conv_k<<<(256*256 + 255)/256, 256, 0, stream>>>(fw2, fw2B, 256*256);

    // --- skill table: Ttab = softmax(scw) @ spw^T   (splitK=8, f32 atomics) ---
    rowsoftmax_k<<<2048, 256, 0, stream>>>(scw, SWb);
    zero4_k<<<(2048 * 256) / 1024, 256, 0, stream>>>((float4*)Ttab);
    gemm2(stream, SWb, SWb, spwB, nullptr, Ttab, nullptr, nullptr, 2048, 2048, 256,
          2048, 0, 2048, 1, 0, 0, 0, 8, 0, 4, 256, nullptr, nullptr, nullptr, 0, 0);

    // --- embeddings ---
    embed_k<<<BNrows, 256, 0, stream>>>(qi, ri, qry, Memb, Eemb, Pp, b0, b1, b0h, b1h);

    // --- attn 0: q=E, kv=M, causal, head-mean -> outW ---
    gemm2(stream, b1h, b0h, ainwB + 0, ainb + 0, nullptr, nullptr, nullptr, BNrows, 256, 768,
          BNrows, 0, 256, 1, 0, 0, 0, 1, 1, 0, 0, Qb, Kb, Vtb, N_, N_);
    attn3_k<1><<<dim3(B_, 32), 256, 0, stream>>>(Qb, Kb, Vtb, Ob, outW, N_, N_, 1, H_);
    gemm2(stream, Ob, Ob, aoutwB + 0, aoutb + 0, b10, nullptr, nullptr, BNrows, 256, 256,
          N_, OBAT, HD_, N_, 0, 0, 0, 1, 0, 0, 0, nullptr, nullptr, nullptr, 0, 0);
    // S_base = LN1(proj + M + E)
    ln_k<<<BNrows, 256, 0, stream>>>(b10, b0, b1, l1g, l1b, nullptr, b2h, b10);

    // --- attn 1 (local, LW=25, causal) on S_base tail ---
    gemm2(stream, b2h + (size_t)(N_ - LW_) * D_, b2h + (size_t)(N_ - LW_) * D_,
          ainwB + 1 * 196608, ainb + 768, nullptr, nullptr, nullptr, B_ * LW_, 256, 768,
          LW_, (long long)N_ * D_, 256, 1, 0, 0, 0, 1, 1, 0, 0, Qb, Kb, Vtb, LW_, 32);
    attn3_k<0><<<dim3(BH, 2), 256, 0, stream>>>(Qb, Kb, Vtb, Ob, nullptr, LW_, 32, 1, 1);
    gemm2(stream, Ob, Ob, aoutwB + 1 * 65536, aoutb + 256, b0, nullptr, nullptr, B_ * LW_,
          256, 256, LW_, OBATL, HD_, LW_, 0, 0, 0, 1, 0, 0, 0, nullptr, nullptr, nullptr, 0, 0);
    scatterlocal_k<<<BNrows, 256, 0, stream>>>(b0, b7h, b10);

    // --- skill group path ---
    gather_k<<<BNrows, 256, 0, stream>>>(qi, Ttab, spb, b1h);   // G bf16
    gemm2(stream, b2h, b2h, b1h, nullptr, nullptr, BNNb, nullptr, N_, 256, N_,
          N_, 0, 256, 1, (long long)N_ * D_, (long long)N_ * D_, (long long)N_ * N_, B_,
          0, 0, 0, nullptr, nullptr, nullptr, 0, 0);
    gemm2(stream, BNNb, BNNb, stewB, steb, nullptr, b11h, nullptr, BNrows, 512, 256,
          BNrows, 0, 512, 1, 0, 0, 0, 1, 0, 0, 0, nullptr, nullptr, nullptr, 0, 0);
    gemm2(stream, b11h, b11h, ainwB + 2 * 196608, ainb + 2 * 768, nullptr, nullptr, nullptr,
          BNrows, 256, 768, BNrows, 0, 256, 1, 0, 0, 0, 1, 1, 0, 0, Qb, Kb, Vtb, N_, N_);
    attn3_k<0><<<dim3(BH, 32), 256, 0, stream>>>(Qb, Kb, Vtb, Ob, nullptr, N_, N_, 0, 1);
    gemm2(stream, Ob, Ob, aoutwB + 2 * 65536, aoutb + 2 * 256, b8, b8h, b10, BNrows,
          256, 256, N_, OBAT, HD_, N_, 0, 0, 0, 1, 0, 0, 0, nullptr, nullptr, nullptr, 0, 0);

    // --- attn 3: self on S_base, causal -> S_glob (+acc) ---
    gemm2(stream, b2h, b2h, ainwB + 3 * 196608, ainb + 3 * 768, nullptr, nullptr, nullptr,
          BNrows, 256, 768, BNrows, 0, 256, 1, 0, 0, 0, 1, 1, 0, 0, Qb, Kb, Vtb, N_, N_);
    attn3_k<0><<<dim3(BH, 32), 256, 0, stream>>>(Qb, Kb, Vtb, Ob, nullptr, N_, N_, 1, 1);
    gemm2(stream, Ob, Ob, aoutwB + 3 * 65536, aoutb + 3 * 256, b9, b9h, b10, BNrows,
          256, 256, N_, OBAT, HD_, N_, 0, 0, 0, 1, 0, 0, 0, nullptr, nullptr, nullptr, 0, 0);

    // --- attn 4: q=S_base, kv=S_local -> accumulate ---
    gemm2(stream, b2h, b7h, ainwB + 4 * 196608, ainb + 4 * 768, nullptr, nullptr, nullptr,
          BNrows, 256, 768, BNrows, 0, 256, 1, 0, 0, 0, 1, 1, 0, 0, Qb, Kb, Vtb, N_, N_);
    attn3_k<0><<<dim3(BH, 32), 256, 0, stream>>>(Qb, Kb, Vtb, Ob, nullptr, N_, N_, 0, 1);
    gemm2(stream, Ob, Ob, aoutwB + 4 * 65536, aoutb + 4 * 256, b10, nullptr, nullptr, BNrows,
          256, 256, N_, OBAT, HD_, N_, 0, 0, 0, 1, 0, 2, 0, nullptr, nullptr, nullptr, 0, 0);

    // --- attn 5: q=S_sg, kv=S_glob -> accumulate + bf16 shadow ---
    gemm2(stream, b8h, b9h, ainwB + 5 * 196608, ainb + 5 * 768, nullptr, nullptr, nullptr,
          BNrows, 256, 768, BNrows, 0, 256, 1, 0, 0, 0, 1, 1, 0, 0, Qb, Kb, Vtb, N_, N_);
    attn3_k<0><<<dim3(BH, 32), 256, 0, stream>>>(Qb, Kb, Vtb, Ob, nullptr, N_, N_, 0, 1);
    gemm2(stream, Ob, Ob, aoutwB + 5 * 65536, aoutb + 5 * 256, b10, b10h, nullptr, BNrows,
          256, 256, N_, OBAT, HD_, N_, 0, 0, 0, 1, 0, 2, 0, nullptr, nullptr, nullptr, 0, 0);

    // --- FFN + LN2 + prediction ---
    gemm2(stream, b10h, b10h, fw1B, fb1, nullptr, b11h, nullptr, BNrows, 256, 256,
          BNrows, 0, 256, 1, 0, 0, 0, 1, 0, 1, 0, nullptr, nullptr, nullptr, 0, 0);
    gemm2(stream, b11h, b11h, fw2B, fb2, b0, nullptr, nullptr, BNrows, 256, 256,
          BNrows, 0, 256, 1, 0, 0, 0, 1, 0, 0, 0, nullptr, nullptr, nullptr, 0, 0);
    ln_k<<<BNrows, 256, 0, stream>>>(b0, b10, nullptr, l2g, l2b, b1, nullptr, nullptr);
    pred_k<<<BNrows / 4, 256, 0, stream>>>(b1, pw, pb, out);
}

// Round 9
// 1159.811 us; speedup vs baseline: 6.5317x; 1.0879x over previous
//
#include <hip/hip_runtime.h>
#include <hip/hip_bf16.h>

#define B_  32
#define N_  512
#define D_  256
#define H_  8
#define HD_ 32
#define LW_ 25

typedef __hip_bfloat16 bf;
typedef __attribute__((ext_vector_type(8))) short short8;
typedef __attribute__((ext_vector_type(4))) float f32x4;

__device__ __forceinline__ void gload16(const void* g, void* l) {
    __builtin_amdgcn_global_load_lds(
        (const __attribute__((address_space(1))) unsigned int*)g,
        (__attribute__((address_space(3))) unsigned int*)l, 16, 0, 0);
}

// 1/sqrt(32) * log2(e): folded into Q so attention uses raw exp2
#define QSC 0.2550349f

// ---------------------------------------------------------------------------
// MFMA bf16 GEMM: C[m,o] = sum_k A[m,k]*W[o,k] (+bias). A,W bf16.
// Tile 128x128, BK=32, 4 waves x (64x64), global_load_lds staging.
// A address: (m/rowsPerA)*aBatch + (m%rowsPerA)*aRstride + k0*aKMul + (k&31)
// flags: 1=relu, 2=accumulate into Cf, 4=atomicAdd (splitK).
// Cacc: optional second accumulator. qkvmode: scatter Q/K/V^T bf16 (Q scaled).
// ---------------------------------------------------------------------------
__global__ __launch_bounds__(256) void gemm2_k(
    const bf* Aq, const bf* Akv, const bf* W, const float* bias,
    float* Cf, bf* Cb, float* Cacc,
    int M, int K, int Onum,
    int rowsPerA, long long aBatch, int aRstride, long long aKMul,
    long long aZ, long long wZ, long long cZ,
    int qkvmode, int flags, int splitKc,
    bf* Qd, bf* Kd, bf* Vd, int Lseq, int Lvt)
{
    __shared__ __align__(16) bf As[128 * 32];
    __shared__ __align__(16) bf Bs[128 * 32];
    const int tid = threadIdx.x;
    const int o0 = blockIdx.x * 128;
    const int m0 = blockIdx.y * 128;
    const int z  = blockIdx.z;
    const bf* A = (qkvmode && o0 >= 256) ? Akv : Aq;
    const bf* Wp = W;
    int kStart = 0, kEnd = K;
    if (splitKc > 0) {
        kStart = z * splitKc;
        kEnd   = min(K, kStart + splitKc);
    } else {
        A  += (long long)z * aZ;
        Wp += (long long)z * wZ;
        if (Cf) Cf += (long long)z * cZ;
        if (Cb) Cb += (long long)z * cZ;
    }

    const int w = tid >> 6, lane = tid & 63;
    const int col = lane & 15, quad = lane >> 4;
    const int wm = (w & 1) * 64;
    const int wn = (w >> 1) * 64;

    const int sidx0 = tid, sidx1 = tid + 256;
    long long arow0, arow1;
    {
        int m = m0 + (sidx0 >> 2);
        arow0 = (long long)(m / rowsPerA) * aBatch + (long long)(m % rowsPerA) * aRstride;
        m = m0 + (sidx1 >> 2);
        arow1 = (long long)(m / rowsPerA) * aBatch + (long long)(m % rowsPerA) * aRstride;
    }
    const long long wrow0 = (long long)(o0 + (sidx0 >> 2)) * K;
    const long long wrow1 = (long long)(o0 + (sidx1 >> 2)) * K;
    const int ac0 = (sidx0 & 3) * 8, ac1 = (sidx1 & 3) * 8;

    f32x4 acc[4][4];
    #pragma unroll
    for (int mt = 0; mt < 4; mt++)
        #pragma unroll
        for (int nt = 0; nt < 4; nt++)
            acc[mt][nt] = (f32x4)0.f;

    for (int k0 = kStart; k0 < kEnd; k0 += 32) {
        const long long ka = (long long)k0 * aKMul;
        gload16(A + arow0 + ka + ac0, As + sidx0 * 8);
        gload16(A + arow1 + ka + ac1, As + sidx1 * 8);
        gload16(Wp + wrow0 + k0 + ac0, Bs + sidx0 * 8);
        gload16(Wp + wrow1 + k0 + ac1, Bs + sidx1 * 8);
        __syncthreads();
        short8 af[4], bfr[4];
        #pragma unroll
        for (int mt = 0; mt < 4; mt++)
            af[mt] = *(const short8*)(As + (wm + mt * 16 + col) * 32 + quad * 8);
        #pragma unroll
        for (int nt = 0; nt < 4; nt++)
            bfr[nt] = *(const short8*)(Bs + (wn + nt * 16 + col) * 32 + quad * 8);
        #pragma unroll
        for (int mt = 0; mt < 4; mt++)
            #pragma unroll
            for (int nt = 0; nt < 4; nt++)
                acc[mt][nt] = __builtin_amdgcn_mfma_f32_16x16x32_bf16(
                    af[mt], bfr[nt], acc[mt][nt], 0, 0, 0);
        __syncthreads();
    }

    #pragma unroll
    for (int mt = 0; mt < 4; mt++) {
        #pragma unroll
        for (int nt = 0; nt < 4; nt++) {
            const int o = o0 + wn + nt * 16 + col;
            #pragma unroll
            for (int r = 0; r < 4; r++) {
                const int m = m0 + wm + mt * 16 + quad * 4 + r;
                if (m >= M) continue;
                float v = acc[mt][nt][r];
                if (bias) v += bias[o];
                if (flags & 1) v = fmaxf(v, 0.f);
                if (qkvmode) {
                    int which = o >> 8;
                    int oo = o & 255;
                    int hh = oo >> 5, j2 = oo & 31;
                    int bb = m / Lseq, nn = m % Lseq;
                    int bh = bb * H_ + hh;
                    if (which == 0) {
                        Qd[((size_t)bh * Lseq + nn) * HD_ + j2] =
                            __float2bfloat16(v * QSC);
                    } else if (which == 1) {
                        Kd[((size_t)bh * Lseq + nn) * HD_ + j2] = __float2bfloat16(v);
                    } else {
                        Vd[((size_t)bh * HD_ + j2) * Lvt + nn] = __float2bfloat16(v);
                    }
                } else if (flags & 4) {
                    atomicAdd(Cf + (long long)m * Onum + o, v);
                } else {
                    long long ci = (long long)m * Onum + o;
                    if (flags & 2) v += Cf[ci];
                    if (Cf) Cf[ci] = v;
                    if (Cb) Cb[ci] = __float2bfloat16(v);
                    if (Cacc) Cacc[ci] += v;
                }
            }
        }
    }
}

// ---------------------------------------------------------------------------
// MFMA attention v4: flash-style per-wave softmax rescaling.
// Grid: x = bh (XCD-local), y = q-tile. Wave w owns key-chunks c%4==w.
// Per wave: local max m_w, unnormalized P = exp2(s - m_w), PV immediately
// (no barrier). One post-PV exchange combines: O = sum_w O_w*2^(m_w-M) / T.
// Q pre-scaled by QSC. Q,K: (BH,L,32) bf16. Vt: (BH,32,Lvt). O: (BH,L,32).
// MEAN: x = b, loops 8 heads, normalized-prob head-mean in registers.
// ---------------------------------------------------------------------------
#define SP 520
#define OPS 34

template<int MEAN>
__global__ __launch_bounds__(256) void attn4_k(
    const bf* Qb, const bf* Kb, const bf* Vtb,
    bf* O, float* meanW, int L, int Lvt, int causal, int nhl)
{
    __shared__ __align__(16) bf Sh[16 * SP];
    __shared__ __align__(16) float redm[2][16][4];
    __shared__ __align__(16) float invRow[16];
    __shared__ __align__(16) float Opart[4][16][OPS];
    const int tid = threadIdx.x;
    const int w = tid >> 6, lane = tid & 63;
    const int col = lane & 15, quad = lane >> 4;
    const int q0 = blockIdx.y * 16;
    const int bh0 = blockIdx.x * nhl;
    const int NCH = (L + 31) >> 5;
    const int cmax = causal ? min(NCH - 1, (q0 + 15) >> 5) : (NCH - 1);
    const int ncc = (w <= cmax) ? ((cmax - w) >> 2) + 1 : 0;

    f32x4 mreg[4][2];
    if (MEAN) {
        #pragma unroll
        for (int cc = 0; cc < 4; cc++)
            #pragma unroll
            for (int hf = 0; hf < 2; hf++) mreg[cc][hf] = (f32x4)0.f;
    }

    for (int hh = 0; hh < nhl; hh++) {
        const int bh = bh0 + hh;
        const bf* Qh = Qb  + (size_t)bh * L * HD_;
        const bf* Kh = Kb  + (size_t)bh * L * HD_;
        const bf* Vh = Vtb + (size_t)bh * HD_ * Lvt;

        // ---- prefetch fragments ----
        short8 aq = (short8)(short)0;
        if (q0 + col < L)
            aq = *(const short8*)(Qh + (size_t)(q0 + col) * HD_ + quad * 8);
        short8 kfr[4][2], vfr[4][2];
        #pragma unroll
        for (int cc = 0; cc < 4; cc++) {
            if (cc >= ncc) break;
            const int c = w + 4 * cc;
            #pragma unroll
            for (int hf = 0; hf < 2; hf++) {
                const int key = c * 32 + hf * 16 + col;
                kfr[cc][hf] = (short8)(short)0;
                if (key < L)
                    kfr[cc][hf] = *(const short8*)(Kh + (size_t)key * HD_ + quad * 8);
                vfr[cc][hf] = *(const short8*)(Vh + (size_t)(hf * 16 + col) * Lvt
                                                + c * 32 + quad * 8);
            }
        }

        // ---- QK^T (scores already in log2 domain via Q pre-scale) ----
        f32x4 sc[4][2];
        #pragma unroll
        for (int cc = 0; cc < 4; cc++) {
            if (cc >= ncc) break;
            #pragma unroll
            for (int hf = 0; hf < 2; hf++)
                sc[cc][hf] = __builtin_amdgcn_mfma_f32_16x16x32_bf16(
                    aq, kfr[cc][hf], (f32x4)0.f, 0, 0, 0);
        }

        // ---- wave-local mask + max ----
        float pm[4] = {-3e38f, -3e38f, -3e38f, -3e38f};
        #pragma unroll
        for (int cc = 0; cc < 4; cc++) {
            if (cc >= ncc) break;
            const int c = w + 4 * cc;
            #pragma unroll
            for (int hf = 0; hf < 2; hf++) {
                const int key = c * 32 + hf * 16 + col;
                #pragma unroll
                for (int r = 0; r < 4; r++) {
                    float v = sc[cc][hf][r];
                    if (causal && key > q0 + quad * 4 + r) v = -1e9f;
                    sc[cc][hf][r] = v;
                    pm[r] = fmaxf(pm[r], v);
                }
            }
        }
        #pragma unroll
        for (int r = 0; r < 4; r++)
            #pragma unroll
            for (int off = 1; off < 16; off <<= 1)
                pm[r] = fmaxf(pm[r], __shfl_xor(pm[r], off));

        // ---- exp2 + wave-local sum; store unnormalized P ----
        float ps[4] = {0.f, 0.f, 0.f, 0.f};
        #pragma unroll
        for (int cc = 0; cc < 4; cc++) {
            if (cc >= ncc) break;
            const int c = w + 4 * cc;
            #pragma unroll
            for (int hf = 0; hf < 2; hf++)
                #pragma unroll
                for (int r = 0; r < 4; r++) {
                    float e = __builtin_amdgcn_exp2f(sc[cc][hf][r] - pm[r]);
                    sc[cc][hf][r] = e;
                    ps[r] += e;
                    Sh[(quad * 4 + r) * SP + c * 32 + hf * 16 + col] =
                        __float2bfloat16(e);
                }
        }
        #pragma unroll
        for (int r = 0; r < 4; r++)
            #pragma unroll
            for (int off = 1; off < 16; off <<= 1)
                ps[r] += __shfl_xor(ps[r], off);

        // ---- PV on own chunks (wave-private, no barrier) ----
        f32x4 oacc[2];
        oacc[0] = (f32x4)0.f; oacc[1] = (f32x4)0.f;
        #pragma unroll
        for (int cc = 0; cc < 4; cc++) {
            if (cc >= ncc) break;
            const int c = w + 4 * cc;
            const short8 ap = *(const short8*)(Sh + col * SP + c * 32 + quad * 8);
            #pragma unroll
            for (int hf = 0; hf < 2; hf++)
                oacc[hf] = __builtin_amdgcn_mfma_f32_16x16x32_bf16(
                    ap, vfr[cc][hf], oacc[hf], 0, 0, 0);
        }

        // ---- exchange (m_w, s_w) ----
        if (col == 0) {
            #pragma unroll
            for (int r = 0; r < 4; r++) {
                redm[0][quad * 4 + r][w] = pm[r];
                redm[1][quad * 4 + r][w] = ps[r];
            }
        }
        __syncthreads();
        float esc[4], inv[4];
        #pragma unroll
        for (int r = 0; r < 4; r++) {
            f32x4 mw = *(const f32x4*)redm[0][quad * 4 + r];
            f32x4 sw = *(const f32x4*)redm[1][quad * 4 + r];
            float M = fmaxf(fmaxf(mw[0], mw[1]), fmaxf(mw[2], mw[3]));
            float T = sw[0] * __builtin_amdgcn_exp2f(mw[0] - M)
                    + sw[1] * __builtin_amdgcn_exp2f(mw[1] - M)
                    + sw[2] * __builtin_amdgcn_exp2f(mw[2] - M)
                    + sw[3] * __builtin_amdgcn_exp2f(mw[3] - M);
            esc[r] = __builtin_amdgcn_exp2f(pm[r] - M);
            inv[r] = 1.f / T;
        }
        if (w == 0 && col == 0) {
            #pragma unroll
            for (int r = 0; r < 4; r++) invRow[quad * 4 + r] = inv[r];
        }
        #pragma unroll
        for (int hf = 0; hf < 2; hf++)
            #pragma unroll
            for (int r = 0; r < 4; r++)
                Opart[w][quad * 4 + r][hf * 16 + col] = oacc[hf][r] * esc[r];
        if (MEAN) {
            #pragma unroll
            for (int cc = 0; cc < 4; cc++) {
                if (cc >= ncc) break;
                #pragma unroll
                for (int hf = 0; hf < 2; hf++)
                    #pragma unroll
                    for (int r = 0; r < 4; r++)
                        mreg[cc][hf][r] += sc[cc][hf][r] * (esc[r] * inv[r]);
            }
        }
        __syncthreads();

        // ---- combine + contiguous (bh,L,32) write ----
        for (int e = tid; e < 512; e += 256) {
            int row = e >> 5, d = e & 31;
            float v = (Opart[0][row][d] + Opart[1][row][d] +
                       Opart[2][row][d] + Opart[3][row][d]) * invRow[row];
            int n = q0 + row;
            if (n < L)
                O[((size_t)bh * L + n) * HD_ + d] = __float2bfloat16(v);
        }
        if (hh + 1 < nhl) __syncthreads();
    }

    if (MEAN) {
        const size_t base = ((size_t)blockIdx.x * N_ + q0) * N_;
        #pragma unroll
        for (int cc = 0; cc < 4; cc++) {
            const int c = w + 4 * cc;
            #pragma unroll
            for (int hf = 0; hf < 2; hf++)
                #pragma unroll
                for (int r = 0; r < 4; r++)
                    meanW[base + (size_t)(quad * 4 + r) * N_ + c * 32 + hf * 16 + col]
                        = mreg[cc][hf][r] * 0.125f;
        }
    }
}

// ---------------------------------------------------------------------------
// Small kernels
// ---------------------------------------------------------------------------
__global__ void conv_k(const float* s, bf* d, int n) {
    int i = blockIdx.x * 256 + threadIdx.x;
    if (i < n) d[i] = __float2bfloat16(s[i]);
}

__global__ __launch_bounds__(256) void rowsoftmax_k(const float* in, bf* out) {
    __shared__ float red[256];
    const long long row = blockIdx.x;
    const int t = threadIdx.x;
    const float* ip = in + row * 2048;
    bf* op = out + row * 2048;
    float m = -3e38f;
    for (int k = t; k < 2048; k += 256) m = fmaxf(m, ip[k]);
    red[t] = m; __syncthreads();
    for (int s = 128; s > 0; s >>= 1) { if (t < s) red[t] = fmaxf(red[t], red[t + s]); __syncthreads(); }
    m = red[0]; __syncthreads();
    float ps = 0.f;
    float ev[8];
    #pragma unroll
    for (int i = 0; i < 8; i++) { ev[i] = __expf(ip[t + i * 256] - m); ps += ev[i]; }
    red[t] = ps; __syncthreads();
    for (int s = 128; s > 0; s >>= 1) { if (t < s) red[t] += red[t + s]; __syncthreads(); }
    const float inv = 1.f / red[0];
    #pragma unroll
    for (int i = 0; i < 8; i++) op[t + i * 256] = __float2bfloat16(ev[i] * inv);
}

__global__ void embed_k(const int* q, const int* r, const int* qry,
                        const float* Memb, const float* Eemb, const float* P,
                        float* M, float* E, bf* Mh, bf* Eh) {
    const int i = blockIdx.x; const int t = threadIdx.x;
    const int n = i & (N_ - 1);
    const int x = q[i] + 2048 * r[i];
    float mv = Memb[(long long)x * D_ + t] + P[(long long)n * D_ + t];
    float evv = Eemb[(long long)qry[i] * D_ + t];
    M[(long long)i * D_ + t] = mv;  Mh[(long long)i * D_ + t] = __float2bfloat16(mv);
    E[(long long)i * D_ + t] = evv; Eh[(long long)i * D_ + t] = __float2bfloat16(evv);
}

__global__ void gather_k(const int* q, const float* T, const float* spb, bf* G) {
    const int i = blockIdx.x; const int t = threadIdx.x;
    G[(long long)i * D_ + t] = __float2bfloat16(T[(long long)q[i] * D_ + t] + spb[t]);
}

__global__ __launch_bounds__(256) void ln_k(const float* xa, const float* xb, const float* xc,
                                            const float* g, const float* bta,
                                            float* outF, bf* outB, float* out2) {
    __shared__ float red[256];
    const long long row = blockIdx.x;
    const int t = threadIdx.x;
    float v = xa[row * D_ + t];
    if (xb) v += xb[row * D_ + t];
    if (xc) v += xc[row * D_ + t];
    red[t] = v; __syncthreads();
    for (int s = 128; s > 0; s >>= 1) { if (t < s) red[t] += red[t + s]; __syncthreads(); }
    const float mean = red[0] * (1.f / 256.f);
    __syncthreads();
    const float d = v - mean;
    red[t] = d * d; __syncthreads();
    for (int s = 128; s > 0; s >>= 1) { if (t < s) red[t] += red[t + s]; __syncthreads(); }
    const float var = red[0] * (1.f / 256.f);
    const float y = d * rsqrtf(var + 1e-5f) * g[t] + bta[t];
    if (outF) outF[row * D_ + t] = y;
    if (outB) outB[row * D_ + t] = __float2bfloat16(y);
    if (out2) out2[row * D_ + t] = y;
}

__global__ void scatterlocal_k(const float* tail, bf* Slocalh, float* Sacc) {
    const int i = blockIdx.x; const int t = threadIdx.x;
    const int n = i & (N_ - 1), b = i >> 9;
    float v = 0.f;
    if (n >= N_ - LW_) {
        v = tail[((long long)(b * LW_ + (n - (N_ - LW_)))) * D_ + t];
        Sacc[(long long)i * D_ + t] += v;
    }
    Slocalh[(long long)i * D_ + t] = __float2bfloat16(v);
}

__global__ void zero4_k(float4* p) {
    p[(long long)blockIdx.x * 256 + threadIdx.x] = make_float4(0.f, 0.f, 0.f, 0.f);
}

__global__ __launch_bounds__(256) void pred_k(const float* F, const float* pw, const float* pb,
                                              float* out) {
    const int tid = threadIdx.x;
    const int wave = tid >> 6, lane = tid & 63;
    const long long row = (long long)blockIdx.x * 4 + wave;
    const float* fp = F + row * D_ + lane * 4;
    float s = 0.f;
    #pragma unroll
    for (int j = 0; j < 4; j++) s += fp[j] * pw[lane * 4 + j];
    #pragma unroll
    for (int off = 32; off > 0; off >>= 1) s += __shfl_down(s, off);
    if (lane == 0) {
        float p = 1.f / (1.f + __expf(-(s + pb[0])));
        out[row] = p;
    }
}

// ---------------------------------------------------------------------------
static void gemm2(hipStream_t st, const bf* Aq, const bf* Akv,
                  const bf* W, const float* bias, float* Cf, bf* Cb, float* Cacc,
                  int M, int K, int Onum,
                  int rowsPerA, long long aBatch, int aRstride, long long aKMul,
                  long long aZ, long long wZ, long long cZ, int Z,
                  int qkv, int flags, int splitKc,
                  bf* Qd, bf* Kd, bf* Vd, int Lseq, int Lvt)
{
    dim3 g(Onum / 128, (M + 127) / 128, Z), blk(256, 1, 1);
    gemm2_k<<<g, blk, 0, st>>>(Aq, Akv, W, bias, Cf, Cb, Cacc, M, K, Onum,
                               rowsPerA, aBatch, aRstride, aKMul,
                               aZ, wZ, cZ, qkv, flags, splitKc,
                               Qd, Kd, Vd, Lseq, Lvt);
}

extern "C" void kernel_launch(void* const* d_in, const int* in_sizes, int n_in,
                              void* d_out, int out_size, void* d_ws, size_t ws_size,
                              hipStream_t stream)
{
    const int* qi  = (const int*)d_in[0];
    const int* ri  = (const int*)d_in[1];
    const int* qry = (const int*)d_in[2];
    const float* Memb = (const float*)d_in[3];
    const float* Eemb = (const float*)d_in[4];
    const float* Pp   = (const float*)d_in[5];
    const float* ainw = (const float*)d_in[6];
    const float* ainb = (const float*)d_in[7];
    const float* aoutw= (const float*)d_in[8];
    const float* aoutb= (const float*)d_in[9];
    const float* scw  = (const float*)d_in[10];
    const float* spw  = (const float*)d_in[11];
    const float* spb  = (const float*)d_in[12];
    const float* stew = (const float*)d_in[13];
    const float* steb = (const float*)d_in[14];
    const float* fw1  = (const float*)d_in[15];
    const float* fb1  = (const float*)d_in[16];
    const float* fw2  = (const float*)d_in[17];
    const float* fb2  = (const float*)d_in[18];
    const float* l1g  = (const float*)d_in[19];
    const float* l1b  = (const float*)d_in[20];
    const float* l2g  = (const float*)d_in[21];
    const float* l2b  = (const float*)d_in[22];
    const float* pw   = (const float*)d_in[23];
    const float* pb   = (const float*)d_in[24];
    float* out = (float*)d_out;
    float* outW = out + B_ * N_;

    const size_t BND = (size_t)B_ * N_ * D_;   // 4,194,304
    float* ws = (float*)d_ws;
    float* b10 = ws;                 // accumulator f32
    float* b0  = ws + 1 * BND;       // M f32 / tail scratch / FFN-out f32
    float* b1  = ws + 2 * BND;       // E f32 / ln2-out f32
    float* b8  = ws + 3 * BND;       // S_sg f32
    float* b9  = ws + 4 * BND;       // S_glob f32
    float* hp  = ws + 5 * BND;       // bf16 region start
    bf* b0h  = (bf*)(hp + 0 * (BND / 2));   // M bf16
    bf* b1h  = (bf*)(hp + 1 * (BND / 2));   // E bf16 / G bf16
    bf* b2h  = (bf*)(hp + 2 * (BND / 2));   // S_base bf16
    bf* b7h  = (bf*)(hp + 3 * (BND / 2));   // S_local bf16
    bf* b8h  = (bf*)(hp + 4 * (BND / 2));
    bf* b9h  = (bf*)(hp + 5 * (BND / 2));
    bf* b10h = (bf*)(hp + 6 * (BND / 2));
    bf* b11h = (bf*)(hp + 7 * (BND / 2));   // S_sg-pre / FFN hidden bf16
    bf* Qb   = (bf*)(hp + 8 * (BND / 2));
    bf* Kb   = (bf*)(hp + 9 * (BND / 2));
    bf* Vtb  = (bf*)(hp + 10 * (BND / 2));
    bf* Ob   = (bf*)(hp + 11 * (BND / 2));  // attn out bf16 (BH,L,32)
    bf* BNNb = (bf*)(hp + 12 * (BND / 2));  // (B,N,N) bf16
    float* Ttab = hp + 12 * (BND / 2) + BND;        // (2048,256) f32
    bf* SWb  = (bf*)(Ttab + 2048 * 256);            // (2048,2048) bf16
    bf* Wb   = SWb + (size_t)2048 * 2048;           // weights bf16
    bf* ainwB = Wb;
    bf* aoutwB = ainwB + 6 * 768 * 256;
    bf* spwB  = aoutwB + 6 * 256 * 256;
    bf* stewB = spwB + 256 * 2048;
    bf* fw1B  = stewB + 256 * 512;
    bf* fw2B  = fw1B + 256 * 256;
    const int BNrows = B_ * N_;               // 16384
    const int BH = B_ * H_;                   // 256
    const long long OBAT = 8LL * N_ * HD_;    // O batch stride (b) full attns
    const long long OBATL = 8LL * LW_ * HD_;  // O batch stride attn1

    // --- weight conversions (bf16) ---
    conv_k<<<(6*768*256 + 255)/256, 256, 0, stream>>>(ainw, ainwB, 6*768*256);
    conv_k<<<(6*256*256 + 255)/256, 256, 0, stream>>>(aoutw, aoutwB, 6*256*256);
    conv_k<<<(256*2048 + 255)/256, 256, 0, stream>>>(spw, spwB, 256*2048);
    conv_k<<<(256*512 + 255)/256, 256, 0, stream>>>(stew, stewB, 256*512);
    conv_k<<<(256*256 + 255)/256, 256, 0, stream>>>(fw1, fw1B, 256*256);
    conv_k<<<(256*256 + 255)/256, 256, 0, stream>>>(fw2, fw2B, 256*256);

    // --- skill table: Ttab = softmax(scw) @ spw^T   (splitK=8, f32 atomics) ---
    rowsoftmax_k<<<2048, 256, 0, stream>>>(scw, SWb);
    zero4_k<<<(2048 * 256) / 1024, 256, 0, stream>>>((float4*)Ttab);
    gemm2(stream, SWb, SWb, spwB, nullptr, Ttab, nullptr, nullptr, 2048, 2048, 256,
          2048, 0, 2048, 1, 0, 0, 0, 8, 0, 4, 256, nullptr, nullptr, nullptr, 0, 0);

    // --- embeddings ---
    embed_k<<<BNrows, 256, 0, stream>>>(qi, ri, qry, Memb, Eemb, Pp, b0, b1, b0h, b1h);

    // --- attn 0: q=E, kv=M, causal, head-mean -> outW ---
    gemm2(stream, b1h, b0h, ainwB + 0, ainb + 0, nullptr, nullptr, nullptr, BNrows, 256, 768,
          BNrows, 0, 256, 1, 0, 0, 0, 1, 1, 0, 0, Qb, Kb, Vtb, N_, N_);
    attn4_k<1><<<dim3(B_, 32), 256, 0, stream>>>(Qb, Kb, Vtb, Ob, outW, N_, N_, 1, H_);
    gemm2(stream, Ob, Ob, aoutwB + 0, aoutb + 0, b10, nullptr, nullptr, BNrows, 256, 256,
          N_, OBAT, HD_, N_, 0, 0, 0, 1, 0, 0, 0, nullptr, nullptr, nullptr, 0, 0);
    // S_base = LN1(proj + M + E)
    ln_k<<<BNrows, 256, 0, stream>>>(b10, b0, b1, l1g, l1b, nullptr, b2h, b10);

    // --- attn 1 (local, LW=25, causal) on S_base tail ---
    gemm2(stream, b2h + (size_t)(N_ - LW_) * D_, b2h + (size_t)(N_ - LW_) * D_,
          ainwB + 1 * 196608, ainb + 768, nullptr, nullptr, nullptr, B_ * LW_, 256, 768,
          LW_, (long long)N_ * D_, 256, 1, 0, 0, 0, 1, 1, 0, 0, Qb, Kb, Vtb, LW_, 32);
    attn4_k<0><<<dim3(BH, 2), 256, 0, stream>>>(Qb, Kb, Vtb, Ob, nullptr, LW_, 32, 1, 1);
    gemm2(stream, Ob, Ob, aoutwB + 1 * 65536, aoutb + 256, b0, nullptr, nullptr, B_ * LW_,
          256, 256, LW_, OBATL, HD_, LW_, 0, 0, 0, 1, 0, 0, 0, nullptr, nullptr, nullptr, 0, 0);
    scatterlocal_k<<<BNrows, 256, 0, stream>>>(b0, b7h, b10);

    // --- skill group path ---
    gather_k<<<BNrows, 256, 0, stream>>>(qi, Ttab, spb, b1h);   // G bf16
    gemm2(stream, b2h, b2h, b1h, nullptr, nullptr, BNNb, nullptr, N_, 256, N_,
          N_, 0, 256, 1, (long long)N_ * D_, (long long)N_ * D_, (long long)N_ * N_, B_,
          0, 0, 0, nullptr, nullptr, nullptr, 0, 0);
    gemm2(stream, BNNb, BNNb, stewB, steb, nullptr, b11h, nullptr, BNrows, 512, 256,
          BNrows, 0, 512, 1, 0, 0, 0, 1, 0, 0, 0, nullptr, nullptr, nullptr, 0, 0);
    gemm2(stream, b11h, b11h, ainwB + 2 * 196608, ainb + 2 * 768, nullptr, nullptr, nullptr,
          BNrows, 256, 768, BNrows, 0, 256, 1, 0, 0, 0, 1, 1, 0, 0, Qb, Kb, Vtb, N_, N_);
    attn4_k<0><<<dim3(BH, 32), 256, 0, stream>>>(Qb, Kb, Vtb, Ob, nullptr, N_, N_, 0, 1);
    gemm2(stream, Ob, Ob, aoutwB + 2 * 65536, aoutb + 2 * 256, b8, b8h, b10, BNrows,
          256, 256, N_, OBAT, HD_, N_, 0, 0, 0, 1, 0, 0, 0, nullptr, nullptr, nullptr, 0, 0);

    // --- attn 3: self on S_base, causal -> S_glob (+acc) ---
    gemm2(stream, b2h, b2h, ainwB + 3 * 196608, ainb + 3 * 768, nullptr, nullptr, nullptr,
          BNrows, 256, 768, BNrows, 0, 256, 1, 0, 0, 0, 1, 1, 0, 0, Qb, Kb, Vtb, N_, N_);
    attn4_k<0><<<dim3(BH, 32), 256, 0, stream>>>(Qb, Kb, Vtb, Ob, nullptr, N_, N_, 1, 1);
    gemm2(stream, Ob, Ob, aoutwB + 3 * 65536, aoutb + 3 * 256, b9, b9h, b10, BNrows,
          256, 256, N_, OBAT, HD_, N_, 0, 0, 0, 1, 0, 0, 0, nullptr, nullptr, nullptr, 0, 0);

    // --- attn 4: q=S_base, kv=S_local -> accumulate ---
    gemm2(stream, b2h, b7h, ainwB + 4 * 196608, ainb + 4 * 768, nullptr, nullptr, nullptr,
          BNrows, 256, 768, BNrows, 0, 256, 1, 0, 0, 0, 1, 1, 0, 0, Qb, Kb, Vtb, N_, N_);
    attn4_k<0><<<dim3(BH, 32), 256, 0, stream>>>(Qb, Kb, Vtb, Ob, nullptr, N_, N_, 0, 1);
    gemm2(stream, Ob, Ob, aoutwB + 4 * 65536, aoutb + 4 * 256, b10, nullptr, nullptr, BNrows,
          256, 256, N_, OBAT, HD_, N_, 0, 0, 0, 1, 0, 2, 0, nullptr, nullptr, nullptr, 0, 0);

    // --- attn 5: q=S_sg, kv=S_glob -> accumulate + bf16 shadow ---
    gemm2(stream, b8h, b9h, ainwB + 5 * 196608, ainb + 5 * 768, nullptr, nullptr, nullptr,
          BNrows, 256, 768, BNrows, 0, 256, 1, 0, 0, 0, 1, 1, 0, 0, Qb, Kb, Vtb, N_, N_);
    attn4_k<0><<<dim3(BH, 32), 256, 0, stream>>>(Qb, Kb, Vtb, Ob, nullptr, N_, N_, 0, 1);
    gemm2(stream, Ob, Ob, aoutwB + 5 * 65536, aoutb + 5 * 256, b10, b10h, nullptr, BNrows,
          256, 256, N_, OBAT, HD_, N_, 0, 0, 0, 1, 0, 2, 0, nullptr, nullptr, nullptr, 0, 0);

    // --- FFN + LN2 + prediction ---
    gemm2(stream, b10h, b10h, fw1B, fb1, nullptr, b11h, nullptr, BNrows, 256, 256,
          BNrows, 0, 256, 1, 0, 0, 0, 1, 0, 1, 0, nullptr, nullptr, nullptr, 0, 0);
    gemm2(stream, b11h, b11h, fw2B, fb2, b0, nullptr, nullptr, BNrows, 256, 256,
          BNrows, 0, 256, 1, 0, 0, 0, 1, 0, 0, 0, nullptr, nullptr, nullptr, 0, 0);
    ln_k<<<BNrows, 256, 0, stream>>>(b0, b10, nullptr, l2g, l2b, b1, nullptr, nullptr);
    pred_k<<<BNrows / 4, 256, 0, stream>>>(b1, pw, pb, out);
}

// Round 10
// 1128.942 us; speedup vs baseline: 6.7103x; 1.0273x over previous
//
#include <hip/hip_runtime.h>
#include <hip/hip_bf16.h>

#define B_  32
#define N_  512
#define D_  256
#define H_  8
#define HD_ 32
#define LW_ 25

typedef __hip_bfloat16 bf;
typedef __attribute__((ext_vector_type(8))) short short8;
typedef __attribute__((ext_vector_type(4))) float f32x4;

__device__ __forceinline__ void gload16(const void* g, void* l) {
    __builtin_amdgcn_global_load_lds(
        (const __attribute__((address_space(1))) unsigned int*)g,
        (__attribute__((address_space(3))) unsigned int*)l, 16, 0, 0);
}

// 1/sqrt(32) * log2(e): folded into Q so attention uses raw exp2
#define QSC 0.2550349f

// ---------------------------------------------------------------------------
// MFMA bf16 GEMM: C[m,o] = sum_k A[m,k]*W[o,k] (+bias). A,W bf16.
// Tile 128x128, BK=32, 4 waves x (64x64), global_load_lds staging.
// A address: (m/rowsPerA)*aBatch + (m%rowsPerA)*aRstride + k0*aKMul + (k&31)
// flags: 1=relu, 2=accumulate into Cf, 4=atomicAdd (splitK).
// Cacc: optional second accumulator. qkvmode: scatter Q/K/V^T bf16 (Q scaled).
// ---------------------------------------------------------------------------
__global__ __launch_bounds__(256) void gemm2_k(
    const bf* Aq, const bf* Akv, const bf* W, const float* bias,
    float* Cf, bf* Cb, float* Cacc,
    int M, int K, int Onum,
    int rowsPerA, long long aBatch, int aRstride, long long aKMul,
    long long aZ, long long wZ, long long cZ,
    int qkvmode, int flags, int splitKc,
    bf* Qd, bf* Kd, bf* Vd, int Lseq, int Lvt)
{
    __shared__ __align__(16) bf As[128 * 32];
    __shared__ __align__(16) bf Bs[128 * 32];
    const int tid = threadIdx.x;
    const int o0 = blockIdx.x * 128;
    const int m0 = blockIdx.y * 128;
    const int z  = blockIdx.z;
    const bf* A = (qkvmode && o0 >= 256) ? Akv : Aq;
    const bf* Wp = W;
    int kStart = 0, kEnd = K;
    if (splitKc > 0) {
        kStart = z * splitKc;
        kEnd   = min(K, kStart + splitKc);
    } else {
        A  += (long long)z * aZ;
        Wp += (long long)z * wZ;
        if (Cf) Cf += (long long)z * cZ;
        if (Cb) Cb += (long long)z * cZ;
    }

    const int w = tid >> 6, lane = tid & 63;
    const int col = lane & 15, quad = lane >> 4;
    const int wm = (w & 1) * 64;
    const int wn = (w >> 1) * 64;

    const int sidx0 = tid, sidx1 = tid + 256;
    long long arow0, arow1;
    {
        int m = m0 + (sidx0 >> 2);
        arow0 = (long long)(m / rowsPerA) * aBatch + (long long)(m % rowsPerA) * aRstride;
        m = m0 + (sidx1 >> 2);
        arow1 = (long long)(m / rowsPerA) * aBatch + (long long)(m % rowsPerA) * aRstride;
    }
    const long long wrow0 = (long long)(o0 + (sidx0 >> 2)) * K;
    const long long wrow1 = (long long)(o0 + (sidx1 >> 2)) * K;
    const int ac0 = (sidx0 & 3) * 8, ac1 = (sidx1 & 3) * 8;

    f32x4 acc[4][4];
    #pragma unroll
    for (int mt = 0; mt < 4; mt++)
        #pragma unroll
        for (int nt = 0; nt < 4; nt++)
            acc[mt][nt] = (f32x4)0.f;

    for (int k0 = kStart; k0 < kEnd; k0 += 32) {
        const long long ka = (long long)k0 * aKMul;
        gload16(A + arow0 + ka + ac0, As + sidx0 * 8);
        gload16(A + arow1 + ka + ac1, As + sidx1 * 8);
        gload16(Wp + wrow0 + k0 + ac0, Bs + sidx0 * 8);
        gload16(Wp + wrow1 + k0 + ac1, Bs + sidx1 * 8);
        __syncthreads();
        short8 af[4], bfr[4];
        #pragma unroll
        for (int mt = 0; mt < 4; mt++)
            af[mt] = *(const short8*)(As + (wm + mt * 16 + col) * 32 + quad * 8);
        #pragma unroll
        for (int nt = 0; nt < 4; nt++)
            bfr[nt] = *(const short8*)(Bs + (wn + nt * 16 + col) * 32 + quad * 8);
        #pragma unroll
        for (int mt = 0; mt < 4; mt++)
            #pragma unroll
            for (int nt = 0; nt < 4; nt++)
                acc[mt][nt] = __builtin_amdgcn_mfma_f32_16x16x32_bf16(
                    af[mt], bfr[nt], acc[mt][nt], 0, 0, 0);
        __syncthreads();
    }

    #pragma unroll
    for (int mt = 0; mt < 4; mt++) {
        #pragma unroll
        for (int nt = 0; nt < 4; nt++) {
            const int o = o0 + wn + nt * 16 + col;
            #pragma unroll
            for (int r = 0; r < 4; r++) {
                const int m = m0 + wm + mt * 16 + quad * 4 + r;
                if (m >= M) continue;
                float v = acc[mt][nt][r];
                if (bias) v += bias[o];
                if (flags & 1) v = fmaxf(v, 0.f);
                if (qkvmode) {
                    int which = o >> 8;
                    int oo = o & 255;
                    int hh = oo >> 5, j2 = oo & 31;
                    int bb = m / Lseq, nn = m % Lseq;
                    int bh = bb * H_ + hh;
                    if (which == 0) {
                        Qd[((size_t)bh * Lseq + nn) * HD_ + j2] =
                            __float2bfloat16(v * QSC);
                    } else if (which == 1) {
                        Kd[((size_t)bh * Lseq + nn) * HD_ + j2] = __float2bfloat16(v);
                    } else {
                        Vd[((size_t)bh * HD_ + j2) * Lvt + nn] = __float2bfloat16(v);
                    }
                } else if (flags & 4) {
                    atomicAdd(Cf + (long long)m * Onum + o, v);
                } else {
                    long long ci = (long long)m * Onum + o;
                    if (flags & 2) v += Cf[ci];
                    if (Cf) Cf[ci] = v;
                    if (Cb) Cb[ci] = __float2bfloat16(v);
                    if (Cacc) Cacc[ci] += v;
                }
            }
        }
    }
}

// ---------------------------------------------------------------------------
// MFMA attention v5: flash-style per-wave softmax + QT q-tiles per block
// (K/V fragments prefetched ONCE, reused across tiles).
// Grid: x = bh (XCD-local), y = q-supertile (16*QT rows). Wave w owns
// key-chunks c%4==w. Q pre-scaled by QSC; exp2 domain.
// Q,K: (BH,L,32) bf16. Vt: (BH,32,Lvt). O: (BH,L,32).
// MEAN (QT=1): x = b, loops 8 heads, prob head-mean in registers -> meanW.
// ---------------------------------------------------------------------------
#define SP 520
#define OPS 34

template<int MEAN, int QT>
__global__ __launch_bounds__(256) void attn5_k(
    const bf* Qb, const bf* Kb, const bf* Vtb,
    bf* O, float* meanW, int L, int Lvt, int causal, int nhl)
{
    __shared__ __align__(16) bf Sh[16 * SP];
    __shared__ __align__(16) float redm[2][16][4];
    __shared__ __align__(16) float invRow[16];
    __shared__ __align__(16) float Opart[4][16][OPS];
    const int tid = threadIdx.x;
    const int w = tid >> 6, lane = tid & 63;
    const int col = lane & 15, quad = lane >> 4;
    const int q0 = blockIdx.y * (16 * QT);
    const int bh0 = blockIdx.x * nhl;
    const int NCH = (L + 31) >> 5;
    // prefetch bound: chunks needed by the LAST tile (superset of earlier)
    const int qLast = q0 + (QT - 1) * 16;
    const int cmaxP = causal ? min(NCH - 1, (qLast + 15) >> 5) : (NCH - 1);
    const int nccP = (w <= cmaxP) ? ((cmaxP - w) >> 2) + 1 : 0;

    f32x4 mreg[4][2];
    if (MEAN) {
        #pragma unroll
        for (int cc = 0; cc < 4; cc++)
            #pragma unroll
            for (int hf = 0; hf < 2; hf++) mreg[cc][hf] = (f32x4)0.f;
    }

    for (int hh = 0; hh < nhl; hh++) {
        const int bh = bh0 + hh;
        const bf* Qh = Qb  + (size_t)bh * L * HD_;
        const bf* Kh = Kb  + (size_t)bh * L * HD_;
        const bf* Vh = Vtb + (size_t)bh * HD_ * Lvt;

        // ---- prefetch Q (all tiles) + K/V (once) ----
        short8 aq[QT];
        #pragma unroll
        for (int t = 0; t < QT; t++) {
            aq[t] = (short8)(short)0;
            const int n = q0 + t * 16 + col;
            if (n < L)
                aq[t] = *(const short8*)(Qh + (size_t)n * HD_ + quad * 8);
        }
        short8 kfr[4][2], vfr[4][2];
        #pragma unroll
        for (int cc = 0; cc < 4; cc++) {
            if (cc >= nccP) break;
            const int c = w + 4 * cc;
            #pragma unroll
            for (int hf = 0; hf < 2; hf++) {
                const int key = c * 32 + hf * 16 + col;
                kfr[cc][hf] = (short8)(short)0;
                if (key < L)
                    kfr[cc][hf] = *(const short8*)(Kh + (size_t)key * HD_ + quad * 8);
                vfr[cc][hf] = *(const short8*)(Vh + (size_t)(hf * 16 + col) * Lvt
                                                + c * 32 + quad * 8);
            }
        }

        #pragma unroll
        for (int t = 0; t < QT; t++) {
            const int qt0 = q0 + t * 16;
            const int cmaxT = causal ? min(NCH - 1, (qt0 + 15) >> 5) : (NCH - 1);
            const int nccT = (w <= cmaxT) ? ((cmaxT - w) >> 2) + 1 : 0;

            // ---- QK^T ----
            f32x4 sc[4][2];
            #pragma unroll
            for (int cc = 0; cc < 4; cc++) {
                if (cc >= nccT) break;
                #pragma unroll
                for (int hf = 0; hf < 2; hf++)
                    sc[cc][hf] = __builtin_amdgcn_mfma_f32_16x16x32_bf16(
                        aq[t], kfr[cc][hf], (f32x4)0.f, 0, 0, 0);
            }

            // ---- wave-local mask + max ----
            float pm[4] = {-3e38f, -3e38f, -3e38f, -3e38f};
            #pragma unroll
            for (int cc = 0; cc < 4; cc++) {
                if (cc >= nccT) break;
                const int c = w + 4 * cc;
                #pragma unroll
                for (int hf = 0; hf < 2; hf++) {
                    const int key = c * 32 + hf * 16 + col;
                    #pragma unroll
                    for (int r = 0; r < 4; r++) {
                        float v = sc[cc][hf][r];
                        if (causal && key > qt0 + quad * 4 + r) v = -1e9f;
                        sc[cc][hf][r] = v;
                        pm[r] = fmaxf(pm[r], v);
                    }
                }
            }
            #pragma unroll
            for (int r = 0; r < 4; r++)
                #pragma unroll
                for (int off = 1; off < 16; off <<= 1)
                    pm[r] = fmaxf(pm[r], __shfl_xor(pm[r], off));

            // ---- exp2 + wave-local sum; store unnormalized P ----
            float ps[4] = {0.f, 0.f, 0.f, 0.f};
            #pragma unroll
            for (int cc = 0; cc < 4; cc++) {
                if (cc >= nccT) break;
                const int c = w + 4 * cc;
                #pragma unroll
                for (int hf = 0; hf < 2; hf++)
                    #pragma unroll
                    for (int r = 0; r < 4; r++) {
                        float e = __builtin_amdgcn_exp2f(sc[cc][hf][r] - pm[r]);
                        sc[cc][hf][r] = e;
                        ps[r] += e;
                        Sh[(quad * 4 + r) * SP + c * 32 + hf * 16 + col] =
                            __float2bfloat16(e);
                    }
            }
            #pragma unroll
            for (int r = 0; r < 4; r++)
                #pragma unroll
                for (int off = 1; off < 16; off <<= 1)
                    ps[r] += __shfl_xor(ps[r], off);

            // ---- PV on own chunks (wave-private, no barrier) ----
            f32x4 oacc[2];
            oacc[0] = (f32x4)0.f; oacc[1] = (f32x4)0.f;
            #pragma unroll
            for (int cc = 0; cc < 4; cc++) {
                if (cc >= nccT) break;
                const int c = w + 4 * cc;
                const short8 ap = *(const short8*)(Sh + col * SP + c * 32 + quad * 8);
                #pragma unroll
                for (int hf = 0; hf < 2; hf++)
                    oacc[hf] = __builtin_amdgcn_mfma_f32_16x16x32_bf16(
                        ap, vfr[cc][hf], oacc[hf], 0, 0, 0);
            }

            // ---- exchange (m_w, s_w) ----
            if (col == 0) {
                #pragma unroll
                for (int r = 0; r < 4; r++) {
                    redm[0][quad * 4 + r][w] = pm[r];
                    redm[1][quad * 4 + r][w] = ps[r];
                }
            }
            __syncthreads();
            float esc[4], inv[4];
            #pragma unroll
            for (int r = 0; r < 4; r++) {
                f32x4 mw = *(const f32x4*)redm[0][quad * 4 + r];
                f32x4 sw = *(const f32x4*)redm[1][quad * 4 + r];
                float M = fmaxf(fmaxf(mw[0], mw[1]), fmaxf(mw[2], mw[3]));
                float T = sw[0] * __builtin_amdgcn_exp2f(mw[0] - M)
                        + sw[1] * __builtin_amdgcn_exp2f(mw[1] - M)
                        + sw[2] * __builtin_amdgcn_exp2f(mw[2] - M)
                        + sw[3] * __builtin_amdgcn_exp2f(mw[3] - M);
                esc[r] = __builtin_amdgcn_exp2f(pm[r] - M);
                inv[r] = 1.f / T;
            }
            if (w == 0 && col == 0) {
                #pragma unroll
                for (int r = 0; r < 4; r++) invRow[quad * 4 + r] = inv[r];
            }
            #pragma unroll
            for (int hf = 0; hf < 2; hf++)
                #pragma unroll
                for (int r = 0; r < 4; r++)
                    Opart[w][quad * 4 + r][hf * 16 + col] = oacc[hf][r] * esc[r];
            if (MEAN) {
                #pragma unroll
                for (int cc = 0; cc < 4; cc++) {
                    if (cc >= nccT) break;
                    #pragma unroll
                    for (int hf = 0; hf < 2; hf++)
                        #pragma unroll
                        for (int r = 0; r < 4; r++)
                            mreg[cc][hf][r] += sc[cc][hf][r] * (esc[r] * inv[r]);
                }
            }
            __syncthreads();

            // ---- combine + contiguous (bh,L,32) write ----
            for (int e = tid; e < 512; e += 256) {
                int row = e >> 5, d = e & 31;
                float v = (Opart[0][row][d] + Opart[1][row][d] +
                           Opart[2][row][d] + Opart[3][row][d]) * invRow[row];
                int n = qt0 + row;
                if (n < L)
                    O[((size_t)bh * L + n) * HD_ + d] = __float2bfloat16(v);
            }
            if (t + 1 < QT || hh + 1 < nhl) __syncthreads();
        }
    }

    if (MEAN) {
        const size_t base = ((size_t)blockIdx.x * N_ + q0) * N_;
        #pragma unroll
        for (int cc = 0; cc < 4; cc++) {
            const int c = w + 4 * cc;
            #pragma unroll
            for (int hf = 0; hf < 2; hf++)
                #pragma unroll
                for (int r = 0; r < 4; r++)
                    meanW[base + (size_t)(quad * 4 + r) * N_ + c * 32 + hf * 16 + col]
                        = mreg[cc][hf][r] * 0.125f;
        }
    }
}

// ---------------------------------------------------------------------------
// Small kernels
// ---------------------------------------------------------------------------
__global__ void conv_k(const float* s, bf* d, int n) {
    int i = blockIdx.x * 256 + threadIdx.x;
    if (i < n) d[i] = __float2bfloat16(s[i]);
}

__global__ __launch_bounds__(256) void rowsoftmax_k(const float* in, bf* out) {
    __shared__ float red[256];
    const long long row = blockIdx.x;
    const int t = threadIdx.x;
    const float* ip = in + row * 2048;
    bf* op = out + row * 2048;
    float m = -3e38f;
    for (int k = t; k < 2048; k += 256) m = fmaxf(m, ip[k]);
    red[t] = m; __syncthreads();
    for (int s = 128; s > 0; s >>= 1) { if (t < s) red[t] = fmaxf(red[t], red[t + s]); __syncthreads(); }
    m = red[0]; __syncthreads();
    float ps = 0.f;
    float ev[8];
    #pragma unroll
    for (int i = 0; i < 8; i++) { ev[i] = __expf(ip[t + i * 256] - m); ps += ev[i]; }
    red[t] = ps; __syncthreads();
    for (int s = 128; s > 0; s >>= 1) { if (t < s) red[t] += red[t + s]; __syncthreads(); }
    const float inv = 1.f / red[0];
    #pragma unroll
    for (int i = 0; i < 8; i++) op[t + i * 256] = __float2bfloat16(ev[i] * inv);
}

__global__ void embed_k(const int* q, const int* r, const int* qry,
                        const float* Memb, const float* Eemb, const float* P,
                        float* M, float* E, bf* Mh, bf* Eh) {
    const int i = blockIdx.x; const int t = threadIdx.x;
    const int n = i & (N_ - 1);
    const int x = q[i] + 2048 * r[i];
    float mv = Memb[(long long)x * D_ + t] + P[(long long)n * D_ + t];
    float evv = Eemb[(long long)qry[i] * D_ + t];
    M[(long long)i * D_ + t] = mv;  Mh[(long long)i * D_ + t] = __float2bfloat16(mv);
    E[(long long)i * D_ + t] = evv; Eh[(long long)i * D_ + t] = __float2bfloat16(evv);
}

__global__ void gather_k(const int* q, const float* T, const float* spb, bf* G) {
    const int i = blockIdx.x; const int t = threadIdx.x;
    G[(long long)i * D_ + t] = __float2bfloat16(T[(long long)q[i] * D_ + t] + spb[t]);
}

__global__ __launch_bounds__(256) void ln_k(const float* xa, const float* xb, const float* xc,
                                            const float* g, const float* bta,
                                            float* outF, bf* outB, float* out2) {
    __shared__ float red[256];
    const long long row = blockIdx.x;
    const int t = threadIdx.x;
    float v = xa[row * D_ + t];
    if (xb) v += xb[row * D_ + t];
    if (xc) v += xc[row * D_ + t];
    red[t] = v; __syncthreads();
    for (int s = 128; s > 0; s >>= 1) { if (t < s) red[t] += red[t + s]; __syncthreads(); }
    const float mean = red[0] * (1.f / 256.f);
    __syncthreads();
    const float d = v - mean;
    red[t] = d * d; __syncthreads();
    for (int s = 128; s > 0; s >>= 1) { if (t < s) red[t] += red[t + s]; __syncthreads(); }
    const float var = red[0] * (1.f / 256.f);
    const float y = d * rsqrtf(var + 1e-5f) * g[t] + bta[t];
    if (outF) outF[row * D_ + t] = y;
    if (outB) outB[row * D_ + t] = __float2bfloat16(y);
    if (out2) out2[row * D_ + t] = y;
}

__global__ void scatterlocal_k(const float* tail, bf* Slocalh, float* Sacc) {
    const int i = blockIdx.x; const int t = threadIdx.x;
    const int n = i & (N_ - 1), b = i >> 9;
    float v = 0.f;
    if (n >= N_ - LW_) {
        v = tail[((long long)(b * LW_ + (n - (N_ - LW_)))) * D_ + t];
        Sacc[(long long)i * D_ + t] += v;
    }
    Slocalh[(long long)i * D_ + t] = __float2bfloat16(v);
}

__global__ void zero4_k(float4* p) {
    p[(long long)blockIdx.x * 256 + threadIdx.x] = make_float4(0.f, 0.f, 0.f, 0.f);
}

__global__ __launch_bounds__(256) void pred_k(const float* F, const float* pw, const float* pb,
                                              float* out) {
    const int tid = threadIdx.x;
    const int wave = tid >> 6, lane = tid & 63;
    const long long row = (long long)blockIdx.x * 4 + wave;
    const float* fp = F + row * D_ + lane * 4;
    float s = 0.f;
    #pragma unroll
    for (int j = 0; j < 4; j++) s += fp[j] * pw[lane * 4 + j];
    #pragma unroll
    for (int off = 32; off > 0; off >>= 1) s += __shfl_down(s, off);
    if (lane == 0) {
        float p = 1.f / (1.f + __expf(-(s + pb[0])));
        out[row] = p;
    }
}

// ---------------------------------------------------------------------------
static void gemm2(hipStream_t st, const bf* Aq, const bf* Akv,
                  const bf* W, const float* bias, float* Cf, bf* Cb, float* Cacc,
                  int M, int K, int Onum,
                  int rowsPerA, long long aBatch, int aRstride, long long aKMul,
                  long long aZ, long long wZ, long long cZ, int Z,
                  int qkv, int flags, int splitKc,
                  bf* Qd, bf* Kd, bf* Vd, int Lseq, int Lvt)
{
    dim3 g(Onum / 128, (M + 127) / 128, Z), blk(256, 1, 1);
    gemm2_k<<<g, blk, 0, st>>>(Aq, Akv, W, bias, Cf, Cb, Cacc, M, K, Onum,
                               rowsPerA, aBatch, aRstride, aKMul,
                               aZ, wZ, cZ, qkv, flags, splitKc,
                               Qd, Kd, Vd, Lseq, Lvt);
}

extern "C" void kernel_launch(void* const* d_in, const int* in_sizes, int n_in,
                              void* d_out, int out_size, void* d_ws, size_t ws_size,
                              hipStream_t stream)
{
    const int* qi  = (const int*)d_in[0];
    const int* ri  = (const int*)d_in[1];
    const int* qry = (const int*)d_in[2];
    const float* Memb = (const float*)d_in[3];
    const float* Eemb = (const float*)d_in[4];
    const float* Pp   = (const float*)d_in[5];
    const float* ainw = (const float*)d_in[6];
    const float* ainb = (const float*)d_in[7];
    const float* aoutw= (const float*)d_in[8];
    const float* aoutb= (const float*)d_in[9];
    const float* scw  = (const float*)d_in[10];
    const float* spw  = (const float*)d_in[11];
    const float* spb  = (const float*)d_in[12];
    const float* stew = (const float*)d_in[13];
    const float* steb = (const float*)d_in[14];
    const float* fw1  = (const float*)d_in[15];
    const float* fb1  = (const float*)d_in[16];
    const float* fw2  = (const float*)d_in[17];
    const float* fb2  = (const float*)d_in[18];
    const float* l1g  = (const float*)d_in[19];
    const float* l1b  = (const float*)d_in[20];
    const float* l2g  = (const float*)d_in[21];
    const float* l2b  = (const float*)d_in[22];
    const float* pw   = (const float*)d_in[23];
    const float* pb   = (const float*)d_in[24];
    float* out = (float*)d_out;
    float* outW = out + B_ * N_;

    const size_t BND = (size_t)B_ * N_ * D_;   // 4,194,304
    float* ws = (float*)d_ws;
    float* b10 = ws;                 // accumulator f32
    float* b0  = ws + 1 * BND;       // M f32 / tail scratch / FFN-out f32
    float* b1  = ws + 2 * BND;       // E f32 / ln2-out f32
    float* b8  = ws + 3 * BND;       // S_sg f32
    float* b9  = ws + 4 * BND;       // S_glob f32
    float* hp  = ws + 5 * BND;       // bf16 region start
    bf* b0h  = (bf*)(hp + 0 * (BND / 2));   // M bf16
    bf* b1h  = (bf*)(hp + 1 * (BND / 2));   // E bf16 / G bf16
    bf* b2h  = (bf*)(hp + 2 * (BND / 2));   // S_base bf16
    bf* b7h  = (bf*)(hp + 3 * (BND / 2));   // S_local bf16
    bf* b8h  = (bf*)(hp + 4 * (BND / 2));
    bf* b9h  = (bf*)(hp + 5 * (BND / 2));
    bf* b10h = (bf*)(hp + 6 * (BND / 2));
    bf* b11h = (bf*)(hp + 7 * (BND / 2));   // S_sg-pre / FFN hidden bf16
    bf* Qb   = (bf*)(hp + 8 * (BND / 2));
    bf* Kb   = (bf*)(hp + 9 * (BND / 2));
    bf* Vtb  = (bf*)(hp + 10 * (BND / 2));
    bf* Ob   = (bf*)(hp + 11 * (BND / 2));  // attn out bf16 (BH,L,32)
    bf* BNNb = (bf*)(hp + 12 * (BND / 2));  // (B,N,N) bf16
    float* Ttab = hp + 12 * (BND / 2) + BND;        // (2048,256) f32
    bf* SWb  = (bf*)(Ttab + 2048 * 256);            // (2048,2048) bf16
    bf* Wb   = SWb + (size_t)2048 * 2048;           // weights bf16
    bf* ainwB = Wb;
    bf* aoutwB = ainwB + 6 * 768 * 256;
    bf* spwB  = aoutwB + 6 * 256 * 256;
    bf* stewB = spwB + 256 * 2048;
    bf* fw1B  = stewB + 256 * 512;
    bf* fw2B  = fw1B + 256 * 256;
    const int BNrows = B_ * N_;               // 16384
    const int BH = B_ * H_;                   // 256
    const long long OBAT = 8LL * N_ * HD_;    // O batch stride (b) full attns
    const long long OBATL = 8LL * LW_ * HD_;  // O batch stride attn1

    // --- weight conversions (bf16) ---
    conv_k<<<(6*768*256 + 255)/256, 256, 0, stream>>>(ainw, ainwB, 6*768*256);
    conv_k<<<(6*256*256 + 255)/256, 256, 0, stream>>>(aoutw, aoutwB, 6*256*256);
    conv_k<<<(256*2048 + 255)/256, 256, 0, stream>>>(spw, spwB, 256*2048);
    conv_k<<<(256*512 + 255)/256, 256, 0, stream>>>(stew, stewB, 256*512);
    conv_k<<<(256*256 + 255)/256, 256, 0, stream>>>(fw1, fw1B, 256*256);
    conv_k<<<(256*256 + 255)/256, 256, 0, stream>>>(fw2, fw2B, 256*256);

    // --- skill table: Ttab = softmax(scw) @ spw^T   (splitK=8, f32 atomics) ---
    rowsoftmax_k<<<2048, 256, 0, stream>>>(scw, SWb);
    zero4_k<<<(2048 * 256) / 1024, 256, 0, stream>>>((float4*)Ttab);
    gemm2(stream, SWb, SWb, spwB, nullptr, Ttab, nullptr, nullptr, 2048, 2048, 256,
          2048, 0, 2048, 1, 0, 0, 0, 8, 0, 4, 256, nullptr, nullptr, nullptr, 0, 0);

    // --- embeddings ---
    embed_k<<<BNrows, 256, 0, stream>>>(qi, ri, qry, Memb, Eemb, Pp, b0, b1, b0h, b1h);

    // --- attn 0: q=E, kv=M, causal, head-mean -> outW ---
    gemm2(stream, b1h, b0h, ainwB + 0, ainb + 0, nullptr, nullptr, nullptr, BNrows, 256, 768,
          BNrows, 0, 256, 1, 0, 0, 0, 1, 1, 0, 0, Qb, Kb, Vtb, N_, N_);
    attn5_k<1, 1><<<dim3(B_, 32), 256, 0, stream>>>(Qb, Kb, Vtb, Ob, outW, N_, N_, 1, H_);
    gemm2(stream, Ob, Ob, aoutwB + 0, aoutb + 0, b10, nullptr, nullptr, BNrows, 256, 256,
          N_, OBAT, HD_, N_, 0, 0, 0, 1, 0, 0, 0, nullptr, nullptr, nullptr, 0, 0);
    // S_base = LN1(proj + M + E)
    ln_k<<<BNrows, 256, 0, stream>>>(b10, b0, b1, l1g, l1b, nullptr, b2h, b10);

    // --- attn 1 (local, LW=25, causal) on S_base tail ---
    gemm2(stream, b2h + (size_t)(N_ - LW_) * D_, b2h + (size_t)(N_ - LW_) * D_,
          ainwB + 1 * 196608, ainb + 768, nullptr, nullptr, nullptr, B_ * LW_, 256, 768,
          LW_, (long long)N_ * D_, 256, 1, 0, 0, 0, 1, 1, 0, 0, Qb, Kb, Vtb, LW_, 32);
    attn5_k<0, 2><<<dim3(BH, 1), 256, 0, stream>>>(Qb, Kb, Vtb, Ob, nullptr, LW_, 32, 1, 1);
    gemm2(stream, Ob, Ob, aoutwB + 1 * 65536, aoutb + 256, b0, nullptr, nullptr, B_ * LW_,
          256, 256, LW_, OBATL, HD_, LW_, 0, 0, 0, 1, 0, 0, 0, nullptr, nullptr, nullptr, 0, 0);
    scatterlocal_k<<<BNrows, 256, 0, stream>>>(b0, b7h, b10);

    // --- skill group path ---
    gather_k<<<BNrows, 256, 0, stream>>>(qi, Ttab, spb, b1h);   // G bf16
    gemm2(stream, b2h, b2h, b1h, nullptr, nullptr, BNNb, nullptr, N_, 256, N_,
          N_, 0, 256, 1, (long long)N_ * D_, (long long)N_ * D_, (long long)N_ * N_, B_,
          0, 0, 0, nullptr, nullptr, nullptr, 0, 0);
    gemm2(stream, BNNb, BNNb, stewB, steb, nullptr, b11h, nullptr, BNrows, 512, 256,
          BNrows, 0, 512, 1, 0, 0, 0, 1, 0, 0, 0, nullptr, nullptr, nullptr, 0, 0);
    gemm2(stream, b11h, b11h, ainwB + 2 * 196608, ainb + 2 * 768, nullptr, nullptr, nullptr,
          BNrows, 256, 768, BNrows, 0, 256, 1, 0, 0, 0, 1, 1, 0, 0, Qb, Kb, Vtb, N_, N_);
    attn5_k<0, 2><<<dim3(BH, 16), 256, 0, stream>>>(Qb, Kb, Vtb, Ob, nullptr, N_, N_, 0, 1);
    gemm2(stream, Ob, Ob, aoutwB + 2 * 65536, aoutb + 2 * 256, b8, b8h, b10, BNrows,
          256, 256, N_, OBAT, HD_, N_, 0, 0, 0, 1, 0, 0, 0, nullptr, nullptr, nullptr, 0, 0);

    // --- attn 3: self on S_base, causal -> S_glob (+acc) ---
    gemm2(stream, b2h, b2h, ainwB + 3 * 196608, ainb + 3 * 768, nullptr, nullptr, nullptr,
          BNrows, 256, 768, BNrows, 0, 256, 1, 0, 0, 0, 1, 1, 0, 0, Qb, Kb, Vtb, N_, N_);
    attn5_k<0, 2><<<dim3(BH, 16), 256, 0, stream>>>(Qb, Kb, Vtb, Ob, nullptr, N_, N_, 1, 1);
    gemm2(stream, Ob, Ob, aoutwB + 3 * 65536, aoutb + 3 * 256, b9, b9h, b10, BNrows,
          256, 256, N_, OBAT, HD_, N_, 0, 0, 0, 1, 0, 0, 0, nullptr, nullptr, nullptr, 0, 0);

    // --- attn 4: q=S_base, kv=S_local -> accumulate ---
    gemm2(stream, b2h, b7h, ainwB + 4 * 196608, ainb + 4 * 768, nullptr, nullptr, nullptr,
          BNrows, 256, 768, BNrows, 0, 256, 1, 0, 0, 0, 1, 1, 0, 0, Qb, Kb, Vtb, N_, N_);
    attn5_k<0, 2><<<dim3(BH, 16), 256, 0, stream>>>(Qb, Kb, Vtb, Ob, nullptr, N_, N_, 0, 1);
    gemm2(stream, Ob, Ob, aoutwB + 4 * 65536, aoutb + 4 * 256, b10, nullptr, nullptr, BNrows,
          256, 256, N_, OBAT, HD_, N_, 0, 0, 0, 1, 0, 2, 0, nullptr, nullptr, nullptr, 0, 0);

    // --- attn 5: q=S_sg, kv=S_glob -> accumulate + bf16 shadow ---
    gemm2(stream, b8h, b9h, ainwB + 5 * 196608, ainb + 5 * 768, nullptr, nullptr, nullptr,
          BNrows, 256, 768, BNrows, 0, 256, 1, 0, 0, 0, 1, 1, 0, 0, Qb, Kb, Vtb, N_, N_);
    attn5_k<0, 2><<<dim3(BH, 16), 256, 0, stream>>>(Qb, Kb, Vtb, Ob, nullptr, N_, N_, 0, 1);
    gemm2(stream, Ob, Ob, aoutwB + 5 * 65536, aoutb + 5 * 256, b10, b10h, nullptr, BNrows,
          256, 256, N_, OBAT, HD_, N_, 0, 0, 0, 1, 0, 2, 0, nullptr, nullptr, nullptr, 0, 0);

    // --- FFN + LN2 + prediction ---
    gemm2(stream, b10h, b10h, fw1B, fb1, nullptr, b11h, nullptr, BNrows, 256, 256,
          BNrows, 0, 256, 1, 0, 0, 0, 1, 0, 1, 0, nullptr, nullptr, nullptr, 0, 0);
    gemm2(stream, b11h, b11h, fw2B, fb2, b0, nullptr, nullptr, BNrows, 256, 256,
          BNrows, 0, 256, 1, 0, 0, 0, 1, 0, 0, 0, nullptr, nullptr, nullptr, 0, 0);
    ln_k<<<BNrows, 256, 0, stream>>>(b0, b10, nullptr, l2g, l2b, b1, nullptr, nullptr);
    pred_k<<<BNrows / 4, 256, 0, stream>>>(b1, pw, pb, out);
}